// Round 15
// baseline (398.957 us; speedup 1.0000x reference)
//
#include <hip/hip_runtime.h>
#include <cfloat>

#define Dm 256
#define HW 1024
#define NE 2048
#define L_TOT 32768
#define QOFF 8388608   // B*C*H*W
#define TAU 0.1f

#define QSCALE 4064.0f               // 32512/8
#define CHC 7.93613e-3f              // 2*65536/QSCALE^2
#define CXC 3.10005e-5f              // 2*256/QSCALE^2

typedef __attribute__((ext_vector_type(4))) int i32x4;
typedef const __attribute__((address_space(1))) unsigned int* as1_u32p;
typedef __attribute__((address_space(3))) unsigned int* as3_u32p;

#define GLL(gp, lp) __builtin_amdgcn_global_load_lds((as1_u32p)(gp), (as3_u32p)(lp), 16, 0, 0)

__device__ __forceinline__ void q8(float x, signed char& hi, signed char& lo) {
    int xi = __float2int_rn(x * QSCALE);
    xi = max(-32512, min(32512, xi));
    int h = (xi + 128) >> 8;
    hi = (signed char)h;
    lo = (signed char)(xi - (h << 8));
}

// ---------------- K1 (fallback only): code norms ----------------
__global__ void k_enorm(const float* __restrict__ emb, float* __restrict__ enorm) {
    int w = threadIdx.x >> 6, lane = threadIdx.x & 63;
    int n = blockIdx.x * 4 + w;
    const float4 v = *reinterpret_cast<const float4*>(emb + (size_t)n * Dm + lane * 4);
    double s = (double)v.x * v.x + (double)v.y * v.y + (double)v.z * v.z + (double)v.w * v.w;
    #pragma unroll
    for (int off = 32; off; off >>= 1) s += __shfl_xor(s, off);
    if (lane == 0) enorm[n] = (float)s;
}

// ---------------- fused: i8 split Z (transpose) + split E + norms + ws zeroing ----------------
__global__ __launch_bounds__(256) void k_split_i8(
    const float* __restrict__ z, const float* __restrict__ emb,
    signed char* __restrict__ z_hi, signed char* __restrict__ z_lo,
    signed char* __restrict__ e_hi, signed char* __restrict__ e_lo,
    float* __restrict__ enorm, float* __restrict__ zn_part,
    float* __restrict__ used, int* __restrict__ flag_cnt)
{
    __shared__ signed char zh[32][264];
    __shared__ signed char zl[32][264];
    __shared__ double zsum[4];
    const int t = threadIdx.x;
    const int w = t >> 6, lane = t & 63;

    if (blockIdx.x >= 16 && blockIdx.x < 24) used[(blockIdx.x - 16) * 256 + t] = 0.f;
    if (blockIdx.x == 24 && t == 0) *flag_cnt = 0;

    // fused E-split: waves 0,1 each handle one emb row
    if (w < 2) {
        int n = blockIdx.x * 2 + w;
        const float4 v = *reinterpret_cast<const float4*>(emb + (size_t)n * Dm + lane * 4);
        float vv[4] = { v.x, v.y, v.z, v.w };
        double s = (double)v.x * v.x + (double)v.y * v.y + (double)v.z * v.z + (double)v.w * v.w;
        #pragma unroll
        for (int off = 32; off; off >>= 1) s += __shfl_xor(s, off);
        if (lane == 0) enorm[n] = (float)s;
        signed char h4[4], l4[4];
        #pragma unroll
        for (int j = 0; j < 4; ++j) q8(vv[j], h4[j], l4[j]);
        *reinterpret_cast<int*>(e_hi + (size_t)n * Dm + lane * 4) = *reinterpret_cast<int*>(h4);
        *reinterpret_cast<int*>(e_lo + (size_t)n * Dm + lane * 4) = *reinterpret_cast<int*>(l4);
    }

    // Z split+transpose + ||z||^2 partial
    const int b  = blockIdx.x >> 5;
    const int p0 = (blockIdx.x & 31) * 32;
    const int pp = t & 31, cb = t >> 5;
    const float* zb = z + (size_t)b * (Dm * HW) + p0 + pp;
    float zs = 0.f;
    for (int ci = 0; ci < 32; ++ci) {
        int c = ci * 8 + cb;
        float x = zb[(size_t)c * HW];
        zs = fmaf(x, x, zs);
        q8(x, zh[pp][c], zl[pp][c]);
    }
    double d = zs;
    #pragma unroll
    for (int off = 32; off; off >>= 1) d += __shfl_xor(d, off);
    if ((t & 63) == 0) zsum[w] = d;
    __syncthreads();
    if (t == 0) zn_part[blockIdx.x] = (float)(zsum[0] + zsum[1] + zsum[2] + zsum[3]);
    const int l0 = b * 1024 + p0;
    #pragma unroll
    for (int r = 0; r < 8; ++r) {
        int id = r * 256 + t;
        int row = id >> 6, ch = id & 63;
        *reinterpret_cast<int*>(z_hi + (size_t)(l0 + row) * Dm + ch * 4) =
            *reinterpret_cast<int*>(&zh[row][ch * 4]);
        *reinterpret_cast<int*>(z_lo + (size_t)(l0 + row) * Dm + ch * 4) =
            *reinterpret_cast<int*>(&zl[row][ch * 4]);
    }
}

// ---------------- K2: i8 fixed-point score GEMM + top-2 argmin ----------------
// r14 step schedule verbatim; single variable: 4 ni-stripes of 512 codes
// (grid 1024) + 4 blocks/CU residency (launch_bounds(256,4); LDS 128 KB/CU,
// VGPR stays at the 128 = 4-waves/SIMD cap). 48 steps/block; 4 independent
// blocks cover each other's GLL barrier drains (r4 TLP mechanism).
__global__ __launch_bounds__(256, 4) void k_score_i8(
    const signed char* __restrict__ zh, const signed char* __restrict__ zl,
    const signed char* __restrict__ eh, const signed char* __restrict__ el,
    const float* __restrict__ enorm,
    float* __restrict__ pd1, float* __restrict__ pd2, int* __restrict__ pi1)
{
    __shared__ signed char ldsA[2][8192];
    __shared__ signed char ldsB[2][8192];

    const int t    = threadIdx.x;
    const int lane = t & 63, w = t >> 6;          // w: 0..3
    const int wm = w >> 1, wc = w & 1;
    const int c15 = lane & 15, g4 = lane >> 4;

    // bijective XCD swizzle (1024 wgs)
    const int bx = blockIdx.x;
    const int wg = (bx & 7) * 128 + (bx >> 3);
    const int mi = wg >> 2, ni = wg & 3;
    const int l0 = mi * 128;
    const int nbase = ni * 512;

    const int srow = t & 127;
    const int sc16 = (t >> 7) << 4;               // 0 or 16
    const size_t abase  = (size_t)(l0 + srow) * Dm + sc16;
    const size_t abase2 = abase + 32;
    const size_t bbase  = (size_t)(nbase + srow) * Dm + sc16;
    const size_t bbase2 = bbase + 32;
    const int ld0 = t * 16, ld1 = t * 16 + 4096;

    int offA[4], offB[4];
    #pragma unroll
    for (int m = 0; m < 4; ++m) offA[m] = g4 * 2048 + (wm * 64 + m * 16 + c15) * 16;
    #pragma unroll
    for (int n = 0; n < 4; ++n) offB[n] = g4 * 2048 + (wc * 64 + n * 16 + c15) * 16;

    float d1[4][4], d2[4][4]; int i1[4][4];
    #pragma unroll
    for (int m = 0; m < 4; ++m)
        #pragma unroll
        for (int r = 0; r < 4; ++r) { d1[m][r] = 3.4e38f; d2[m][r] = 3.4e38f; i1[m][r] = 0; }

    GLL(zh + abase,  &ldsA[0][ld0]);
    GLL(zh + abase2, &ldsA[0][ld1]);
    GLL(eh + bbase,  &ldsB[0][ld0]);
    GLL(eh + bbase2, &ldsB[0][ld1]);
    __syncthreads();

    int cur = 0, it = 0;
    int pnt = 0, pkt = 1;
    size_t pntoff = 0;

    auto kstep = [&](i32x4 (&ACC)[4][4]) {
        if (it + 1 < 48) {
            const int term = pkt >> 2;
            const size_t kcf = (size_t)((pkt & 3) << 6);
            const signed char* As = (term == 2) ? zl : zh;
            const signed char* Bs = (term == 1) ? el : eh;
            GLL(As + abase  + kcf,           &ldsA[cur ^ 1][ld0]);
            GLL(As + abase2 + kcf,           &ldsA[cur ^ 1][ld1]);
            GLL(Bs + bbase  + pntoff + kcf,  &ldsB[cur ^ 1][ld0]);
            GLL(Bs + bbase2 + pntoff + kcf,  &ldsB[cur ^ 1][ld1]);
            if (++pkt == 12) { pkt = 0; ++pnt; pntoff = (size_t)pnt << 15; }
        }
        i32x4 af[4], bfv[4];
        #pragma unroll
        for (int m = 0; m < 4; ++m)
            af[m] = *reinterpret_cast<const i32x4*>(&ldsA[cur][offA[m]]);
        #pragma unroll
        for (int n = 0; n < 4; ++n)
            bfv[n] = *reinterpret_cast<const i32x4*>(&ldsB[cur][offB[n]]);
        __builtin_amdgcn_s_setprio(1);
        #pragma unroll
        for (int m = 0; m < 4; ++m)
            #pragma unroll
            for (int n = 0; n < 4; ++n)
                ACC[m][n] = __builtin_amdgcn_mfma_i32_16x16x64_i8(
                    af[m], bfv[n], ACC[m][n], 0, 0, 0);
        __builtin_amdgcn_s_setprio(0);
        __syncthreads();
        cur ^= 1;
        ++it;
    };

    for (int nt = 0; nt < 4; ++nt) {
        i32x4 accH[4][4], accX[4][4];
        #pragma unroll
        for (int m = 0; m < 4; ++m)
            #pragma unroll
            for (int n = 0; n < 4; ++n) {
                accH[m][n] = (i32x4){0, 0, 0, 0};
                accX[m][n] = (i32x4){0, 0, 0, 0};
            }

        #pragma unroll
        for (int k4 = 0; k4 < 4; ++k4) kstep(accH);   // (zh, eh) -> HH
        #pragma unroll
        for (int k4 = 0; k4 < 4; ++k4) kstep(accX);   // (zh, el) -> HL
        #pragma unroll
        for (int k4 = 0; k4 < 4; ++k4) kstep(accX);   // (zl, eh) -> LH

        int n0 = nbase + nt * 128;
        #pragma unroll
        for (int n = 0; n < 4; ++n) {
            int ng = n0 + wc * 64 + n * 16 + c15;
            float en = enorm[ng];
            #pragma unroll
            for (int m = 0; m < 4; ++m)
                #pragma unroll
                for (int r = 0; r < 4; ++r) {
                    float sx = fmaf(-CXC, (float)accX[m][n][r], en);
                    float s  = fmaf(-CHC, (float)accH[m][n][r], sx);
                    if (s < d1[m][r]) { d2[m][r] = d1[m][r]; d1[m][r] = s; i1[m][r] = ng; }
                    else if (s < d2[m][r]) d2[m][r] = s;
                }
        }
    }

    #pragma unroll
    for (int off = 1; off <= 8; off <<= 1) {
        #pragma unroll
        for (int m = 0; m < 4; ++m)
            #pragma unroll
            for (int r = 0; r < 4; ++r) {
                float od1 = __shfl_xor(d1[m][r], off);
                int   oi1 = __shfl_xor(i1[m][r], off);
                float od2 = __shfl_xor(d2[m][r], off);
                float nd2 = fminf(fminf(d2[m][r], od2), fmaxf(d1[m][r], od1));
                if (od1 < d1[m][r] || (od1 == d1[m][r] && oi1 < i1[m][r])) {
                    d1[m][r] = od1; i1[m][r] = oi1;
                }
                d2[m][r] = nd2;
            }
    }

    float* rs1 = (float*)&ldsA[0][0];
    float* rs2 = rs1 + 128;
    int*   ri  = (int*)(rs2 + 128);
    if (wc == 1 && c15 == 0) {
        #pragma unroll
        for (int m = 0; m < 4; ++m)
            #pragma unroll
            for (int r = 0; r < 4; ++r) {
                int q = wm * 64 + m * 16 + g4 * 4 + r;
                rs1[q] = d1[m][r];
                rs2[q] = d2[m][r];
                ri [q] = i1[m][r];
            }
    }
    __syncthreads();
    if (wc == 0 && c15 == 0) {
        #pragma unroll
        for (int m = 0; m < 4; ++m)
            #pragma unroll
            for (int r = 0; r < 4; ++r) {
                int q = wm * 64 + m * 16 + g4 * 4 + r;
                float bd1 = d1[m][r], bd2 = d2[m][r]; int bi1 = i1[m][r];
                float od1 = rs1[q], od2 = rs2[q];
                int   oi1 = ri [q];
                float nd2 = fminf(fminf(bd2, od2), fmaxf(bd1, od1));
                if (od1 < bd1 || (od1 == bd1 && oi1 < bi1)) { bd1 = od1; bi1 = oi1; }
                bd2 = nd2;
                int gq = l0 + q;
                pd1[ni * L_TOT + gq] = bd1;
                pd2[ni * L_TOT + gq] = bd2;
                pi1[ni * L_TOT + gq] = bi1;
            }
    }
}

// ---------------- fused merge (4 stripes) + gather ----------------
__global__ __launch_bounds__(256) void k_mg(
    const float* __restrict__ pd1, const float* __restrict__ pd2,
    const int* __restrict__ pi1, const float* __restrict__ emb,
    int* __restrict__ ws_idx, float* __restrict__ out_idxf,
    float* __restrict__ used, int* __restrict__ flag_cnt,
    int* __restrict__ flag_list, float* __restrict__ d1_part,
    float* __restrict__ outq)
{
    __shared__ int sidx[64];
    __shared__ float eldT[Dm][65];
    const int t = threadIdx.x;
    const int l0 = blockIdx.x * 64;
    const int b = l0 >> 10, p0 = l0 & 1023;

    if (t < 64) {
        int gq = l0 + t;
        float d1 = pd1[gq], d2 = pd2[gq]; int i1 = pi1[gq];
        #pragma unroll
        for (int s = 1; s < 4; ++s) {
            float od1 = pd1[(size_t)s * L_TOT + gq], od2 = pd2[(size_t)s * L_TOT + gq];
            int   oi1 = pi1[(size_t)s * L_TOT + gq];
            float nd2 = fminf(fminf(d2, od2), fmaxf(d1, od1));
            if (od1 < d1 || (od1 == d1 && oi1 < i1)) { d1 = od1; i1 = oi1; }
            d2 = nd2;
        }
        ws_idx[gq] = i1;
        out_idxf[gq] = (float)i1;
        if (d2 - d1 < TAU) {
            int pos = atomicAdd(flag_cnt, 1);
            flag_list[pos] = gq;
        } else {
            used[i1] = 1.0f;
        }
        sidx[t] = i1;
        float s = d1;
        #pragma unroll
        for (int off = 32; off; off >>= 1) s += __shfl_xor(s, off);
        if (t == 0) d1_part[blockIdx.x] = s;
    }
    __syncthreads();

    int w = t >> 6, lane = t & 63;
    for (int r = 0; r < 16; ++r) {
        int q = r * 4 + w;
        const float4 v = *reinterpret_cast<const float4*>(emb + (size_t)sidx[q] * Dm + lane * 4);
        eldT[lane * 4 + 0][q] = v.x; eldT[lane * 4 + 1][q] = v.y;
        eldT[lane * 4 + 2][q] = v.z; eldT[lane * 4 + 3][q] = v.w;
    }
    __syncthreads();
    const size_t obase = (size_t)b * (Dm * HW) + p0 + lane;
    #pragma unroll 4
    for (int it = 0; it < 64; ++it) {
        int c = w * 64 + it;
        outq[obase + (size_t)c * HW] = eldT[c][lane];
    }
}

// ---------------- fallback fp32 argmin (round-1 proven) ----------------
#define BM 64
#define BN 128
#define BK 64
__global__ __launch_bounds__(256, 2) void k_argmin_f32(
    const float* __restrict__ z, const float* __restrict__ emb,
    const float* __restrict__ enorm, int* __restrict__ ws_idx,
    float* __restrict__ out_idxf, float* __restrict__ used,
    int* __restrict__ flag_cnt, int* __restrict__ flag_list)
{
    __shared__ float zlds[BK][BM];
    __shared__ float el[BK][BN + 4];
    __shared__ float rd1[4][64];
    __shared__ int   ri1[4][64];
    __shared__ float rd2[4][64];

    const int t  = threadIdx.x;
    const int tq = t & 15;
    const int tn = t >> 4;
    const int l0 = blockIdx.x * BM;
    const int b  = l0 >> 10, p0 = l0 & 1023;
    const float* zb = z + (size_t)b * (Dm * HW) + p0;

    float d1[4], d2[4]; int i1[4];
    #pragma unroll
    for (int i = 0; i < 4; ++i) { d1[i] = FLT_MAX; d2[i] = FLT_MAX; i1[i] = 0; }

    for (int nt = 0; nt < NE / BN; ++nt) {
        const int n0 = nt * BN;
        float acc[4][8];
        #pragma unroll
        for (int i = 0; i < 4; ++i)
            #pragma unroll
            for (int j = 0; j < 8; ++j) acc[i][j] = 0.f;

        for (int kc = 0; kc < Dm / BK; ++kc) {
            __syncthreads();
            #pragma unroll
            for (int r = 0; r < 4; ++r) {
                int f = r * 256 + t;
                int kk = f >> 4, q4 = (f & 15) << 2;
                float4 v = *reinterpret_cast<const float4*>(zb + (size_t)(kc * BK + kk) * HW + q4);
                *reinterpret_cast<float4*>(&zlds[kk][q4]) = v;
            }
            #pragma unroll
            for (int r = 0; r < 8; ++r) {
                int f = r * 256 + t;
                int n = f >> 4, k4 = (f & 15) << 2;
                float4 v = *reinterpret_cast<const float4*>(emb + (size_t)(n0 + n) * Dm + kc * BK + k4);
                el[k4 + 0][n] = v.x; el[k4 + 1][n] = v.y;
                el[k4 + 2][n] = v.z; el[k4 + 3][n] = v.w;
            }
            __syncthreads();
            #pragma unroll 4
            for (int kk = 0; kk < BK; ++kk) {
                float4 zf = *reinterpret_cast<const float4*>(&zlds[kk][tq << 2]);
                float4 e0 = *reinterpret_cast<const float4*>(&el[kk][tn << 3]);
                float4 e1 = *reinterpret_cast<const float4*>(&el[kk][(tn << 3) + 4]);
                float zr[4] = { zf.x, zf.y, zf.z, zf.w };
                float er[8] = { e0.x, e0.y, e0.z, e0.w, e1.x, e1.y, e1.z, e1.w };
                #pragma unroll
                for (int i = 0; i < 4; ++i)
                    #pragma unroll
                    for (int j = 0; j < 8; ++j)
                        acc[i][j] = fmaf(zr[i], er[j], acc[i][j]);
            }
        }
        #pragma unroll
        for (int j = 0; j < 8; ++j) {
            int ng = n0 + (tn << 3) + j;
            float en = enorm[ng];
            #pragma unroll
            for (int i = 0; i < 4; ++i) {
                float s = fmaf(-2.f, acc[i][j], en);
                if (s < d1[i]) { d2[i] = d1[i]; d1[i] = s; i1[i] = ng; }
                else if (s < d2[i]) d2[i] = s;
            }
        }
    }
    #pragma unroll
    for (int off = 16; off <= 32; off <<= 1) {
        #pragma unroll
        for (int i = 0; i < 4; ++i) {
            float od1 = __shfl_xor(d1[i], off);
            int   oi1 = __shfl_xor(i1[i], off);
            float od2 = __shfl_xor(d2[i], off);
            float nd2 = fminf(fminf(d2[i], od2), fmaxf(d1[i], od1));
            bool take = (od1 < d1[i]) || (od1 == d1[i] && oi1 < i1[i]);
            if (take) { d1[i] = od1; i1[i] = oi1; }
            d2[i] = nd2;
        }
    }
    int w = t >> 6;
    if ((t & 63) < 16) {
        #pragma unroll
        for (int i = 0; i < 4; ++i) {
            rd1[w][(tq << 2) + i] = d1[i];
            ri1[w][(tq << 2) + i] = i1[i];
            rd2[w][(tq << 2) + i] = d2[i];
        }
    }
    __syncthreads();
    if (t < 64) {
        float bd1 = rd1[0][t]; int bi1 = ri1[0][t]; float bd2 = rd2[0][t];
        #pragma unroll
        for (int ww = 1; ww < 4; ++ww) {
            float od1 = rd1[ww][t]; int oi1 = ri1[ww][t]; float od2 = rd2[ww][t];
            float nd2 = fminf(fminf(bd2, od2), fmaxf(bd1, od1));
            if (od1 < bd1 || (od1 == bd1 && oi1 < bi1)) { bd1 = od1; bi1 = oi1; }
            bd2 = nd2;
        }
        int l = l0 + t;
        ws_idx[l] = bi1;
        out_idxf[l] = (float)bi1;
        if (bd2 - bd1 < TAU) {
            int pos = atomicAdd(flag_cnt, 1);
            flag_list[pos] = l;
        } else {
            used[bi1] = 1.0f;
        }
    }
}

// ---------------- K_refine scan: parallel (query x 256-code chunk) fp64 partial argmin ----------------
__global__ __launch_bounds__(256) void k_refine_scan(
    const float* __restrict__ z, const float* __restrict__ emb,
    const int* __restrict__ flag_cnt, const int* __restrict__ flag_list,
    double* __restrict__ pbd, int* __restrict__ pbi)
{
    __shared__ float zrow[Dm];
    __shared__ double sd[256];
    __shared__ int    si[256];
    const int t = threadIdx.x;
    const int ntask = *flag_cnt * 8;
    for (int task = blockIdx.x; task < ntask; task += gridDim.x) {
        const int fi = task >> 3, chunk = task & 7;
        const int l = flag_list[fi];
        const int b = l >> 10, p = l & 1023;
        const float* zq = z + (size_t)b * (Dm * HW) + p;
        __syncthreads();
        zrow[t] = zq[(size_t)t * HW];
        __syncthreads();
        const int n = chunk * 256 + t;
        const float* er = emb + (size_t)n * Dm;
        double dt0 = 0.0, dt1 = 0.0, dt2 = 0.0, dt3 = 0.0;
        double nm0 = 0.0, nm1 = 0.0, nm2 = 0.0, nm3 = 0.0;
        for (int c = 0; c < Dm; c += 4) {
            double e0 = er[c], e1 = er[c + 1], e2 = er[c + 2], e3 = er[c + 3];
            dt0 += e0 * (double)zrow[c];     nm0 += e0 * e0;
            dt1 += e1 * (double)zrow[c + 1]; nm1 += e1 * e1;
            dt2 += e2 * (double)zrow[c + 2]; nm2 += e2 * e2;
            dt3 += e3 * (double)zrow[c + 3]; nm3 += e3 * e3;
        }
        sd[t] = (nm0 + nm1) + (nm2 + nm3) - 2.0 * ((dt0 + dt1) + (dt2 + dt3));
        si[t] = n;
        __syncthreads();
        for (int st = 128; st; st >>= 1) {
            if (t < st) {
                double od = sd[t + st]; int oi = si[t + st];
                if (od < sd[t] || (od == sd[t] && oi < si[t])) { sd[t] = od; si[t] = oi; }
            }
            __syncthreads();
        }
        if (t == 0) { pbd[task] = sd[0]; pbi[task] = si[0]; }
    }
}

// ---------------- K_refine merge: 8-way lexicographic combine + outputs + outq patch ----------------
__global__ __launch_bounds__(256) void k_refine_merge(
    const float* __restrict__ emb, const int* __restrict__ flag_cnt,
    const int* __restrict__ flag_list, const double* __restrict__ pbd,
    const int* __restrict__ pbi, int* __restrict__ ws_idx,
    float* __restrict__ out_idxf, float* __restrict__ used,
    float* __restrict__ outq)
{
    __shared__ int bestn;
    const int t = threadIdx.x;
    const int nf = *flag_cnt;
    for (int fi = blockIdx.x; fi < nf; fi += gridDim.x) {
        const int l = flag_list[fi];
        __syncthreads();
        if (t == 0) {
            double bd = pbd[fi * 8]; int bi = pbi[fi * 8];
            #pragma unroll
            for (int c = 1; c < 8; ++c) {
                double od = pbd[fi * 8 + c]; int oi = pbi[fi * 8 + c];
                if (od < bd || (od == bd && oi < bi)) { bd = od; bi = oi; }
            }
            ws_idx[l] = bi;
            out_idxf[l] = (float)bi;
            used[bi] = 1.0f;
            bestn = bi;
        }
        __syncthreads();
        const int b = l >> 10, p = l & 1023;
        outq[(size_t)b * (Dm * HW) + (size_t)t * HW + p] = emb[(size_t)bestn * Dm + t];
    }
}

// ---------------- fallback serial refine (r8-proven) ----------------
__global__ void k_refine(const float* __restrict__ z, const float* __restrict__ emb,
                         const int* __restrict__ flag_cnt, const int* __restrict__ flag_list,
                         int* __restrict__ ws_idx, float* __restrict__ out_idxf,
                         float* __restrict__ used, float* __restrict__ outq)
{
    __shared__ float zrow[Dm];
    __shared__ double sd[256];
    __shared__ int    si[256];
    int nf = *flag_cnt;
    for (int fi = blockIdx.x; fi < nf; fi += gridDim.x) {
        int l = flag_list[fi];
        int b = l >> 10, p = l & 1023;
        const float* zq = z + (size_t)b * (Dm * HW) + p;
        __syncthreads();
        for (int c = threadIdx.x; c < Dm; c += blockDim.x) zrow[c] = zq[(size_t)c * HW];
        __syncthreads();
        double bd = DBL_MAX; int bi = 0;
        for (int nb = 0; nb < NE / 256; ++nb) {
            int n = nb * 256 + threadIdx.x;
            const float* er = emb + (size_t)n * Dm;
            double dt0 = 0.0, dt1 = 0.0, dt2 = 0.0, dt3 = 0.0;
            double nm0 = 0.0, nm1 = 0.0, nm2 = 0.0, nm3 = 0.0;
            for (int c = 0; c < Dm; c += 4) {
                double e0 = er[c], e1 = er[c + 1], e2 = er[c + 2], e3 = er[c + 3];
                dt0 += e0 * (double)zrow[c];     nm0 += e0 * e0;
                dt1 += e1 * (double)zrow[c + 1]; nm1 += e1 * e1;
                dt2 += e2 * (double)zrow[c + 2]; nm2 += e2 * e2;
                dt3 += e3 * (double)zrow[c + 3]; nm3 += e3 * e3;
            }
            double s = (nm0 + nm1) + (nm2 + nm3) - 2.0 * ((dt0 + dt1) + (dt2 + dt3));
            if (s < bd) { bd = s; bi = n; }
        }
        sd[threadIdx.x] = bd; si[threadIdx.x] = bi;
        __syncthreads();
        for (int st = 128; st; st >>= 1) {
            if (threadIdx.x < (unsigned)st) {
                double od = sd[threadIdx.x + st]; int oi = si[threadIdx.x + st];
                if (od < sd[threadIdx.x] || (od == sd[threadIdx.x] && oi < si[threadIdx.x])) {
                    sd[threadIdx.x] = od; si[threadIdx.x] = oi;
                }
            }
            __syncthreads();
        }
        if (threadIdx.x == 0) {
            ws_idx[l] = si[0];
            out_idxf[l] = (float)si[0];
            used[si[0]] = 1.0f;
        }
        __syncthreads();
        int bi0 = si[0];
        int c = threadIdx.x;
        outq[(size_t)b * (Dm * HW) + (size_t)c * HW + p] = emb[(size_t)bi0 * Dm + c];
        __syncthreads();
    }
}

// ---------------- fallback gather+loss ----------------
__global__ __launch_bounds__(256) void k_gather_loss(
    const float* __restrict__ z, const float* __restrict__ emb,
    const int* __restrict__ ws_idx, float* __restrict__ outq,
    float* __restrict__ partials)
{
    __shared__ int sidx[64];
    __shared__ float eldT[Dm][65];
    __shared__ float wsum[4];
    const int t = threadIdx.x;
    const int l0 = blockIdx.x * 64;
    const int b = l0 >> 10, p0 = l0 & 1023;
    if (t < 64) sidx[t] = ws_idx[l0 + t];
    __syncthreads();
    int w = t >> 6, lane = t & 63;
    for (int r = 0; r < 16; ++r) {
        int q = r * 4 + w;
        const float4 v = *reinterpret_cast<const float4*>(emb + (size_t)sidx[q] * Dm + lane * 4);
        eldT[lane * 4 + 0][q] = v.x; eldT[lane * 4 + 1][q] = v.y;
        eldT[lane * 4 + 2][q] = v.z; eldT[lane * 4 + 3][q] = v.w;
    }
    __syncthreads();
    float ls = 0.f;
    const size_t obase = (size_t)b * (Dm * HW) + p0 + lane;
    for (int it = 0; it < 64; ++it) {
        int c = w * 64 + it;
        size_t o = obase + (size_t)c * HW;
        float qv = eldT[c][lane];
        float zv = z[o];
        outq[o] = qv;
        float df = qv - zv;
        ls = fmaf(df, df, ls);
    }
    #pragma unroll
    for (int off = 32; off; off >>= 1) ls += __shfl_xor(ls, off);
    if (lane == 0) wsum[w] = ls;
    __syncthreads();
    if (t == 0) partials[blockIdx.x] = wsum[0] + wsum[1] + wsum[2] + wsum[3];
}

// ---------------- final: loss = (Sum||z||^2 + Sum d1)/count, used count ----------------
__global__ void k_final(const float* __restrict__ zn_part, const float* __restrict__ d1_part,
                        int nd1, const float* __restrict__ used,
                        float* __restrict__ out_loss, float* __restrict__ out_used)
{
    __shared__ double s1[256];
    __shared__ float  s2[256];
    int t = threadIdx.x;
    double a = 0.0;
    for (int i = t; i < 1024; i += 256) a += (double)zn_part[i];
    for (int i = t; i < nd1; i += 256) a += (double)d1_part[i];
    float u = 0.f;
    for (int i = t; i < NE; i += 256) u += used[i];
    s1[t] = a; s2[t] = u;
    __syncthreads();
    for (int st = 128; st; st >>= 1) {
        if (t < st) { s1[t] += s1[t + st]; s2[t] += s2[t + st]; }
        __syncthreads();
    }
    if (t == 0) { *out_loss = (float)(s1[0] / 8388608.0); *out_used = s2[0]; }
}

// ---------------- fallback final ----------------
__global__ void k_final_fb(const float* __restrict__ partials, const float* __restrict__ used,
                           float* __restrict__ out_loss, float* __restrict__ out_used)
{
    __shared__ float s1[256], s2[256];
    int t = threadIdx.x;
    float a = partials[t] + partials[t + 256];
    float u = 0.f;
    for (int i = t; i < NE; i += 256) u += used[i];
    s1[t] = a; s2[t] = u;
    __syncthreads();
    for (int st = 128; st; st >>= 1) {
        if (t < st) { s1[t] += s1[t + st]; s2[t] += s2[t + st]; }
        __syncthreads();
    }
    if (t == 0) { *out_loss = s1[0] / 8388608.f; *out_used = s2[0]; }
}

extern "C" void kernel_launch(void* const* d_in, const int* in_sizes, int n_in,
                              void* d_out, int out_size, void* d_ws, size_t ws_size,
                              hipStream_t stream) {
    const float* z   = (const float*)d_in[0];
    const float* emb = (const float*)d_in[1];
    float* out      = (float*)d_out;
    float* outq     = out;
    float* out_loss = out + QOFF;
    float* out_idxf = out + QOFF + 1;
    float* out_used = out + QOFF + 1 + L_TOT;

    float* ws       = (float*)d_ws;
    float* enorm    = ws;                         // [0, 2048)
    float* used     = ws + 2048;                  // [2048, 4096)
    float* zn_part  = ws + 4096;                  // [4096, 5120)
    float* d1_part  = ws + 5120;                  // [5120, 5632)  512
    int*   flag_cnt = (int*)(ws + 5632);          // 1 (+pad)
    int*   ws_idx   = (int*)(ws + 5888);          // 32768
    int*   flag_list= (int*)(ws + 5888 + L_TOT);  // 32768 -> ends 71424

    // 4-stripe partials
    float* pd1w = ws + 71680;                     // 131072
    float* pd2w = ws + 202752;                    // 131072
    int*   pi1w = (int*)(ws + 333824);            // 131072 -> ends 464896 floats

    size_t i8_bytes = 2ull * (NE + L_TOT) * Dm;   // 17825792
    size_t i8_off_f = 464896;                     // byte off 1859584, 16B-aligned
    size_t pbd_off_f = i8_off_f + i8_bytes / 4;   // 8B-aligned byte offset
    size_t pbi_off_f = pbd_off_f + 2 * 262144;
    size_t need_i8 = (pbi_off_f + 262144) * 4;    // ~22.8 MB

    if (ws_size >= need_i8) {
        signed char* e_hi8 = (signed char*)(ws + i8_off_f);
        signed char* e_lo8 = e_hi8 + (size_t)NE * Dm;
        signed char* z_hi8 = e_lo8 + (size_t)NE * Dm;
        signed char* z_lo8 = z_hi8 + (size_t)L_TOT * Dm;
        double* pbd = (double*)(ws + pbd_off_f);
        int*    pbi = (int*)(ws + pbi_off_f);
        k_split_i8<<<1024, 256, 0, stream>>>(z, emb, z_hi8, z_lo8, e_hi8, e_lo8,
                                             enorm, zn_part, used, flag_cnt);
        k_score_i8<<<1024, 256, 0, stream>>>(z_hi8, z_lo8, e_hi8, e_lo8, enorm,
                                             pd1w, pd2w, pi1w);
        k_mg<<<L_TOT / 64, 256, 0, stream>>>(pd1w, pd2w, pi1w, emb, ws_idx, out_idxf,
                                             used, flag_cnt, flag_list, d1_part, outq);
        k_refine_scan<<<2048, 256, 0, stream>>>(z, emb, flag_cnt, flag_list, pbd, pbi);
        k_refine_merge<<<256, 256, 0, stream>>>(emb, flag_cnt, flag_list, pbd, pbi,
                                                ws_idx, out_idxf, used, outq);
        k_final<<<1, 256, 0, stream>>>(zn_part, d1_part, 512, used, out_loss, out_used);
    } else {
        hipMemsetAsync(used, 0, (size_t)3584 * 4, stream);
        k_enorm<<<NE / 4, 256, 0, stream>>>(emb, enorm);
        k_argmin_f32<<<L_TOT / BM, 256, 0, stream>>>(z, emb, enorm, ws_idx, out_idxf, used,
                                                     flag_cnt, flag_list);
        k_refine<<<256, 256, 0, stream>>>(z, emb, flag_cnt, flag_list, ws_idx, out_idxf,
                                          used, outq);
        k_gather_loss<<<L_TOT / 64, 256, 0, stream>>>(z, emb, ws_idx, outq, zn_part);
        k_final_fb<<<1, 256, 0, stream>>>(zn_part, used, out_loss, out_used);
    }
}

// Round 16
// 253.103 us; speedup vs baseline: 1.5763x; 1.5763x over previous
//
#include <hip/hip_runtime.h>
#include <cfloat>

#define Dm 256
#define HW 1024
#define NE 2048
#define L_TOT 32768
#define QOFF 8388608   // B*C*H*W
#define TAU 0.1f

#define QSCALE 4064.0f               // 32512/8
#define CHC 7.93613e-3f              // 2*65536/QSCALE^2
#define CXC 3.10005e-5f              // 2*256/QSCALE^2

typedef __attribute__((ext_vector_type(4))) int i32x4;
typedef const __attribute__((address_space(1))) unsigned int* as1_u32p;
typedef __attribute__((address_space(3))) unsigned int* as3_u32p;

#define GLL(gp, lp) __builtin_amdgcn_global_load_lds((as1_u32p)(gp), (as3_u32p)(lp), 16, 0, 0)

__device__ __forceinline__ void q8(float x, signed char& hi, signed char& lo) {
    int xi = __float2int_rn(x * QSCALE);
    xi = max(-32512, min(32512, xi));
    int h = (xi + 128) >> 8;
    hi = (signed char)h;
    lo = (signed char)(xi - (h << 8));
}

// ---------------- K1 (fallback only): code norms ----------------
__global__ void k_enorm(const float* __restrict__ emb, float* __restrict__ enorm) {
    int w = threadIdx.x >> 6, lane = threadIdx.x & 63;
    int n = blockIdx.x * 4 + w;
    const float4 v = *reinterpret_cast<const float4*>(emb + (size_t)n * Dm + lane * 4);
    double s = (double)v.x * v.x + (double)v.y * v.y + (double)v.z * v.z + (double)v.w * v.w;
    #pragma unroll
    for (int off = 32; off; off >>= 1) s += __shfl_xor(s, off);
    if (lane == 0) enorm[n] = (float)s;
}

// ---------------- fused: i8 split Z (transpose) + split E + norms + ws zeroing ----------------
__global__ __launch_bounds__(256) void k_split_i8(
    const float* __restrict__ z, const float* __restrict__ emb,
    signed char* __restrict__ z_hi, signed char* __restrict__ z_lo,
    signed char* __restrict__ e_hi, signed char* __restrict__ e_lo,
    float* __restrict__ enorm, float* __restrict__ zn_part,
    float* __restrict__ used, int* __restrict__ flag_cnt)
{
    __shared__ signed char zh[32][264];
    __shared__ signed char zl[32][264];
    __shared__ double zsum[4];
    const int t = threadIdx.x;
    const int w = t >> 6, lane = t & 63;

    if (blockIdx.x >= 16 && blockIdx.x < 24) used[(blockIdx.x - 16) * 256 + t] = 0.f;
    if (blockIdx.x == 24 && t == 0) *flag_cnt = 0;

    // fused E-split: waves 0,1 each handle one emb row
    if (w < 2) {
        int n = blockIdx.x * 2 + w;
        const float4 v = *reinterpret_cast<const float4*>(emb + (size_t)n * Dm + lane * 4);
        float vv[4] = { v.x, v.y, v.z, v.w };
        double s = (double)v.x * v.x + (double)v.y * v.y + (double)v.z * v.z + (double)v.w * v.w;
        #pragma unroll
        for (int off = 32; off; off >>= 1) s += __shfl_xor(s, off);
        if (lane == 0) enorm[n] = (float)s;
        signed char h4[4], l4[4];
        #pragma unroll
        for (int j = 0; j < 4; ++j) q8(vv[j], h4[j], l4[j]);
        *reinterpret_cast<int*>(e_hi + (size_t)n * Dm + lane * 4) = *reinterpret_cast<int*>(h4);
        *reinterpret_cast<int*>(e_lo + (size_t)n * Dm + lane * 4) = *reinterpret_cast<int*>(l4);
    }

    // Z split+transpose + ||z||^2 partial
    const int b  = blockIdx.x >> 5;
    const int p0 = (blockIdx.x & 31) * 32;
    const int pp = t & 31, cb = t >> 5;
    const float* zb = z + (size_t)b * (Dm * HW) + p0 + pp;
    float zs = 0.f;
    for (int ci = 0; ci < 32; ++ci) {
        int c = ci * 8 + cb;
        float x = zb[(size_t)c * HW];
        zs = fmaf(x, x, zs);
        q8(x, zh[pp][c], zl[pp][c]);
    }
    double d = zs;
    #pragma unroll
    for (int off = 32; off; off >>= 1) d += __shfl_xor(d, off);
    if ((t & 63) == 0) zsum[w] = d;
    __syncthreads();
    if (t == 0) zn_part[blockIdx.x] = (float)(zsum[0] + zsum[1] + zsum[2] + zsum[3]);
    const int l0 = b * 1024 + p0;
    #pragma unroll
    for (int r = 0; r < 8; ++r) {
        int id = r * 256 + t;
        int row = id >> 6, ch = id & 63;
        *reinterpret_cast<int*>(z_hi + (size_t)(l0 + row) * Dm + ch * 4) =
            *reinterpret_cast<int*>(&zh[row][ch * 4]);
        *reinterpret_cast<int*>(z_lo + (size_t)(l0 + row) * Dm + ch * 4) =
            *reinterpret_cast<int*>(&zl[row][ch * 4]);
    }
}

// ---------------- K2: i8 fixed-point score GEMM + top-2 argmin ----------------
// 4 ni-stripes of 512 codes (grid 1024), 48 steps/block; launch_bounds(256,2)
// so the compiler keeps 128 VGPR (no accumulator spills — r15 lesson). At
// 128 VGPR + 32 KB LDS the HW can still co-schedule 4 blocks/CU; grid 1024
// provides them (4 blocks/CU cover each other's GLL barrier drains).
__global__ __launch_bounds__(256, 2) void k_score_i8(
    const signed char* __restrict__ zh, const signed char* __restrict__ zl,
    const signed char* __restrict__ eh, const signed char* __restrict__ el,
    const float* __restrict__ enorm,
    float* __restrict__ pd1, float* __restrict__ pd2, int* __restrict__ pi1)
{
    __shared__ signed char ldsA[2][8192];
    __shared__ signed char ldsB[2][8192];

    const int t    = threadIdx.x;
    const int lane = t & 63, w = t >> 6;          // w: 0..3
    const int wm = w >> 1, wc = w & 1;
    const int c15 = lane & 15, g4 = lane >> 4;

    // bijective XCD swizzle (1024 wgs)
    const int bx = blockIdx.x;
    const int wg = (bx & 7) * 128 + (bx >> 3);
    const int mi = wg >> 2, ni = wg & 3;
    const int l0 = mi * 128;
    const int nbase = ni * 512;

    const int srow = t & 127;
    const int sc16 = (t >> 7) << 4;               // 0 or 16
    const size_t abase  = (size_t)(l0 + srow) * Dm + sc16;
    const size_t abase2 = abase + 32;
    const size_t bbase  = (size_t)(nbase + srow) * Dm + sc16;
    const size_t bbase2 = bbase + 32;
    const int ld0 = t * 16, ld1 = t * 16 + 4096;

    int offA[4], offB[4];
    #pragma unroll
    for (int m = 0; m < 4; ++m) offA[m] = g4 * 2048 + (wm * 64 + m * 16 + c15) * 16;
    #pragma unroll
    for (int n = 0; n < 4; ++n) offB[n] = g4 * 2048 + (wc * 64 + n * 16 + c15) * 16;

    float d1[4][4], d2[4][4]; int i1[4][4];
    #pragma unroll
    for (int m = 0; m < 4; ++m)
        #pragma unroll
        for (int r = 0; r < 4; ++r) { d1[m][r] = 3.4e38f; d2[m][r] = 3.4e38f; i1[m][r] = 0; }

    GLL(zh + abase,  &ldsA[0][ld0]);
    GLL(zh + abase2, &ldsA[0][ld1]);
    GLL(eh + bbase,  &ldsB[0][ld0]);
    GLL(eh + bbase2, &ldsB[0][ld1]);
    __syncthreads();

    int cur = 0, it = 0;
    int pnt = 0, pkt = 1;
    size_t pntoff = 0;

    auto kstep = [&](i32x4 (&ACC)[4][4]) {
        if (it + 1 < 48) {
            const int term = pkt >> 2;
            const size_t kcf = (size_t)((pkt & 3) << 6);
            const signed char* As = (term == 2) ? zl : zh;
            const signed char* Bs = (term == 1) ? el : eh;
            GLL(As + abase  + kcf,           &ldsA[cur ^ 1][ld0]);
            GLL(As + abase2 + kcf,           &ldsA[cur ^ 1][ld1]);
            GLL(Bs + bbase  + pntoff + kcf,  &ldsB[cur ^ 1][ld0]);
            GLL(Bs + bbase2 + pntoff + kcf,  &ldsB[cur ^ 1][ld1]);
            if (++pkt == 12) { pkt = 0; ++pnt; pntoff = (size_t)pnt << 15; }
        }
        i32x4 af[4], bfv[4];
        #pragma unroll
        for (int m = 0; m < 4; ++m)
            af[m] = *reinterpret_cast<const i32x4*>(&ldsA[cur][offA[m]]);
        #pragma unroll
        for (int n = 0; n < 4; ++n)
            bfv[n] = *reinterpret_cast<const i32x4*>(&ldsB[cur][offB[n]]);
        __builtin_amdgcn_s_setprio(1);
        #pragma unroll
        for (int m = 0; m < 4; ++m)
            #pragma unroll
            for (int n = 0; n < 4; ++n)
                ACC[m][n] = __builtin_amdgcn_mfma_i32_16x16x64_i8(
                    af[m], bfv[n], ACC[m][n], 0, 0, 0);
        __builtin_amdgcn_s_setprio(0);
        __syncthreads();
        cur ^= 1;
        ++it;
    };

    for (int nt = 0; nt < 4; ++nt) {
        i32x4 accH[4][4], accX[4][4];
        #pragma unroll
        for (int m = 0; m < 4; ++m)
            #pragma unroll
            for (int n = 0; n < 4; ++n) {
                accH[m][n] = (i32x4){0, 0, 0, 0};
                accX[m][n] = (i32x4){0, 0, 0, 0};
            }

        #pragma unroll
        for (int k4 = 0; k4 < 4; ++k4) kstep(accH);   // (zh, eh) -> HH
        #pragma unroll
        for (int k4 = 0; k4 < 4; ++k4) kstep(accX);   // (zh, el) -> HL
        #pragma unroll
        for (int k4 = 0; k4 < 4; ++k4) kstep(accX);   // (zl, eh) -> LH

        int n0 = nbase + nt * 128;
        #pragma unroll
        for (int n = 0; n < 4; ++n) {
            int ng = n0 + wc * 64 + n * 16 + c15;
            float en = enorm[ng];
            #pragma unroll
            for (int m = 0; m < 4; ++m)
                #pragma unroll
                for (int r = 0; r < 4; ++r) {
                    float sx = fmaf(-CXC, (float)accX[m][n][r], en);
                    float s  = fmaf(-CHC, (float)accH[m][n][r], sx);
                    if (s < d1[m][r]) { d2[m][r] = d1[m][r]; d1[m][r] = s; i1[m][r] = ng; }
                    else if (s < d2[m][r]) d2[m][r] = s;
                }
        }
    }

    #pragma unroll
    for (int off = 1; off <= 8; off <<= 1) {
        #pragma unroll
        for (int m = 0; m < 4; ++m)
            #pragma unroll
            for (int r = 0; r < 4; ++r) {
                float od1 = __shfl_xor(d1[m][r], off);
                int   oi1 = __shfl_xor(i1[m][r], off);
                float od2 = __shfl_xor(d2[m][r], off);
                float nd2 = fminf(fminf(d2[m][r], od2), fmaxf(d1[m][r], od1));
                if (od1 < d1[m][r] || (od1 == d1[m][r] && oi1 < i1[m][r])) {
                    d1[m][r] = od1; i1[m][r] = oi1;
                }
                d2[m][r] = nd2;
            }
    }

    float* rs1 = (float*)&ldsA[0][0];
    float* rs2 = rs1 + 128;
    int*   ri  = (int*)(rs2 + 128);
    if (wc == 1 && c15 == 0) {
        #pragma unroll
        for (int m = 0; m < 4; ++m)
            #pragma unroll
            for (int r = 0; r < 4; ++r) {
                int q = wm * 64 + m * 16 + g4 * 4 + r;
                rs1[q] = d1[m][r];
                rs2[q] = d2[m][r];
                ri [q] = i1[m][r];
            }
    }
    __syncthreads();
    if (wc == 0 && c15 == 0) {
        #pragma unroll
        for (int m = 0; m < 4; ++m)
            #pragma unroll
            for (int r = 0; r < 4; ++r) {
                int q = wm * 64 + m * 16 + g4 * 4 + r;
                float bd1 = d1[m][r], bd2 = d2[m][r]; int bi1 = i1[m][r];
                float od1 = rs1[q], od2 = rs2[q];
                int   oi1 = ri [q];
                float nd2 = fminf(fminf(bd2, od2), fmaxf(bd1, od1));
                if (od1 < bd1 || (od1 == bd1 && oi1 < bi1)) { bd1 = od1; bi1 = oi1; }
                bd2 = nd2;
                int gq = l0 + q;
                pd1[ni * L_TOT + gq] = bd1;
                pd2[ni * L_TOT + gq] = bd2;
                pi1[ni * L_TOT + gq] = bi1;
            }
    }
}

// ---------------- fused merge (4 stripes) + gather ----------------
__global__ __launch_bounds__(256) void k_mg(
    const float* __restrict__ pd1, const float* __restrict__ pd2,
    const int* __restrict__ pi1, const float* __restrict__ emb,
    int* __restrict__ ws_idx, float* __restrict__ out_idxf,
    float* __restrict__ used, int* __restrict__ flag_cnt,
    int* __restrict__ flag_list, float* __restrict__ d1_part,
    float* __restrict__ outq)
{
    __shared__ int sidx[64];
    __shared__ float eldT[Dm][65];
    const int t = threadIdx.x;
    const int l0 = blockIdx.x * 64;
    const int b = l0 >> 10, p0 = l0 & 1023;

    if (t < 64) {
        int gq = l0 + t;
        float d1 = pd1[gq], d2 = pd2[gq]; int i1 = pi1[gq];
        #pragma unroll
        for (int s = 1; s < 4; ++s) {
            float od1 = pd1[(size_t)s * L_TOT + gq], od2 = pd2[(size_t)s * L_TOT + gq];
            int   oi1 = pi1[(size_t)s * L_TOT + gq];
            float nd2 = fminf(fminf(d2, od2), fmaxf(d1, od1));
            if (od1 < d1 || (od1 == d1 && oi1 < i1)) { d1 = od1; i1 = oi1; }
            d2 = nd2;
        }
        ws_idx[gq] = i1;
        out_idxf[gq] = (float)i1;
        if (d2 - d1 < TAU) {
            int pos = atomicAdd(flag_cnt, 1);
            flag_list[pos] = gq;
        } else {
            used[i1] = 1.0f;
        }
        sidx[t] = i1;
        float s = d1;
        #pragma unroll
        for (int off = 32; off; off >>= 1) s += __shfl_xor(s, off);
        if (t == 0) d1_part[blockIdx.x] = s;
    }
    __syncthreads();

    int w = t >> 6, lane = t & 63;
    for (int r = 0; r < 16; ++r) {
        int q = r * 4 + w;
        const float4 v = *reinterpret_cast<const float4*>(emb + (size_t)sidx[q] * Dm + lane * 4);
        eldT[lane * 4 + 0][q] = v.x; eldT[lane * 4 + 1][q] = v.y;
        eldT[lane * 4 + 2][q] = v.z; eldT[lane * 4 + 3][q] = v.w;
    }
    __syncthreads();
    const size_t obase = (size_t)b * (Dm * HW) + p0 + lane;
    #pragma unroll 4
    for (int it = 0; it < 64; ++it) {
        int c = w * 64 + it;
        outq[obase + (size_t)c * HW] = eldT[c][lane];
    }
}

// ---------------- fallback fp32 argmin (round-1 proven) ----------------
#define BM 64
#define BN 128
#define BK 64
__global__ __launch_bounds__(256, 2) void k_argmin_f32(
    const float* __restrict__ z, const float* __restrict__ emb,
    const float* __restrict__ enorm, int* __restrict__ ws_idx,
    float* __restrict__ out_idxf, float* __restrict__ used,
    int* __restrict__ flag_cnt, int* __restrict__ flag_list)
{
    __shared__ float zlds[BK][BM];
    __shared__ float el[BK][BN + 4];
    __shared__ float rd1[4][64];
    __shared__ int   ri1[4][64];
    __shared__ float rd2[4][64];

    const int t  = threadIdx.x;
    const int tq = t & 15;
    const int tn = t >> 4;
    const int l0 = blockIdx.x * BM;
    const int b  = l0 >> 10, p0 = l0 & 1023;
    const float* zb = z + (size_t)b * (Dm * HW) + p0;

    float d1[4], d2[4]; int i1[4];
    #pragma unroll
    for (int i = 0; i < 4; ++i) { d1[i] = FLT_MAX; d2[i] = FLT_MAX; i1[i] = 0; }

    for (int nt = 0; nt < NE / BN; ++nt) {
        const int n0 = nt * BN;
        float acc[4][8];
        #pragma unroll
        for (int i = 0; i < 4; ++i)
            #pragma unroll
            for (int j = 0; j < 8; ++j) acc[i][j] = 0.f;

        for (int kc = 0; kc < Dm / BK; ++kc) {
            __syncthreads();
            #pragma unroll
            for (int r = 0; r < 4; ++r) {
                int f = r * 256 + t;
                int kk = f >> 4, q4 = (f & 15) << 2;
                float4 v = *reinterpret_cast<const float4*>(zb + (size_t)(kc * BK + kk) * HW + q4);
                *reinterpret_cast<float4*>(&zlds[kk][q4]) = v;
            }
            #pragma unroll
            for (int r = 0; r < 8; ++r) {
                int f = r * 256 + t;
                int n = f >> 4, k4 = (f & 15) << 2;
                float4 v = *reinterpret_cast<const float4*>(emb + (size_t)(n0 + n) * Dm + kc * BK + k4);
                el[k4 + 0][n] = v.x; el[k4 + 1][n] = v.y;
                el[k4 + 2][n] = v.z; el[k4 + 3][n] = v.w;
            }
            __syncthreads();
            #pragma unroll 4
            for (int kk = 0; kk < BK; ++kk) {
                float4 zf = *reinterpret_cast<const float4*>(&zlds[kk][tq << 2]);
                float4 e0 = *reinterpret_cast<const float4*>(&el[kk][tn << 3]);
                float4 e1 = *reinterpret_cast<const float4*>(&el[kk][(tn << 3) + 4]);
                float zr[4] = { zf.x, zf.y, zf.z, zf.w };
                float er[8] = { e0.x, e0.y, e0.z, e0.w, e1.x, e1.y, e1.z, e1.w };
                #pragma unroll
                for (int i = 0; i < 4; ++i)
                    #pragma unroll
                    for (int j = 0; j < 8; ++j)
                        acc[i][j] = fmaf(zr[i], er[j], acc[i][j]);
            }
        }
        #pragma unroll
        for (int j = 0; j < 8; ++j) {
            int ng = n0 + (tn << 3) + j;
            float en = enorm[ng];
            #pragma unroll
            for (int i = 0; i < 4; ++i) {
                float s = fmaf(-2.f, acc[i][j], en);
                if (s < d1[i]) { d2[i] = d1[i]; d1[i] = s; i1[i] = ng; }
                else if (s < d2[i]) d2[i] = s;
            }
        }
    }
    #pragma unroll
    for (int off = 16; off <= 32; off <<= 1) {
        #pragma unroll
        for (int i = 0; i < 4; ++i) {
            float od1 = __shfl_xor(d1[i], off);
            int   oi1 = __shfl_xor(i1[i], off);
            float od2 = __shfl_xor(d2[i], off);
            float nd2 = fminf(fminf(d2[i], od2), fmaxf(d1[i], od1));
            bool take = (od1 < d1[i]) || (od1 == d1[i] && oi1 < i1[i]);
            if (take) { d1[i] = od1; i1[i] = oi1; }
            d2[i] = nd2;
        }
    }
    int w = t >> 6;
    if ((t & 63) < 16) {
        #pragma unroll
        for (int i = 0; i < 4; ++i) {
            rd1[w][(tq << 2) + i] = d1[i];
            ri1[w][(tq << 2) + i] = i1[i];
            rd2[w][(tq << 2) + i] = d2[i];
        }
    }
    __syncthreads();
    if (t < 64) {
        float bd1 = rd1[0][t]; int bi1 = ri1[0][t]; float bd2 = rd2[0][t];
        #pragma unroll
        for (int ww = 1; ww < 4; ++ww) {
            float od1 = rd1[ww][t]; int oi1 = ri1[ww][t]; float od2 = rd2[ww][t];
            float nd2 = fminf(fminf(bd2, od2), fmaxf(bd1, od1));
            if (od1 < bd1 || (od1 == bd1 && oi1 < bi1)) { bd1 = od1; bi1 = oi1; }
            bd2 = nd2;
        }
        int l = l0 + t;
        ws_idx[l] = bi1;
        out_idxf[l] = (float)bi1;
        if (bd2 - bd1 < TAU) {
            int pos = atomicAdd(flag_cnt, 1);
            flag_list[pos] = l;
        } else {
            used[bi1] = 1.0f;
        }
    }
}

// ---------------- K_refine scan: parallel (query x 256-code chunk) fp64 partial argmin ----------------
__global__ __launch_bounds__(256) void k_refine_scan(
    const float* __restrict__ z, const float* __restrict__ emb,
    const int* __restrict__ flag_cnt, const int* __restrict__ flag_list,
    double* __restrict__ pbd, int* __restrict__ pbi)
{
    __shared__ float zrow[Dm];
    __shared__ double sd[256];
    __shared__ int    si[256];
    const int t = threadIdx.x;
    const int ntask = *flag_cnt * 8;
    for (int task = blockIdx.x; task < ntask; task += gridDim.x) {
        const int fi = task >> 3, chunk = task & 7;
        const int l = flag_list[fi];
        const int b = l >> 10, p = l & 1023;
        const float* zq = z + (size_t)b * (Dm * HW) + p;
        __syncthreads();
        zrow[t] = zq[(size_t)t * HW];
        __syncthreads();
        const int n = chunk * 256 + t;
        const float* er = emb + (size_t)n * Dm;
        double dt0 = 0.0, dt1 = 0.0, dt2 = 0.0, dt3 = 0.0;
        double nm0 = 0.0, nm1 = 0.0, nm2 = 0.0, nm3 = 0.0;
        for (int c = 0; c < Dm; c += 4) {
            double e0 = er[c], e1 = er[c + 1], e2 = er[c + 2], e3 = er[c + 3];
            dt0 += e0 * (double)zrow[c];     nm0 += e0 * e0;
            dt1 += e1 * (double)zrow[c + 1]; nm1 += e1 * e1;
            dt2 += e2 * (double)zrow[c + 2]; nm2 += e2 * e2;
            dt3 += e3 * (double)zrow[c + 3]; nm3 += e3 * e3;
        }
        sd[t] = (nm0 + nm1) + (nm2 + nm3) - 2.0 * ((dt0 + dt1) + (dt2 + dt3));
        si[t] = n;
        __syncthreads();
        for (int st = 128; st; st >>= 1) {
            if (t < st) {
                double od = sd[t + st]; int oi = si[t + st];
                if (od < sd[t] || (od == sd[t] && oi < si[t])) { sd[t] = od; si[t] = oi; }
            }
            __syncthreads();
        }
        if (t == 0) { pbd[task] = sd[0]; pbi[task] = si[0]; }
    }
}

// ---------------- K_refine merge: 8-way lexicographic combine + outputs + outq patch ----------------
__global__ __launch_bounds__(256) void k_refine_merge(
    const float* __restrict__ emb, const int* __restrict__ flag_cnt,
    const int* __restrict__ flag_list, const double* __restrict__ pbd,
    const int* __restrict__ pbi, int* __restrict__ ws_idx,
    float* __restrict__ out_idxf, float* __restrict__ used,
    float* __restrict__ outq)
{
    __shared__ int bestn;
    const int t = threadIdx.x;
    const int nf = *flag_cnt;
    for (int fi = blockIdx.x; fi < nf; fi += gridDim.x) {
        const int l = flag_list[fi];
        __syncthreads();
        if (t == 0) {
            double bd = pbd[fi * 8]; int bi = pbi[fi * 8];
            #pragma unroll
            for (int c = 1; c < 8; ++c) {
                double od = pbd[fi * 8 + c]; int oi = pbi[fi * 8 + c];
                if (od < bd || (od == bd && oi < bi)) { bd = od; bi = oi; }
            }
            ws_idx[l] = bi;
            out_idxf[l] = (float)bi;
            used[bi] = 1.0f;
            bestn = bi;
        }
        __syncthreads();
        const int b = l >> 10, p = l & 1023;
        outq[(size_t)b * (Dm * HW) + (size_t)t * HW + p] = emb[(size_t)bestn * Dm + t];
    }
}

// ---------------- fallback serial refine (r8-proven) ----------------
__global__ void k_refine(const float* __restrict__ z, const float* __restrict__ emb,
                         const int* __restrict__ flag_cnt, const int* __restrict__ flag_list,
                         int* __restrict__ ws_idx, float* __restrict__ out_idxf,
                         float* __restrict__ used, float* __restrict__ outq)
{
    __shared__ float zrow[Dm];
    __shared__ double sd[256];
    __shared__ int    si[256];
    int nf = *flag_cnt;
    for (int fi = blockIdx.x; fi < nf; fi += gridDim.x) {
        int l = flag_list[fi];
        int b = l >> 10, p = l & 1023;
        const float* zq = z + (size_t)b * (Dm * HW) + p;
        __syncthreads();
        for (int c = threadIdx.x; c < Dm; c += blockDim.x) zrow[c] = zq[(size_t)c * HW];
        __syncthreads();
        double bd = DBL_MAX; int bi = 0;
        for (int nb = 0; nb < NE / 256; ++nb) {
            int n = nb * 256 + threadIdx.x;
            const float* er = emb + (size_t)n * Dm;
            double dt0 = 0.0, dt1 = 0.0, dt2 = 0.0, dt3 = 0.0;
            double nm0 = 0.0, nm1 = 0.0, nm2 = 0.0, nm3 = 0.0;
            for (int c = 0; c < Dm; c += 4) {
                double e0 = er[c], e1 = er[c + 1], e2 = er[c + 2], e3 = er[c + 3];
                dt0 += e0 * (double)zrow[c];     nm0 += e0 * e0;
                dt1 += e1 * (double)zrow[c + 1]; nm1 += e1 * e1;
                dt2 += e2 * (double)zrow[c + 2]; nm2 += e2 * e2;
                dt3 += e3 * (double)zrow[c + 3]; nm3 += e3 * e3;
            }
            double s = (nm0 + nm1) + (nm2 + nm3) - 2.0 * ((dt0 + dt1) + (dt2 + dt3));
            if (s < bd) { bd = s; bi = n; }
        }
        sd[threadIdx.x] = bd; si[threadIdx.x] = bi;
        __syncthreads();
        for (int st = 128; st; st >>= 1) {
            if (threadIdx.x < (unsigned)st) {
                double od = sd[threadIdx.x + st]; int oi = si[threadIdx.x + st];
                if (od < sd[threadIdx.x] || (od == sd[threadIdx.x] && oi < si[threadIdx.x])) {
                    sd[threadIdx.x] = od; si[threadIdx.x] = oi;
                }
            }
            __syncthreads();
        }
        if (threadIdx.x == 0) {
            ws_idx[l] = si[0];
            out_idxf[l] = (float)si[0];
            used[si[0]] = 1.0f;
        }
        __syncthreads();
        int bi0 = si[0];
        int c = threadIdx.x;
        outq[(size_t)b * (Dm * HW) + (size_t)c * HW + p] = emb[(size_t)bi0 * Dm + c];
        __syncthreads();
    }
}

// ---------------- fallback gather+loss ----------------
__global__ __launch_bounds__(256) void k_gather_loss(
    const float* __restrict__ z, const float* __restrict__ emb,
    const int* __restrict__ ws_idx, float* __restrict__ outq,
    float* __restrict__ partials)
{
    __shared__ int sidx[64];
    __shared__ float eldT[Dm][65];
    __shared__ float wsum[4];
    const int t = threadIdx.x;
    const int l0 = blockIdx.x * 64;
    const int b = l0 >> 10, p0 = l0 & 1023;
    if (t < 64) sidx[t] = ws_idx[l0 + t];
    __syncthreads();
    int w = t >> 6, lane = t & 63;
    for (int r = 0; r < 16; ++r) {
        int q = r * 4 + w;
        const float4 v = *reinterpret_cast<const float4*>(emb + (size_t)sidx[q] * Dm + lane * 4);
        eldT[lane * 4 + 0][q] = v.x; eldT[lane * 4 + 1][q] = v.y;
        eldT[lane * 4 + 2][q] = v.z; eldT[lane * 4 + 3][q] = v.w;
    }
    __syncthreads();
    float ls = 0.f;
    const size_t obase = (size_t)b * (Dm * HW) + p0 + lane;
    for (int it = 0; it < 64; ++it) {
        int c = w * 64 + it;
        size_t o = obase + (size_t)c * HW;
        float qv = eldT[c][lane];
        float zv = z[o];
        outq[o] = qv;
        float df = qv - zv;
        ls = fmaf(df, df, ls);
    }
    #pragma unroll
    for (int off = 32; off; off >>= 1) ls += __shfl_xor(ls, off);
    if (lane == 0) wsum[w] = ls;
    __syncthreads();
    if (t == 0) partials[blockIdx.x] = wsum[0] + wsum[1] + wsum[2] + wsum[3];
}

// ---------------- final: loss = (Sum||z||^2 + Sum d1)/count, used count ----------------
__global__ void k_final(const float* __restrict__ zn_part, const float* __restrict__ d1_part,
                        int nd1, const float* __restrict__ used,
                        float* __restrict__ out_loss, float* __restrict__ out_used)
{
    __shared__ double s1[256];
    __shared__ float  s2[256];
    int t = threadIdx.x;
    double a = 0.0;
    for (int i = t; i < 1024; i += 256) a += (double)zn_part[i];
    for (int i = t; i < nd1; i += 256) a += (double)d1_part[i];
    float u = 0.f;
    for (int i = t; i < NE; i += 256) u += used[i];
    s1[t] = a; s2[t] = u;
    __syncthreads();
    for (int st = 128; st; st >>= 1) {
        if (t < st) { s1[t] += s1[t + st]; s2[t] += s2[t + st]; }
        __syncthreads();
    }
    if (t == 0) { *out_loss = (float)(s1[0] / 8388608.0); *out_used = s2[0]; }
}

// ---------------- fallback final ----------------
__global__ void k_final_fb(const float* __restrict__ partials, const float* __restrict__ used,
                           float* __restrict__ out_loss, float* __restrict__ out_used)
{
    __shared__ float s1[256], s2[256];
    int t = threadIdx.x;
    float a = partials[t] + partials[t + 256];
    float u = 0.f;
    for (int i = t; i < NE; i += 256) u += used[i];
    s1[t] = a; s2[t] = u;
    __syncthreads();
    for (int st = 128; st; st >>= 1) {
        if (t < st) { s1[t] += s1[t + st]; s2[t] += s2[t + st]; }
        __syncthreads();
    }
    if (t == 0) { *out_loss = s1[0] / 8388608.f; *out_used = s2[0]; }
}

extern "C" void kernel_launch(void* const* d_in, const int* in_sizes, int n_in,
                              void* d_out, int out_size, void* d_ws, size_t ws_size,
                              hipStream_t stream) {
    const float* z   = (const float*)d_in[0];
    const float* emb = (const float*)d_in[1];
    float* out      = (float*)d_out;
    float* outq     = out;
    float* out_loss = out + QOFF;
    float* out_idxf = out + QOFF + 1;
    float* out_used = out + QOFF + 1 + L_TOT;

    float* ws       = (float*)d_ws;
    float* enorm    = ws;                         // [0, 2048)
    float* used     = ws + 2048;                  // [2048, 4096)
    float* zn_part  = ws + 4096;                  // [4096, 5120)
    float* d1_part  = ws + 5120;                  // [5120, 5632)  512
    int*   flag_cnt = (int*)(ws + 5632);          // 1 (+pad)
    int*   ws_idx   = (int*)(ws + 5888);          // 32768
    int*   flag_list= (int*)(ws + 5888 + L_TOT);  // 32768 -> ends 71424

    // 4-stripe partials
    float* pd1w = ws + 71680;                     // 131072
    float* pd2w = ws + 202752;                    // 131072
    int*   pi1w = (int*)(ws + 333824);            // 131072 -> ends 464896 floats

    size_t i8_bytes = 2ull * (NE + L_TOT) * Dm;   // 17825792
    size_t i8_off_f = 464896;                     // byte off 1859584, 16B-aligned
    size_t pbd_off_f = i8_off_f + i8_bytes / 4;   // 8B-aligned byte offset
    size_t pbi_off_f = pbd_off_f + 2 * 262144;
    size_t need_i8 = (pbi_off_f + 262144) * 4;    // ~22.8 MB

    if (ws_size >= need_i8) {
        signed char* e_hi8 = (signed char*)(ws + i8_off_f);
        signed char* e_lo8 = e_hi8 + (size_t)NE * Dm;
        signed char* z_hi8 = e_lo8 + (size_t)NE * Dm;
        signed char* z_lo8 = z_hi8 + (size_t)L_TOT * Dm;
        double* pbd = (double*)(ws + pbd_off_f);
        int*    pbi = (int*)(ws + pbi_off_f);
        k_split_i8<<<1024, 256, 0, stream>>>(z, emb, z_hi8, z_lo8, e_hi8, e_lo8,
                                             enorm, zn_part, used, flag_cnt);
        k_score_i8<<<1024, 256, 0, stream>>>(z_hi8, z_lo8, e_hi8, e_lo8, enorm,
                                             pd1w, pd2w, pi1w);
        k_mg<<<L_TOT / 64, 256, 0, stream>>>(pd1w, pd2w, pi1w, emb, ws_idx, out_idxf,
                                             used, flag_cnt, flag_list, d1_part, outq);
        k_refine_scan<<<2048, 256, 0, stream>>>(z, emb, flag_cnt, flag_list, pbd, pbi);
        k_refine_merge<<<256, 256, 0, stream>>>(emb, flag_cnt, flag_list, pbd, pbi,
                                                ws_idx, out_idxf, used, outq);
        k_final<<<1, 256, 0, stream>>>(zn_part, d1_part, 512, used, out_loss, out_used);
    } else {
        hipMemsetAsync(used, 0, (size_t)3584 * 4, stream);
        k_enorm<<<NE / 4, 256, 0, stream>>>(emb, enorm);
        k_argmin_f32<<<L_TOT / BM, 256, 0, stream>>>(z, emb, enorm, ws_idx, out_idxf, used,
                                                     flag_cnt, flag_list);
        k_refine<<<256, 256, 0, stream>>>(z, emb, flag_cnt, flag_list, ws_idx, out_idxf,
                                          used, outq);
        k_gather_loss<<<L_TOT / 64, 256, 0, stream>>>(z, emb, ws_idx, outq, zn_part);
        k_final_fb<<<1, 256, 0, stream>>>(zn_part, used, out_loss, out_used);
    }
}

// Round 17
// 243.099 us; speedup vs baseline: 1.6411x; 1.0411x over previous
//
#include <hip/hip_runtime.h>
#include <cfloat>

#define Dm 256
#define HW 1024
#define NE 2048
#define L_TOT 32768
#define QOFF 8388608   // B*C*H*W
#define TAU 0.1f

#define QSCALE 4064.0f               // 32512/8
#define CHC 7.93613e-3f              // 2*65536/QSCALE^2
#define CXC 3.10005e-5f              // 2*256/QSCALE^2

typedef __attribute__((ext_vector_type(4))) int i32x4;
typedef const __attribute__((address_space(1))) unsigned int* as1_u32p;
typedef __attribute__((address_space(3))) unsigned int* as3_u32p;

#define GLL(gp, lp) __builtin_amdgcn_global_load_lds((as1_u32p)(gp), (as3_u32p)(lp), 16, 0, 0)

__device__ __forceinline__ void q8(float x, signed char& hi, signed char& lo) {
    int xi = __float2int_rn(x * QSCALE);
    xi = max(-32512, min(32512, xi));
    int h = (xi + 128) >> 8;
    hi = (signed char)h;
    lo = (signed char)(xi - (h << 8));
}

// ---------------- K1 (fallback only): code norms ----------------
__global__ void k_enorm(const float* __restrict__ emb, float* __restrict__ enorm) {
    int w = threadIdx.x >> 6, lane = threadIdx.x & 63;
    int n = blockIdx.x * 4 + w;
    const float4 v = *reinterpret_cast<const float4*>(emb + (size_t)n * Dm + lane * 4);
    double s = (double)v.x * v.x + (double)v.y * v.y + (double)v.z * v.z + (double)v.w * v.w;
    #pragma unroll
    for (int off = 32; off; off >>= 1) s += __shfl_xor(s, off);
    if (lane == 0) enorm[n] = (float)s;
}

// ---------------- fused: i8 split Z (transpose) + split E + norms + ws zeroing ----------------
__global__ __launch_bounds__(256) void k_split_i8(
    const float* __restrict__ z, const float* __restrict__ emb,
    signed char* __restrict__ z_hi, signed char* __restrict__ z_lo,
    signed char* __restrict__ e_hi, signed char* __restrict__ e_lo,
    float* __restrict__ enorm, float* __restrict__ zn_part,
    float* __restrict__ used, int* __restrict__ flag_cnt)
{
    __shared__ signed char zh[32][264];
    __shared__ signed char zl[32][264];
    __shared__ double zsum[4];
    const int t = threadIdx.x;
    const int w = t >> 6, lane = t & 63;

    if (blockIdx.x >= 16 && blockIdx.x < 24) used[(blockIdx.x - 16) * 256 + t] = 0.f;
    if (blockIdx.x == 24 && t == 0) *flag_cnt = 0;

    // fused E-split: waves 0,1 each handle one emb row
    if (w < 2) {
        int n = blockIdx.x * 2 + w;
        const float4 v = *reinterpret_cast<const float4*>(emb + (size_t)n * Dm + lane * 4);
        float vv[4] = { v.x, v.y, v.z, v.w };
        double s = (double)v.x * v.x + (double)v.y * v.y + (double)v.z * v.z + (double)v.w * v.w;
        #pragma unroll
        for (int off = 32; off; off >>= 1) s += __shfl_xor(s, off);
        if (lane == 0) enorm[n] = (float)s;
        signed char h4[4], l4[4];
        #pragma unroll
        for (int j = 0; j < 4; ++j) q8(vv[j], h4[j], l4[j]);
        *reinterpret_cast<int*>(e_hi + (size_t)n * Dm + lane * 4) = *reinterpret_cast<int*>(h4);
        *reinterpret_cast<int*>(e_lo + (size_t)n * Dm + lane * 4) = *reinterpret_cast<int*>(l4);
    }

    // Z split+transpose + ||z||^2 partial
    const int b  = blockIdx.x >> 5;
    const int p0 = (blockIdx.x & 31) * 32;
    const int pp = t & 31, cb = t >> 5;
    const float* zb = z + (size_t)b * (Dm * HW) + p0 + pp;
    float zs = 0.f;
    for (int ci = 0; ci < 32; ++ci) {
        int c = ci * 8 + cb;
        float x = zb[(size_t)c * HW];
        zs = fmaf(x, x, zs);
        q8(x, zh[pp][c], zl[pp][c]);
    }
    double d = zs;
    #pragma unroll
    for (int off = 32; off; off >>= 1) d += __shfl_xor(d, off);
    if ((t & 63) == 0) zsum[w] = d;
    __syncthreads();
    if (t == 0) zn_part[blockIdx.x] = (float)(zsum[0] + zsum[1] + zsum[2] + zsum[3]);
    const int l0 = b * 1024 + p0;
    #pragma unroll
    for (int r = 0; r < 8; ++r) {
        int id = r * 256 + t;
        int row = id >> 6, ch = id & 63;
        *reinterpret_cast<int*>(z_hi + (size_t)(l0 + row) * Dm + ch * 4) =
            *reinterpret_cast<int*>(&zh[row][ch * 4]);
        *reinterpret_cast<int*>(z_lo + (size_t)(l0 + row) * Dm + ch * 4) =
            *reinterpret_cast<int*>(&zl[row][ch * 4]);
    }
}

// ---------------- K2: i8 fixed-point score GEMM + top-2 argmin ----------------
// r14 schedule with K-chunk doubled to 128 i8 (2 MFMA sub-iters per barrier):
// halves the number of vmcnt(0)+barrier drains (96 -> 48) at unchanged
// residency (64 KB LDS -> still 2 blocks/CU). grid 512 = 256 mi x 2 ni.
// LDS layout: 16B slot = chunk*128 + row (chunk = 16 i8 of K), linear GLL dest.
// i32 accumulation exact -> scores bit-identical to r14.
__global__ __launch_bounds__(256, 2) void k_score_i8(
    const signed char* __restrict__ zh, const signed char* __restrict__ zl,
    const signed char* __restrict__ eh, const signed char* __restrict__ el,
    const float* __restrict__ enorm,
    float* __restrict__ pd1, float* __restrict__ pd2, int* __restrict__ pi1)
{
    __shared__ signed char ldsA[2][16384];
    __shared__ signed char ldsB[2][16384];

    const int t    = threadIdx.x;
    const int lane = t & 63, w = t >> 6;          // w: 0..3
    const int wm = w >> 1, wc = w & 1;
    const int c15 = lane & 15, g4 = lane >> 4;

    // bijective XCD swizzle (512 wgs)
    const int bx = blockIdx.x;
    const int wg = (bx & 7) * 64 + (bx >> 3);
    const int mi = wg >> 1, ni = wg & 1;
    const int l0 = mi * 128;
    const int nbase = ni * 1024;

    // staging: thread t stages slots t+256r (r=0..3); slot = chunk*128 + row
    const int srow = t & 127;
    const int cb0  = t >> 7;                      // 0 or 1
    unsigned aoffs[4], boffs[4];
    #pragma unroll
    for (int r = 0; r < 4; ++r) {
        aoffs[r] = (unsigned)((l0 + srow) * Dm + (cb0 + 2 * r) * 16);
        boffs[r] = (unsigned)((nbase + srow) * Dm + (cb0 + 2 * r) * 16);
    }
    const int ldd = t * 16;

    // frag read offsets (bytes): chunk (ks*4 + g4), row*16
    int offA[4], offB[4];
    #pragma unroll
    for (int m = 0; m < 4; ++m) offA[m] = g4 * 2048 + (wm * 64 + m * 16 + c15) * 16;
    #pragma unroll
    for (int n = 0; n < 4; ++n) offB[n] = g4 * 2048 + (wc * 64 + n * 16 + c15) * 16;

    float d1[4][4], d2[4][4]; int i1[4][4];
    #pragma unroll
    for (int m = 0; m < 4; ++m)
        #pragma unroll
        for (int r = 0; r < 4; ++r) { d1[m][r] = 3.4e38f; d2[m][r] = 3.4e38f; i1[m][r] = 0; }

    // prologue: stage (nt=0, term=HH, kc=0)
    #pragma unroll
    for (int r = 0; r < 4; ++r) {
        GLL(zh + aoffs[r], &ldsA[0][ldd + r * 4096]);
        GLL(eh + boffs[r], &ldsB[0][ldd + r * 4096]);
    }
    __syncthreads();

    int cur = 0, it = 0;
    int pnt = 0, pkt = 1;       // next chunk: (nt=pnt, seq=pkt); seq: term=pkt>>1, kc=(pkt&1)*128
    unsigned pntoff = 0;

    auto kstep = [&](i32x4 (&ACC)[4][4]) {
        if (it + 1 < 48) {
            const int term = pkt >> 1;
            const unsigned kcf = (unsigned)((pkt & 1) << 7);
            const signed char* As = (term == 2) ? zl : zh;
            const signed char* Bs = (term == 1) ? el : eh;
            #pragma unroll
            for (int r = 0; r < 4; ++r) {
                GLL(As + aoffs[r] + kcf,          &ldsA[cur ^ 1][ldd + r * 4096]);
                GLL(Bs + boffs[r] + pntoff + kcf, &ldsB[cur ^ 1][ldd + r * 4096]);
            }
            if (++pkt == 6) { pkt = 0; ++pnt; pntoff = (unsigned)pnt << 15; }
        }
        #pragma unroll
        for (int ks = 0; ks < 2; ++ks) {
            i32x4 af[4], bfv[4];
            #pragma unroll
            for (int m = 0; m < 4; ++m)
                af[m] = *reinterpret_cast<const i32x4*>(&ldsA[cur][ks * 8192 + offA[m]]);
            #pragma unroll
            for (int n = 0; n < 4; ++n)
                bfv[n] = *reinterpret_cast<const i32x4*>(&ldsB[cur][ks * 8192 + offB[n]]);
            __builtin_amdgcn_s_setprio(1);
            #pragma unroll
            for (int m = 0; m < 4; ++m)
                #pragma unroll
                for (int n = 0; n < 4; ++n)
                    ACC[m][n] = __builtin_amdgcn_mfma_i32_16x16x64_i8(
                        af[m], bfv[n], ACC[m][n], 0, 0, 0);
            __builtin_amdgcn_s_setprio(0);
        }
        __syncthreads();
        cur ^= 1;
        ++it;
    };

    for (int nt = 0; nt < 8; ++nt) {
        i32x4 accH[4][4], accX[4][4];
        #pragma unroll
        for (int m = 0; m < 4; ++m)
            #pragma unroll
            for (int n = 0; n < 4; ++n) {
                accH[m][n] = (i32x4){0, 0, 0, 0};
                accX[m][n] = (i32x4){0, 0, 0, 0};
            }

        kstep(accH); kstep(accH);     // HH: kc 0, 128
        kstep(accX); kstep(accX);     // HL
        kstep(accX); kstep(accX);     // LH

        int n0 = nbase + nt * 128;
        #pragma unroll
        for (int n = 0; n < 4; ++n) {
            int ng = n0 + wc * 64 + n * 16 + c15;
            float en = enorm[ng];
            #pragma unroll
            for (int m = 0; m < 4; ++m)
                #pragma unroll
                for (int r = 0; r < 4; ++r) {
                    float sx = fmaf(-CXC, (float)accX[m][n][r], en);
                    float s  = fmaf(-CHC, (float)accH[m][n][r], sx);
                    if (s < d1[m][r]) { d2[m][r] = d1[m][r]; d1[m][r] = s; i1[m][r] = ng; }
                    else if (s < d2[m][r]) d2[m][r] = s;
                }
        }
    }

    #pragma unroll
    for (int off = 1; off <= 8; off <<= 1) {
        #pragma unroll
        for (int m = 0; m < 4; ++m)
            #pragma unroll
            for (int r = 0; r < 4; ++r) {
                float od1 = __shfl_xor(d1[m][r], off);
                int   oi1 = __shfl_xor(i1[m][r], off);
                float od2 = __shfl_xor(d2[m][r], off);
                float nd2 = fminf(fminf(d2[m][r], od2), fmaxf(d1[m][r], od1));
                if (od1 < d1[m][r] || (od1 == d1[m][r] && oi1 < i1[m][r])) {
                    d1[m][r] = od1; i1[m][r] = oi1;
                }
                d2[m][r] = nd2;
            }
    }

    float* rs1 = (float*)&ldsA[0][0];
    float* rs2 = rs1 + 128;
    int*   ri  = (int*)(rs2 + 128);
    if (wc == 1 && c15 == 0) {
        #pragma unroll
        for (int m = 0; m < 4; ++m)
            #pragma unroll
            for (int r = 0; r < 4; ++r) {
                int q = wm * 64 + m * 16 + g4 * 4 + r;
                rs1[q] = d1[m][r];
                rs2[q] = d2[m][r];
                ri [q] = i1[m][r];
            }
    }
    __syncthreads();
    if (wc == 0 && c15 == 0) {
        #pragma unroll
        for (int m = 0; m < 4; ++m)
            #pragma unroll
            for (int r = 0; r < 4; ++r) {
                int q = wm * 64 + m * 16 + g4 * 4 + r;
                float bd1 = d1[m][r], bd2 = d2[m][r]; int bi1 = i1[m][r];
                float od1 = rs1[q], od2 = rs2[q];
                int   oi1 = ri [q];
                float nd2 = fminf(fminf(bd2, od2), fmaxf(bd1, od1));
                if (od1 < bd1 || (od1 == bd1 && oi1 < bi1)) { bd1 = od1; bi1 = oi1; }
                bd2 = nd2;
                int gq = l0 + q;
                pd1[ni * L_TOT + gq] = bd1;
                pd2[ni * L_TOT + gq] = bd2;
                pi1[ni * L_TOT + gq] = bi1;
            }
    }
}

// ---------------- fused merge (2 stripes) + gather ----------------
__global__ __launch_bounds__(256) void k_mg(
    const float* __restrict__ pd1, const float* __restrict__ pd2,
    const int* __restrict__ pi1, const float* __restrict__ emb,
    int* __restrict__ ws_idx, float* __restrict__ out_idxf,
    float* __restrict__ used, int* __restrict__ flag_cnt,
    int* __restrict__ flag_list, float* __restrict__ d1_part,
    float* __restrict__ outq)
{
    __shared__ int sidx[64];
    __shared__ float eldT[Dm][65];
    const int t = threadIdx.x;
    const int l0 = blockIdx.x * 64;
    const int b = l0 >> 10, p0 = l0 & 1023;

    if (t < 64) {
        int gq = l0 + t;
        float d1 = pd1[gq], d2 = pd2[gq]; int i1 = pi1[gq];
        float od1 = pd1[L_TOT + gq], od2 = pd2[L_TOT + gq];
        int   oi1 = pi1[L_TOT + gq];
        float nd2 = fminf(fminf(d2, od2), fmaxf(d1, od1));
        if (od1 < d1 || (od1 == d1 && oi1 < i1)) { d1 = od1; i1 = oi1; }
        d2 = nd2;
        ws_idx[gq] = i1;
        out_idxf[gq] = (float)i1;
        if (d2 - d1 < TAU) {
            int pos = atomicAdd(flag_cnt, 1);
            flag_list[pos] = gq;
        } else {
            used[i1] = 1.0f;
        }
        sidx[t] = i1;
        float s = d1;
        #pragma unroll
        for (int off = 32; off; off >>= 1) s += __shfl_xor(s, off);
        if (t == 0) d1_part[blockIdx.x] = s;
    }
    __syncthreads();

    int w = t >> 6, lane = t & 63;
    for (int r = 0; r < 16; ++r) {
        int q = r * 4 + w;
        const float4 v = *reinterpret_cast<const float4*>(emb + (size_t)sidx[q] * Dm + lane * 4);
        eldT[lane * 4 + 0][q] = v.x; eldT[lane * 4 + 1][q] = v.y;
        eldT[lane * 4 + 2][q] = v.z; eldT[lane * 4 + 3][q] = v.w;
    }
    __syncthreads();
    const size_t obase = (size_t)b * (Dm * HW) + p0 + lane;
    #pragma unroll 4
    for (int it = 0; it < 64; ++it) {
        int c = w * 64 + it;
        outq[obase + (size_t)c * HW] = eldT[c][lane];
    }
}

// ---------------- fallback fp32 argmin (round-1 proven) ----------------
#define BM 64
#define BN 128
#define BK 64
__global__ __launch_bounds__(256, 2) void k_argmin_f32(
    const float* __restrict__ z, const float* __restrict__ emb,
    const float* __restrict__ enorm, int* __restrict__ ws_idx,
    float* __restrict__ out_idxf, float* __restrict__ used,
    int* __restrict__ flag_cnt, int* __restrict__ flag_list)
{
    __shared__ float zlds[BK][BM];
    __shared__ float el[BK][BN + 4];
    __shared__ float rd1[4][64];
    __shared__ int   ri1[4][64];
    __shared__ float rd2[4][64];

    const int t  = threadIdx.x;
    const int tq = t & 15;
    const int tn = t >> 4;
    const int l0 = blockIdx.x * BM;
    const int b  = l0 >> 10, p0 = l0 & 1023;
    const float* zb = z + (size_t)b * (Dm * HW) + p0;

    float d1[4], d2[4]; int i1[4];
    #pragma unroll
    for (int i = 0; i < 4; ++i) { d1[i] = FLT_MAX; d2[i] = FLT_MAX; i1[i] = 0; }

    for (int nt = 0; nt < NE / BN; ++nt) {
        const int n0 = nt * BN;
        float acc[4][8];
        #pragma unroll
        for (int i = 0; i < 4; ++i)
            #pragma unroll
            for (int j = 0; j < 8; ++j) acc[i][j] = 0.f;

        for (int kc = 0; kc < Dm / BK; ++kc) {
            __syncthreads();
            #pragma unroll
            for (int r = 0; r < 4; ++r) {
                int f = r * 256 + t;
                int kk = f >> 4, q4 = (f & 15) << 2;
                float4 v = *reinterpret_cast<const float4*>(zb + (size_t)(kc * BK + kk) * HW + q4);
                *reinterpret_cast<float4*>(&zlds[kk][q4]) = v;
            }
            #pragma unroll
            for (int r = 0; r < 8; ++r) {
                int f = r * 256 + t;
                int n = f >> 4, k4 = (f & 15) << 2;
                float4 v = *reinterpret_cast<const float4*>(emb + (size_t)(n0 + n) * Dm + kc * BK + k4);
                el[k4 + 0][n] = v.x; el[k4 + 1][n] = v.y;
                el[k4 + 2][n] = v.z; el[k4 + 3][n] = v.w;
            }
            __syncthreads();
            #pragma unroll 4
            for (int kk = 0; kk < BK; ++kk) {
                float4 zf = *reinterpret_cast<const float4*>(&zlds[kk][tq << 2]);
                float4 e0 = *reinterpret_cast<const float4*>(&el[kk][tn << 3]);
                float4 e1 = *reinterpret_cast<const float4*>(&el[kk][(tn << 3) + 4]);
                float zr[4] = { zf.x, zf.y, zf.z, zf.w };
                float er[8] = { e0.x, e0.y, e0.z, e0.w, e1.x, e1.y, e1.z, e1.w };
                #pragma unroll
                for (int i = 0; i < 4; ++i)
                    #pragma unroll
                    for (int j = 0; j < 8; ++j)
                        acc[i][j] = fmaf(zr[i], er[j], acc[i][j]);
            }
        }
        #pragma unroll
        for (int j = 0; j < 8; ++j) {
            int ng = n0 + (tn << 3) + j;
            float en = enorm[ng];
            #pragma unroll
            for (int i = 0; i < 4; ++i) {
                float s = fmaf(-2.f, acc[i][j], en);
                if (s < d1[i]) { d2[i] = d1[i]; d1[i] = s; i1[i] = ng; }
                else if (s < d2[i]) d2[i] = s;
            }
        }
    }
    #pragma unroll
    for (int off = 16; off <= 32; off <<= 1) {
        #pragma unroll
        for (int i = 0; i < 4; ++i) {
            float od1 = __shfl_xor(d1[i], off);
            int   oi1 = __shfl_xor(i1[i], off);
            float od2 = __shfl_xor(d2[i], off);
            float nd2 = fminf(fminf(d2[i], od2), fmaxf(d1[i], od1));
            bool take = (od1 < d1[i]) || (od1 == d1[i] && oi1 < i1[i]);
            if (take) { d1[i] = od1; i1[i] = oi1; }
            d2[i] = nd2;
        }
    }
    int w = t >> 6;
    if ((t & 63) < 16) {
        #pragma unroll
        for (int i = 0; i < 4; ++i) {
            rd1[w][(tq << 2) + i] = d1[i];
            ri1[w][(tq << 2) + i] = i1[i];
            rd2[w][(tq << 2) + i] = d2[i];
        }
    }
    __syncthreads();
    if (t < 64) {
        float bd1 = rd1[0][t]; int bi1 = ri1[0][t]; float bd2 = rd2[0][t];
        #pragma unroll
        for (int ww = 1; ww < 4; ++ww) {
            float od1 = rd1[ww][t]; int oi1 = ri1[ww][t]; float od2 = rd2[ww][t];
            float nd2 = fminf(fminf(bd2, od2), fmaxf(bd1, od1));
            if (od1 < bd1 || (od1 == bd1 && oi1 < bi1)) { bd1 = od1; bi1 = oi1; }
            bd2 = nd2;
        }
        int l = l0 + t;
        ws_idx[l] = bi1;
        out_idxf[l] = (float)bi1;
        if (bd2 - bd1 < TAU) {
            int pos = atomicAdd(flag_cnt, 1);
            flag_list[pos] = l;
        } else {
            used[bi1] = 1.0f;
        }
    }
}

// ---------------- K_refine scan: parallel (query x 256-code chunk) fp64 partial argmin ----------------
__global__ __launch_bounds__(256) void k_refine_scan(
    const float* __restrict__ z, const float* __restrict__ emb,
    const int* __restrict__ flag_cnt, const int* __restrict__ flag_list,
    double* __restrict__ pbd, int* __restrict__ pbi)
{
    __shared__ float zrow[Dm];
    __shared__ double sd[256];
    __shared__ int    si[256];
    const int t = threadIdx.x;
    const int ntask = *flag_cnt * 8;
    for (int task = blockIdx.x; task < ntask; task += gridDim.x) {
        const int fi = task >> 3, chunk = task & 7;
        const int l = flag_list[fi];
        const int b = l >> 10, p = l & 1023;
        const float* zq = z + (size_t)b * (Dm * HW) + p;
        __syncthreads();
        zrow[t] = zq[(size_t)t * HW];
        __syncthreads();
        const int n = chunk * 256 + t;
        const float* er = emb + (size_t)n * Dm;
        double dt0 = 0.0, dt1 = 0.0, dt2 = 0.0, dt3 = 0.0;
        double nm0 = 0.0, nm1 = 0.0, nm2 = 0.0, nm3 = 0.0;
        for (int c = 0; c < Dm; c += 4) {
            double e0 = er[c], e1 = er[c + 1], e2 = er[c + 2], e3 = er[c + 3];
            dt0 += e0 * (double)zrow[c];     nm0 += e0 * e0;
            dt1 += e1 * (double)zrow[c + 1]; nm1 += e1 * e1;
            dt2 += e2 * (double)zrow[c + 2]; nm2 += e2 * e2;
            dt3 += e3 * (double)zrow[c + 3]; nm3 += e3 * e3;
        }
        sd[t] = (nm0 + nm1) + (nm2 + nm3) - 2.0 * ((dt0 + dt1) + (dt2 + dt3));
        si[t] = n;
        __syncthreads();
        for (int st = 128; st; st >>= 1) {
            if (t < st) {
                double od = sd[t + st]; int oi = si[t + st];
                if (od < sd[t] || (od == sd[t] && oi < si[t])) { sd[t] = od; si[t] = oi; }
            }
            __syncthreads();
        }
        if (t == 0) { pbd[task] = sd[0]; pbi[task] = si[0]; }
    }
}

// ---------------- K_refine merge: 8-way lexicographic combine + outputs + outq patch ----------------
__global__ __launch_bounds__(256) void k_refine_merge(
    const float* __restrict__ emb, const int* __restrict__ flag_cnt,
    const int* __restrict__ flag_list, const double* __restrict__ pbd,
    const int* __restrict__ pbi, int* __restrict__ ws_idx,
    float* __restrict__ out_idxf, float* __restrict__ used,
    float* __restrict__ outq)
{
    __shared__ int bestn;
    const int t = threadIdx.x;
    const int nf = *flag_cnt;
    for (int fi = blockIdx.x; fi < nf; fi += gridDim.x) {
        const int l = flag_list[fi];
        __syncthreads();
        if (t == 0) {
            double bd = pbd[fi * 8]; int bi = pbi[fi * 8];
            #pragma unroll
            for (int c = 1; c < 8; ++c) {
                double od = pbd[fi * 8 + c]; int oi = pbi[fi * 8 + c];
                if (od < bd || (od == bd && oi < bi)) { bd = od; bi = oi; }
            }
            ws_idx[l] = bi;
            out_idxf[l] = (float)bi;
            used[bi] = 1.0f;
            bestn = bi;
        }
        __syncthreads();
        const int b = l >> 10, p = l & 1023;
        outq[(size_t)b * (Dm * HW) + (size_t)t * HW + p] = emb[(size_t)bestn * Dm + t];
    }
}

// ---------------- fallback serial refine (r8-proven) ----------------
__global__ void k_refine(const float* __restrict__ z, const float* __restrict__ emb,
                         const int* __restrict__ flag_cnt, const int* __restrict__ flag_list,
                         int* __restrict__ ws_idx, float* __restrict__ out_idxf,
                         float* __restrict__ used, float* __restrict__ outq)
{
    __shared__ float zrow[Dm];
    __shared__ double sd[256];
    __shared__ int    si[256];
    int nf = *flag_cnt;
    for (int fi = blockIdx.x; fi < nf; fi += gridDim.x) {
        int l = flag_list[fi];
        int b = l >> 10, p = l & 1023;
        const float* zq = z + (size_t)b * (Dm * HW) + p;
        __syncthreads();
        for (int c = threadIdx.x; c < Dm; c += blockDim.x) zrow[c] = zq[(size_t)c * HW];
        __syncthreads();
        double bd = DBL_MAX; int bi = 0;
        for (int nb = 0; nb < NE / 256; ++nb) {
            int n = nb * 256 + threadIdx.x;
            const float* er = emb + (size_t)n * Dm;
            double dt0 = 0.0, dt1 = 0.0, dt2 = 0.0, dt3 = 0.0;
            double nm0 = 0.0, nm1 = 0.0, nm2 = 0.0, nm3 = 0.0;
            for (int c = 0; c < Dm; c += 4) {
                double e0 = er[c], e1 = er[c + 1], e2 = er[c + 2], e3 = er[c + 3];
                dt0 += e0 * (double)zrow[c];     nm0 += e0 * e0;
                dt1 += e1 * (double)zrow[c + 1]; nm1 += e1 * e1;
                dt2 += e2 * (double)zrow[c + 2]; nm2 += e2 * e2;
                dt3 += e3 * (double)zrow[c + 3]; nm3 += e3 * e3;
            }
            double s = (nm0 + nm1) + (nm2 + nm3) - 2.0 * ((dt0 + dt1) + (dt2 + dt3));
            if (s < bd) { bd = s; bi = n; }
        }
        sd[threadIdx.x] = bd; si[threadIdx.x] = bi;
        __syncthreads();
        for (int st = 128; st; st >>= 1) {
            if (threadIdx.x < (unsigned)st) {
                double od = sd[threadIdx.x + st]; int oi = si[threadIdx.x + st];
                if (od < sd[threadIdx.x] || (od == sd[threadIdx.x] && oi < si[threadIdx.x])) {
                    sd[threadIdx.x] = od; si[threadIdx.x] = oi;
                }
            }
            __syncthreads();
        }
        if (threadIdx.x == 0) {
            ws_idx[l] = si[0];
            out_idxf[l] = (float)si[0];
            used[si[0]] = 1.0f;
        }
        __syncthreads();
        int bi0 = si[0];
        int c = threadIdx.x;
        outq[(size_t)b * (Dm * HW) + (size_t)c * HW + p] = emb[(size_t)bi0 * Dm + c];
        __syncthreads();
    }
}

// ---------------- fallback gather+loss ----------------
__global__ __launch_bounds__(256) void k_gather_loss(
    const float* __restrict__ z, const float* __restrict__ emb,
    const int* __restrict__ ws_idx, float* __restrict__ outq,
    float* __restrict__ partials)
{
    __shared__ int sidx[64];
    __shared__ float eldT[Dm][65];
    __shared__ float wsum[4];
    const int t = threadIdx.x;
    const int l0 = blockIdx.x * 64;
    const int b = l0 >> 10, p0 = l0 & 1023;
    if (t < 64) sidx[t] = ws_idx[l0 + t];
    __syncthreads();
    int w = t >> 6, lane = t & 63;
    for (int r = 0; r < 16; ++r) {
        int q = r * 4 + w;
        const float4 v = *reinterpret_cast<const float4*>(emb + (size_t)sidx[q] * Dm + lane * 4);
        eldT[lane * 4 + 0][q] = v.x; eldT[lane * 4 + 1][q] = v.y;
        eldT[lane * 4 + 2][q] = v.z; eldT[lane * 4 + 3][q] = v.w;
    }
    __syncthreads();
    float ls = 0.f;
    const size_t obase = (size_t)b * (Dm * HW) + p0 + lane;
    for (int it = 0; it < 64; ++it) {
        int c = w * 64 + it;
        size_t o = obase + (size_t)c * HW;
        float qv = eldT[c][lane];
        float zv = z[o];
        outq[o] = qv;
        float df = qv - zv;
        ls = fmaf(df, df, ls);
    }
    #pragma unroll
    for (int off = 32; off; off >>= 1) ls += __shfl_xor(ls, off);
    if (lane == 0) wsum[w] = ls;
    __syncthreads();
    if (t == 0) partials[blockIdx.x] = wsum[0] + wsum[1] + wsum[2] + wsum[3];
}

// ---------------- final: loss = (Sum||z||^2 + Sum d1)/count, used count ----------------
__global__ void k_final(const float* __restrict__ zn_part, const float* __restrict__ d1_part,
                        int nd1, const float* __restrict__ used,
                        float* __restrict__ out_loss, float* __restrict__ out_used)
{
    __shared__ double s1[256];
    __shared__ float  s2[256];
    int t = threadIdx.x;
    double a = 0.0;
    for (int i = t; i < 1024; i += 256) a += (double)zn_part[i];
    for (int i = t; i < nd1; i += 256) a += (double)d1_part[i];
    float u = 0.f;
    for (int i = t; i < NE; i += 256) u += used[i];
    s1[t] = a; s2[t] = u;
    __syncthreads();
    for (int st = 128; st; st >>= 1) {
        if (t < st) { s1[t] += s1[t + st]; s2[t] += s2[t + st]; }
        __syncthreads();
    }
    if (t == 0) { *out_loss = (float)(s1[0] / 8388608.0); *out_used = s2[0]; }
}

// ---------------- fallback final ----------------
__global__ void k_final_fb(const float* __restrict__ partials, const float* __restrict__ used,
                           float* __restrict__ out_loss, float* __restrict__ out_used)
{
    __shared__ float s1[256], s2[256];
    int t = threadIdx.x;
    float a = partials[t] + partials[t + 256];
    float u = 0.f;
    for (int i = t; i < NE; i += 256) u += used[i];
    s1[t] = a; s2[t] = u;
    __syncthreads();
    for (int st = 128; st; st >>= 1) {
        if (t < st) { s1[t] += s1[t + st]; s2[t] += s2[t + st]; }
        __syncthreads();
    }
    if (t == 0) { *out_loss = s1[0] / 8388608.f; *out_used = s2[0]; }
}

extern "C" void kernel_launch(void* const* d_in, const int* in_sizes, int n_in,
                              void* d_out, int out_size, void* d_ws, size_t ws_size,
                              hipStream_t stream) {
    const float* z   = (const float*)d_in[0];
    const float* emb = (const float*)d_in[1];
    float* out      = (float*)d_out;
    float* outq     = out;
    float* out_loss = out + QOFF;
    float* out_idxf = out + QOFF + 1;
    float* out_used = out + QOFF + 1 + L_TOT;

    float* ws       = (float*)d_ws;
    float* enorm    = ws;                         // [0, 2048)
    float* used     = ws + 2048;                  // [2048, 4096)
    float* zn_part  = ws + 4096;                  // [4096, 5120)
    float* d1_part  = ws + 5120;                  // [5120, 5632)  512
    int*   flag_cnt = (int*)(ws + 5632);          // 1 (+pad)
    int*   ws_idx   = (int*)(ws + 5888);          // 32768
    int*   flag_list= (int*)(ws + 5888 + L_TOT);  // 32768 -> ends 71424

    // 2-stripe partials
    float* pd1w = ws + 71680;                     // 65536
    float* pd2w = ws + 137216;                    // 65536
    int*   pi1w = (int*)(ws + 202752);            // 65536 -> ends 268288 floats

    size_t i8_bytes = 2ull * (NE + L_TOT) * Dm;   // 17825792
    size_t pbd_off_f = 268288 + i8_bytes / 4;     // 8B-aligned byte offset
    size_t pbi_off_f = pbd_off_f + 2 * 262144;
    size_t need_i8 = (pbi_off_f + 262144) * 4;    // ~22.1 MB

    if (ws_size >= need_i8) {
        signed char* e_hi8 = (signed char*)(ws + 268288);
        signed char* e_lo8 = e_hi8 + (size_t)NE * Dm;
        signed char* z_hi8 = e_lo8 + (size_t)NE * Dm;
        signed char* z_lo8 = z_hi8 + (size_t)L_TOT * Dm;
        double* pbd = (double*)(ws + pbd_off_f);
        int*    pbi = (int*)(ws + pbi_off_f);
        k_split_i8<<<1024, 256, 0, stream>>>(z, emb, z_hi8, z_lo8, e_hi8, e_lo8,
                                             enorm, zn_part, used, flag_cnt);
        k_score_i8<<<512, 256, 0, stream>>>(z_hi8, z_lo8, e_hi8, e_lo8, enorm,
                                            pd1w, pd2w, pi1w);
        k_mg<<<L_TOT / 64, 256, 0, stream>>>(pd1w, pd2w, pi1w, emb, ws_idx, out_idxf,
                                             used, flag_cnt, flag_list, d1_part, outq);
        k_refine_scan<<<2048, 256, 0, stream>>>(z, emb, flag_cnt, flag_list, pbd, pbi);
        k_refine_merge<<<256, 256, 0, stream>>>(emb, flag_cnt, flag_list, pbd, pbi,
                                                ws_idx, out_idxf, used, outq);
        k_final<<<1, 256, 0, stream>>>(zn_part, d1_part, 512, used, out_loss, out_used);
    } else {
        hipMemsetAsync(used, 0, (size_t)3584 * 4, stream);
        k_enorm<<<NE / 4, 256, 0, stream>>>(emb, enorm);
        k_argmin_f32<<<L_TOT / BM, 256, 0, stream>>>(z, emb, enorm, ws_idx, out_idxf, used,
                                                     flag_cnt, flag_list);
        k_refine<<<256, 256, 0, stream>>>(z, emb, flag_cnt, flag_list, ws_idx, out_idxf,
                                          used, outq);
        k_gather_loss<<<L_TOT / 64, 256, 0, stream>>>(z, emb, ws_idx, outq, zn_part);
        k_final_fb<<<1, 256, 0, stream>>>(zn_part, used, out_loss, out_used);
    }
}

// Round 18
// 216.734 us; speedup vs baseline: 1.8408x; 1.1216x over previous
//
#include <hip/hip_runtime.h>
#include <cfloat>

#define Dm 256
#define HW 1024
#define NE 2048
#define L_TOT 32768
#define QOFF 8388608   // B*C*H*W
#define TAU 0.1f

#define QSCALE 4064.0f               // 32512/8
#define CHC 7.93613e-3f              // 2*65536/QSCALE^2
#define CXC 3.10005e-5f              // 2*256/QSCALE^2

typedef __attribute__((ext_vector_type(4))) int i32x4;
typedef const __attribute__((address_space(1))) unsigned int* as1_u32p;
typedef __attribute__((address_space(3))) unsigned int* as3_u32p;

#define GLL(gp, lp) __builtin_amdgcn_global_load_lds((as1_u32p)(gp), (as3_u32p)(lp), 16, 0, 0)

__device__ __forceinline__ void q8(float x, signed char& hi, signed char& lo) {
    int xi = __float2int_rn(x * QSCALE);
    xi = max(-32512, min(32512, xi));
    int h = (xi + 128) >> 8;
    hi = (signed char)h;
    lo = (signed char)(xi - (h << 8));
}

// ---------------- K1 (fallback only): code norms ----------------
__global__ void k_enorm(const float* __restrict__ emb, float* __restrict__ enorm) {
    int w = threadIdx.x >> 6, lane = threadIdx.x & 63;
    int n = blockIdx.x * 4 + w;
    const float4 v = *reinterpret_cast<const float4*>(emb + (size_t)n * Dm + lane * 4);
    double s = (double)v.x * v.x + (double)v.y * v.y + (double)v.z * v.z + (double)v.w * v.w;
    #pragma unroll
    for (int off = 32; off; off >>= 1) s += __shfl_xor(s, off);
    if (lane == 0) enorm[n] = (float)s;
}

// ---------------- fused: i8 split Z (transpose) + split E + norms + ws zeroing ----------------
__global__ __launch_bounds__(256) void k_split_i8(
    const float* __restrict__ z, const float* __restrict__ emb,
    signed char* __restrict__ z_hi, signed char* __restrict__ z_lo,
    signed char* __restrict__ e_hi, signed char* __restrict__ e_lo,
    float* __restrict__ enorm, float* __restrict__ zn_part,
    float* __restrict__ used, int* __restrict__ flag_cnt)
{
    __shared__ signed char zh[32][264];
    __shared__ signed char zl[32][264];
    __shared__ double zsum[4];
    const int t = threadIdx.x;
    const int w = t >> 6, lane = t & 63;

    if (blockIdx.x >= 16 && blockIdx.x < 24) used[(blockIdx.x - 16) * 256 + t] = 0.f;
    if (blockIdx.x == 24 && t == 0) *flag_cnt = 0;

    // fused E-split: waves 0,1 each handle one emb row
    if (w < 2) {
        int n = blockIdx.x * 2 + w;
        const float4 v = *reinterpret_cast<const float4*>(emb + (size_t)n * Dm + lane * 4);
        float vv[4] = { v.x, v.y, v.z, v.w };
        double s = (double)v.x * v.x + (double)v.y * v.y + (double)v.z * v.z + (double)v.w * v.w;
        #pragma unroll
        for (int off = 32; off; off >>= 1) s += __shfl_xor(s, off);
        if (lane == 0) enorm[n] = (float)s;
        signed char h4[4], l4[4];
        #pragma unroll
        for (int j = 0; j < 4; ++j) q8(vv[j], h4[j], l4[j]);
        *reinterpret_cast<int*>(e_hi + (size_t)n * Dm + lane * 4) = *reinterpret_cast<int*>(h4);
        *reinterpret_cast<int*>(e_lo + (size_t)n * Dm + lane * 4) = *reinterpret_cast<int*>(l4);
    }

    // Z split+transpose + ||z||^2 partial
    const int b  = blockIdx.x >> 5;
    const int p0 = (blockIdx.x & 31) * 32;
    const int pp = t & 31, cb = t >> 5;
    const float* zb = z + (size_t)b * (Dm * HW) + p0 + pp;
    float zs = 0.f;
    for (int ci = 0; ci < 32; ++ci) {
        int c = ci * 8 + cb;
        float x = zb[(size_t)c * HW];
        zs = fmaf(x, x, zs);
        q8(x, zh[pp][c], zl[pp][c]);
    }
    double d = zs;
    #pragma unroll
    for (int off = 32; off; off >>= 1) d += __shfl_xor(d, off);
    if ((t & 63) == 0) zsum[w] = d;
    __syncthreads();
    if (t == 0) zn_part[blockIdx.x] = (float)(zsum[0] + zsum[1] + zsum[2] + zsum[3]);
    const int l0 = b * 1024 + p0;
    #pragma unroll
    for (int r = 0; r < 8; ++r) {
        int id = r * 256 + t;
        int row = id >> 6, ch = id & 63;
        *reinterpret_cast<int*>(z_hi + (size_t)(l0 + row) * Dm + ch * 4) =
            *reinterpret_cast<int*>(&zh[row][ch * 4]);
        *reinterpret_cast<int*>(z_lo + (size_t)(l0 + row) * Dm + ch * 4) =
            *reinterpret_cast<int*>(&zl[row][ch * 4]);
    }
}

// ---------------- K2: i8 score GEMM, A-resident LDS (unique-byte staging) ----------------
// A tile (zh+zl, 128 rows x K=256 = 64 KB) staged ONCE; per nt only unique B
// bytes staged (8 chunks of 8 KB: eh kc0..3, el kc0..3, double-buffered).
// eh chunks feed BOTH accH (zh x eh) and accX (zl x eh) -> LH costs no staging.
// GLL/thread: 384 -> 142. LDS 80 KB -> 2 blocks/CU unchanged. i32 exact ->
// scores bit-identical to r17. grid 512 = 256 mi x 2 ni.
__global__ __launch_bounds__(256, 2) void k_score_i8(
    const signed char* __restrict__ zh, const signed char* __restrict__ zl,
    const signed char* __restrict__ eh, const signed char* __restrict__ el,
    const float* __restrict__ enorm,
    float* __restrict__ pd1, float* __restrict__ pd2, int* __restrict__ pi1)
{
    __shared__ signed char ldsA[65536];    // 8 regions (arr2 x kc4) of 8 KB
    __shared__ signed char ldsB[2][8192];  // double-buffered B chunk (K=64)

    const int t    = threadIdx.x;
    const int lane = t & 63, w = t >> 6;          // w: 0..3
    const int wm = w >> 1, wc = w & 1;
    const int c15 = lane & 15, g4 = lane >> 4;

    // bijective XCD swizzle (512 wgs)
    const int bx = blockIdx.x;
    const int wg = (bx & 7) * 64 + (bx >> 3);
    const int mi = wg >> 1, ni = wg & 1;
    const int l0 = mi * 128;
    const int nbase = ni * 1024;

    const int srow = t & 127;
    const int sc16 = t >> 7;                      // 0 or 1
    const unsigned abase = (unsigned)((l0 + srow) * Dm);
    const unsigned bbase = (unsigned)((nbase + srow) * Dm);
    const int ldd = t * 16;

    // ---- A prologue: 8 regions x 2 rounds = 16 GLL/thread ----
    #pragma unroll
    for (int arr = 0; arr < 2; ++arr) {
        const signed char* As = arr ? zl : zh;
        #pragma unroll
        for (int kc = 0; kc < 4; ++kc) {
            #pragma unroll
            for (int r = 0; r < 2; ++r) {
                GLL(As + abase + kc * 64 + (r * 2 + sc16) * 16,
                    &ldsA[((arr * 4 + kc) * 2 + r) * 4096 + ldd]);
            }
        }
    }
    // first B chunk (nt=0, eh, kc=0)
    #pragma unroll
    for (int r = 0; r < 2; ++r)
        GLL(eh + bbase + (r * 2 + sc16) * 16, &ldsB[0][r * 4096 + ldd]);
    __syncthreads();

    // fragment read offsets (bytes): sub-chunk g4, row*16
    int rowA[4], offB[4];
    #pragma unroll
    for (int m = 0; m < 4; ++m) rowA[m] = g4 * 2048 + (wm * 64 + m * 16 + c15) * 16;
    #pragma unroll
    for (int n = 0; n < 4; ++n) offB[n] = g4 * 2048 + (wc * 64 + n * 16 + c15) * 16;

    float d1[4][4], d2[4][4]; int i1[4][4];
    #pragma unroll
    for (int m = 0; m < 4; ++m)
        #pragma unroll
        for (int r = 0; r < 4; ++r) { d1[m][r] = 3.4e38f; d2[m][r] = 3.4e38f; i1[m][r] = 0; }

    int cur = 0;
    for (int nt = 0; nt < 8; ++nt) {
        i32x4 accH[4][4], accX[4][4];
        #pragma unroll
        for (int m = 0; m < 4; ++m)
            #pragma unroll
            for (int n = 0; n < 4; ++n) {
                accH[m][n] = (i32x4){0, 0, 0, 0};
                accX[m][n] = (i32x4){0, 0, 0, 0};
            }

        #pragma unroll
        for (int c = 0; c < 8; ++c) {
            // prefetch next B chunk (double buffer; WAR-safe: cur^1 readers done)
            if (!(c == 7 && nt == 7)) {
                int nc = c + 1, nnt = nt;
                if (nc == 8) { nc = 0; ++nnt; }
                const signed char* Bs = (nc < 4) ? eh : el;
                const unsigned boff = bbase + ((unsigned)nnt << 15) + (unsigned)((nc & 3) * 64);
                #pragma unroll
                for (int r = 0; r < 2; ++r)
                    GLL(Bs + boff + (r * 2 + sc16) * 16, &ldsB[cur ^ 1][r * 4096 + ldd]);
            }
            const int kc = c & 3;
            i32x4 bfv[4];
            #pragma unroll
            for (int n = 0; n < 4; ++n)
                bfv[n] = *reinterpret_cast<const i32x4*>(&ldsB[cur][offB[n]]);
            if (c < 4) {
                // eh chunk: accH += zh[kc] x B,  accX += zl[kc] x B
                i32x4 afh[4], afl[4];
                #pragma unroll
                for (int m = 0; m < 4; ++m) {
                    afh[m] = *reinterpret_cast<const i32x4*>(&ldsA[kc * 8192 + rowA[m]]);
                    afl[m] = *reinterpret_cast<const i32x4*>(&ldsA[(4 + kc) * 8192 + rowA[m]]);
                }
                __builtin_amdgcn_s_setprio(1);
                #pragma unroll
                for (int m = 0; m < 4; ++m)
                    #pragma unroll
                    for (int n = 0; n < 4; ++n) {
                        accH[m][n] = __builtin_amdgcn_mfma_i32_16x16x64_i8(
                            afh[m], bfv[n], accH[m][n], 0, 0, 0);
                        accX[m][n] = __builtin_amdgcn_mfma_i32_16x16x64_i8(
                            afl[m], bfv[n], accX[m][n], 0, 0, 0);
                    }
                __builtin_amdgcn_s_setprio(0);
            } else {
                // el chunk: accX += zh[kc] x B
                i32x4 afh[4];
                #pragma unroll
                for (int m = 0; m < 4; ++m)
                    afh[m] = *reinterpret_cast<const i32x4*>(&ldsA[kc * 8192 + rowA[m]]);
                __builtin_amdgcn_s_setprio(1);
                #pragma unroll
                for (int m = 0; m < 4; ++m)
                    #pragma unroll
                    for (int n = 0; n < 4; ++n)
                        accX[m][n] = __builtin_amdgcn_mfma_i32_16x16x64_i8(
                            afh[m], bfv[n], accX[m][n], 0, 0, 0);
                __builtin_amdgcn_s_setprio(0);
            }
            __syncthreads();
            cur ^= 1;
        }

        // distances + running top-2 (codes ascend per lane -> lowest idx on tie)
        int n0 = nbase + nt * 128;
        #pragma unroll
        for (int n = 0; n < 4; ++n) {
            int ng = n0 + wc * 64 + n * 16 + c15;
            float en = enorm[ng];
            #pragma unroll
            for (int m = 0; m < 4; ++m)
                #pragma unroll
                for (int r = 0; r < 4; ++r) {
                    float sx = fmaf(-CXC, (float)accX[m][n][r], en);
                    float s  = fmaf(-CHC, (float)accH[m][n][r], sx);
                    if (s < d1[m][r]) { d2[m][r] = d1[m][r]; d1[m][r] = s; i1[m][r] = ng; }
                    else if (s < d2[m][r]) d2[m][r] = s;
                }
        }
    }

    #pragma unroll
    for (int off = 1; off <= 8; off <<= 1) {
        #pragma unroll
        for (int m = 0; m < 4; ++m)
            #pragma unroll
            for (int r = 0; r < 4; ++r) {
                float od1 = __shfl_xor(d1[m][r], off);
                int   oi1 = __shfl_xor(i1[m][r], off);
                float od2 = __shfl_xor(d2[m][r], off);
                float nd2 = fminf(fminf(d2[m][r], od2), fmaxf(d1[m][r], od1));
                if (od1 < d1[m][r] || (od1 == d1[m][r] && oi1 < i1[m][r])) {
                    d1[m][r] = od1; i1[m][r] = oi1;
                }
                d2[m][r] = nd2;
            }
    }

    float* rs1 = (float*)&ldsA[0];
    float* rs2 = rs1 + 128;
    int*   ri  = (int*)(rs2 + 128);
    if (wc == 1 && c15 == 0) {
        #pragma unroll
        for (int m = 0; m < 4; ++m)
            #pragma unroll
            for (int r = 0; r < 4; ++r) {
                int q = wm * 64 + m * 16 + g4 * 4 + r;
                rs1[q] = d1[m][r];
                rs2[q] = d2[m][r];
                ri [q] = i1[m][r];
            }
    }
    __syncthreads();
    if (wc == 0 && c15 == 0) {
        #pragma unroll
        for (int m = 0; m < 4; ++m)
            #pragma unroll
            for (int r = 0; r < 4; ++r) {
                int q = wm * 64 + m * 16 + g4 * 4 + r;
                float bd1 = d1[m][r], bd2 = d2[m][r]; int bi1 = i1[m][r];
                float od1 = rs1[q], od2 = rs2[q];
                int   oi1 = ri [q];
                float nd2 = fminf(fminf(bd2, od2), fmaxf(bd1, od1));
                if (od1 < bd1 || (od1 == bd1 && oi1 < bi1)) { bd1 = od1; bi1 = oi1; }
                bd2 = nd2;
                int gq = l0 + q;
                pd1[ni * L_TOT + gq] = bd1;
                pd2[ni * L_TOT + gq] = bd2;
                pi1[ni * L_TOT + gq] = bi1;
            }
    }
}

// ---------------- fused merge (2 stripes) + gather ----------------
__global__ __launch_bounds__(256) void k_mg(
    const float* __restrict__ pd1, const float* __restrict__ pd2,
    const int* __restrict__ pi1, const float* __restrict__ emb,
    int* __restrict__ ws_idx, float* __restrict__ out_idxf,
    float* __restrict__ used, int* __restrict__ flag_cnt,
    int* __restrict__ flag_list, float* __restrict__ d1_part,
    float* __restrict__ outq)
{
    __shared__ int sidx[64];
    __shared__ float eldT[Dm][65];
    const int t = threadIdx.x;
    const int l0 = blockIdx.x * 64;
    const int b = l0 >> 10, p0 = l0 & 1023;

    if (t < 64) {
        int gq = l0 + t;
        float d1 = pd1[gq], d2 = pd2[gq]; int i1 = pi1[gq];
        float od1 = pd1[L_TOT + gq], od2 = pd2[L_TOT + gq];
        int   oi1 = pi1[L_TOT + gq];
        float nd2 = fminf(fminf(d2, od2), fmaxf(d1, od1));
        if (od1 < d1 || (od1 == d1 && oi1 < i1)) { d1 = od1; i1 = oi1; }
        d2 = nd2;
        ws_idx[gq] = i1;
        out_idxf[gq] = (float)i1;
        if (d2 - d1 < TAU) {
            int pos = atomicAdd(flag_cnt, 1);
            flag_list[pos] = gq;
        } else {
            used[i1] = 1.0f;
        }
        sidx[t] = i1;
        float s = d1;
        #pragma unroll
        for (int off = 32; off; off >>= 1) s += __shfl_xor(s, off);
        if (t == 0) d1_part[blockIdx.x] = s;
    }
    __syncthreads();

    int w = t >> 6, lane = t & 63;
    for (int r = 0; r < 16; ++r) {
        int q = r * 4 + w;
        const float4 v = *reinterpret_cast<const float4*>(emb + (size_t)sidx[q] * Dm + lane * 4);
        eldT[lane * 4 + 0][q] = v.x; eldT[lane * 4 + 1][q] = v.y;
        eldT[lane * 4 + 2][q] = v.z; eldT[lane * 4 + 3][q] = v.w;
    }
    __syncthreads();
    const size_t obase = (size_t)b * (Dm * HW) + p0 + lane;
    #pragma unroll 4
    for (int it = 0; it < 64; ++it) {
        int c = w * 64 + it;
        outq[obase + (size_t)c * HW] = eldT[c][lane];
    }
}

// ---------------- fallback fp32 argmin (round-1 proven) ----------------
#define BM 64
#define BN 128
#define BK 64
__global__ __launch_bounds__(256, 2) void k_argmin_f32(
    const float* __restrict__ z, const float* __restrict__ emb,
    const float* __restrict__ enorm, int* __restrict__ ws_idx,
    float* __restrict__ out_idxf, float* __restrict__ used,
    int* __restrict__ flag_cnt, int* __restrict__ flag_list)
{
    __shared__ float zlds[BK][BM];
    __shared__ float el[BK][BN + 4];
    __shared__ float rd1[4][64];
    __shared__ int   ri1[4][64];
    __shared__ float rd2[4][64];

    const int t  = threadIdx.x;
    const int tq = t & 15;
    const int tn = t >> 4;
    const int l0 = blockIdx.x * BM;
    const int b  = l0 >> 10, p0 = l0 & 1023;
    const float* zb = z + (size_t)b * (Dm * HW) + p0;

    float d1[4], d2[4]; int i1[4];
    #pragma unroll
    for (int i = 0; i < 4; ++i) { d1[i] = FLT_MAX; d2[i] = FLT_MAX; i1[i] = 0; }

    for (int nt = 0; nt < NE / BN; ++nt) {
        const int n0 = nt * BN;
        float acc[4][8];
        #pragma unroll
        for (int i = 0; i < 4; ++i)
            #pragma unroll
            for (int j = 0; j < 8; ++j) acc[i][j] = 0.f;

        for (int kc = 0; kc < Dm / BK; ++kc) {
            __syncthreads();
            #pragma unroll
            for (int r = 0; r < 4; ++r) {
                int f = r * 256 + t;
                int kk = f >> 4, q4 = (f & 15) << 2;
                float4 v = *reinterpret_cast<const float4*>(zb + (size_t)(kc * BK + kk) * HW + q4);
                *reinterpret_cast<float4*>(&zlds[kk][q4]) = v;
            }
            #pragma unroll
            for (int r = 0; r < 8; ++r) {
                int f = r * 256 + t;
                int n = f >> 4, k4 = (f & 15) << 2;
                float4 v = *reinterpret_cast<const float4*>(emb + (size_t)(n0 + n) * Dm + kc * BK + k4);
                el[k4 + 0][n] = v.x; el[k4 + 1][n] = v.y;
                el[k4 + 2][n] = v.z; el[k4 + 3][n] = v.w;
            }
            __syncthreads();
            #pragma unroll 4
            for (int kk = 0; kk < BK; ++kk) {
                float4 zf = *reinterpret_cast<const float4*>(&zlds[kk][tq << 2]);
                float4 e0 = *reinterpret_cast<const float4*>(&el[kk][tn << 3]);
                float4 e1 = *reinterpret_cast<const float4*>(&el[kk][(tn << 3) + 4]);
                float zr[4] = { zf.x, zf.y, zf.z, zf.w };
                float er[8] = { e0.x, e0.y, e0.z, e0.w, e1.x, e1.y, e1.z, e1.w };
                #pragma unroll
                for (int i = 0; i < 4; ++i)
                    #pragma unroll
                    for (int j = 0; j < 8; ++j)
                        acc[i][j] = fmaf(zr[i], er[j], acc[i][j]);
            }
        }
        #pragma unroll
        for (int j = 0; j < 8; ++j) {
            int ng = n0 + (tn << 3) + j;
            float en = enorm[ng];
            #pragma unroll
            for (int i = 0; i < 4; ++i) {
                float s = fmaf(-2.f, acc[i][j], en);
                if (s < d1[i]) { d2[i] = d1[i]; d1[i] = s; i1[i] = ng; }
                else if (s < d2[i]) d2[i] = s;
            }
        }
    }
    #pragma unroll
    for (int off = 16; off <= 32; off <<= 1) {
        #pragma unroll
        for (int i = 0; i < 4; ++i) {
            float od1 = __shfl_xor(d1[i], off);
            int   oi1 = __shfl_xor(i1[i], off);
            float od2 = __shfl_xor(d2[i], off);
            float nd2 = fminf(fminf(d2[i], od2), fmaxf(d1[i], od1));
            bool take = (od1 < d1[i]) || (od1 == d1[i] && oi1 < i1[i]);
            if (take) { d1[i] = od1; i1[i] = oi1; }
            d2[i] = nd2;
        }
    }
    int w = t >> 6;
    if ((t & 63) < 16) {
        #pragma unroll
        for (int i = 0; i < 4; ++i) {
            rd1[w][(tq << 2) + i] = d1[i];
            ri1[w][(tq << 2) + i] = i1[i];
            rd2[w][(tq << 2) + i] = d2[i];
        }
    }
    __syncthreads();
    if (t < 64) {
        float bd1 = rd1[0][t]; int bi1 = ri1[0][t]; float bd2 = rd2[0][t];
        #pragma unroll
        for (int ww = 1; ww < 4; ++ww) {
            float od1 = rd1[ww][t]; int oi1 = ri1[ww][t]; float od2 = rd2[ww][t];
            float nd2 = fminf(fminf(bd2, od2), fmaxf(bd1, od1));
            if (od1 < bd1 || (od1 == bd1 && oi1 < bi1)) { bd1 = od1; bi1 = oi1; }
            bd2 = nd2;
        }
        int l = l0 + t;
        ws_idx[l] = bi1;
        out_idxf[l] = (float)bi1;
        if (bd2 - bd1 < TAU) {
            int pos = atomicAdd(flag_cnt, 1);
            flag_list[pos] = l;
        } else {
            used[bi1] = 1.0f;
        }
    }
}

// ---------------- K_refine scan: parallel (query x 256-code chunk) fp64 partial argmin ----------------
__global__ __launch_bounds__(256) void k_refine_scan(
    const float* __restrict__ z, const float* __restrict__ emb,
    const int* __restrict__ flag_cnt, const int* __restrict__ flag_list,
    double* __restrict__ pbd, int* __restrict__ pbi)
{
    __shared__ float zrow[Dm];
    __shared__ double sd[256];
    __shared__ int    si[256];
    const int t = threadIdx.x;
    const int ntask = *flag_cnt * 8;
    for (int task = blockIdx.x; task < ntask; task += gridDim.x) {
        const int fi = task >> 3, chunk = task & 7;
        const int l = flag_list[fi];
        const int b = l >> 10, p = l & 1023;
        const float* zq = z + (size_t)b * (Dm * HW) + p;
        __syncthreads();
        zrow[t] = zq[(size_t)t * HW];
        __syncthreads();
        const int n = chunk * 256 + t;
        const float* er = emb + (size_t)n * Dm;
        double dt0 = 0.0, dt1 = 0.0, dt2 = 0.0, dt3 = 0.0;
        double nm0 = 0.0, nm1 = 0.0, nm2 = 0.0, nm3 = 0.0;
        for (int c = 0; c < Dm; c += 4) {
            double e0 = er[c], e1 = er[c + 1], e2 = er[c + 2], e3 = er[c + 3];
            dt0 += e0 * (double)zrow[c];     nm0 += e0 * e0;
            dt1 += e1 * (double)zrow[c + 1]; nm1 += e1 * e1;
            dt2 += e2 * (double)zrow[c + 2]; nm2 += e2 * e2;
            dt3 += e3 * (double)zrow[c + 3]; nm3 += e3 * e3;
        }
        sd[t] = (nm0 + nm1) + (nm2 + nm3) - 2.0 * ((dt0 + dt1) + (dt2 + dt3));
        si[t] = n;
        __syncthreads();
        for (int st = 128; st; st >>= 1) {
            if (t < st) {
                double od = sd[t + st]; int oi = si[t + st];
                if (od < sd[t] || (od == sd[t] && oi < si[t])) { sd[t] = od; si[t] = oi; }
            }
            __syncthreads();
        }
        if (t == 0) { pbd[task] = sd[0]; pbi[task] = si[0]; }
    }
}

// ---------------- K_refine merge: 8-way lexicographic combine + outputs + outq patch ----------------
__global__ __launch_bounds__(256) void k_refine_merge(
    const float* __restrict__ emb, const int* __restrict__ flag_cnt,
    const int* __restrict__ flag_list, const double* __restrict__ pbd,
    const int* __restrict__ pbi, int* __restrict__ ws_idx,
    float* __restrict__ out_idxf, float* __restrict__ used,
    float* __restrict__ outq)
{
    __shared__ int bestn;
    const int t = threadIdx.x;
    const int nf = *flag_cnt;
    for (int fi = blockIdx.x; fi < nf; fi += gridDim.x) {
        const int l = flag_list[fi];
        __syncthreads();
        if (t == 0) {
            double bd = pbd[fi * 8]; int bi = pbi[fi * 8];
            #pragma unroll
            for (int c = 1; c < 8; ++c) {
                double od = pbd[fi * 8 + c]; int oi = pbi[fi * 8 + c];
                if (od < bd || (od == bd && oi < bi)) { bd = od; bi = oi; }
            }
            ws_idx[l] = bi;
            out_idxf[l] = (float)bi;
            used[bi] = 1.0f;
            bestn = bi;
        }
        __syncthreads();
        const int b = l >> 10, p = l & 1023;
        outq[(size_t)b * (Dm * HW) + (size_t)t * HW + p] = emb[(size_t)bestn * Dm + t];
    }
}

// ---------------- fallback serial refine (r8-proven) ----------------
__global__ void k_refine(const float* __restrict__ z, const float* __restrict__ emb,
                         const int* __restrict__ flag_cnt, const int* __restrict__ flag_list,
                         int* __restrict__ ws_idx, float* __restrict__ out_idxf,
                         float* __restrict__ used, float* __restrict__ outq)
{
    __shared__ float zrow[Dm];
    __shared__ double sd[256];
    __shared__ int    si[256];
    int nf = *flag_cnt;
    for (int fi = blockIdx.x; fi < nf; fi += gridDim.x) {
        int l = flag_list[fi];
        int b = l >> 10, p = l & 1023;
        const float* zq = z + (size_t)b * (Dm * HW) + p;
        __syncthreads();
        for (int c = threadIdx.x; c < Dm; c += blockDim.x) zrow[c] = zq[(size_t)c * HW];
        __syncthreads();
        double bd = DBL_MAX; int bi = 0;
        for (int nb = 0; nb < NE / 256; ++nb) {
            int n = nb * 256 + threadIdx.x;
            const float* er = emb + (size_t)n * Dm;
            double dt0 = 0.0, dt1 = 0.0, dt2 = 0.0, dt3 = 0.0;
            double nm0 = 0.0, nm1 = 0.0, nm2 = 0.0, nm3 = 0.0;
            for (int c = 0; c < Dm; c += 4) {
                double e0 = er[c], e1 = er[c + 1], e2 = er[c + 2], e3 = er[c + 3];
                dt0 += e0 * (double)zrow[c];     nm0 += e0 * e0;
                dt1 += e1 * (double)zrow[c + 1]; nm1 += e1 * e1;
                dt2 += e2 * (double)zrow[c + 2]; nm2 += e2 * e2;
                dt3 += e3 * (double)zrow[c + 3]; nm3 += e3 * e3;
            }
            double s = (nm0 + nm1) + (nm2 + nm3) - 2.0 * ((dt0 + dt1) + (dt2 + dt3));
            if (s < bd) { bd = s; bi = n; }
        }
        sd[threadIdx.x] = bd; si[threadIdx.x] = bi;
        __syncthreads();
        for (int st = 128; st; st >>= 1) {
            if (threadIdx.x < (unsigned)st) {
                double od = sd[threadIdx.x + st]; int oi = si[threadIdx.x + st];
                if (od < sd[threadIdx.x] || (od == sd[threadIdx.x] && oi < si[threadIdx.x])) {
                    sd[threadIdx.x] = od; si[threadIdx.x] = oi;
                }
            }
            __syncthreads();
        }
        if (threadIdx.x == 0) {
            ws_idx[l] = si[0];
            out_idxf[l] = (float)si[0];
            used[si[0]] = 1.0f;
        }
        __syncthreads();
        int bi0 = si[0];
        int c = threadIdx.x;
        outq[(size_t)b * (Dm * HW) + (size_t)c * HW + p] = emb[(size_t)bi0 * Dm + c];
        __syncthreads();
    }
}

// ---------------- fallback gather+loss ----------------
__global__ __launch_bounds__(256) void k_gather_loss(
    const float* __restrict__ z, const float* __restrict__ emb,
    const int* __restrict__ ws_idx, float* __restrict__ outq,
    float* __restrict__ partials)
{
    __shared__ int sidx[64];
    __shared__ float eldT[Dm][65];
    __shared__ float wsum[4];
    const int t = threadIdx.x;
    const int l0 = blockIdx.x * 64;
    const int b = l0 >> 10, p0 = l0 & 1023;
    if (t < 64) sidx[t] = ws_idx[l0 + t];
    __syncthreads();
    int w = t >> 6, lane = t & 63;
    for (int r = 0; r < 16; ++r) {
        int q = r * 4 + w;
        const float4 v = *reinterpret_cast<const float4*>(emb + (size_t)sidx[q] * Dm + lane * 4);
        eldT[lane * 4 + 0][q] = v.x; eldT[lane * 4 + 1][q] = v.y;
        eldT[lane * 4 + 2][q] = v.z; eldT[lane * 4 + 3][q] = v.w;
    }
    __syncthreads();
    float ls = 0.f;
    const size_t obase = (size_t)b * (Dm * HW) + p0 + lane;
    for (int it = 0; it < 64; ++it) {
        int c = w * 64 + it;
        size_t o = obase + (size_t)c * HW;
        float qv = eldT[c][lane];
        float zv = z[o];
        outq[o] = qv;
        float df = qv - zv;
        ls = fmaf(df, df, ls);
    }
    #pragma unroll
    for (int off = 32; off; off >>= 1) ls += __shfl_xor(ls, off);
    if (lane == 0) wsum[w] = ls;
    __syncthreads();
    if (t == 0) partials[blockIdx.x] = wsum[0] + wsum[1] + wsum[2] + wsum[3];
}

// ---------------- final: loss = (Sum||z||^2 + Sum d1)/count, used count ----------------
__global__ void k_final(const float* __restrict__ zn_part, const float* __restrict__ d1_part,
                        int nd1, const float* __restrict__ used,
                        float* __restrict__ out_loss, float* __restrict__ out_used)
{
    __shared__ double s1[256];
    __shared__ float  s2[256];
    int t = threadIdx.x;
    double a = 0.0;
    for (int i = t; i < 1024; i += 256) a += (double)zn_part[i];
    for (int i = t; i < nd1; i += 256) a += (double)d1_part[i];
    float u = 0.f;
    for (int i = t; i < NE; i += 256) u += used[i];
    s1[t] = a; s2[t] = u;
    __syncthreads();
    for (int st = 128; st; st >>= 1) {
        if (t < st) { s1[t] += s1[t + st]; s2[t] += s2[t + st]; }
        __syncthreads();
    }
    if (t == 0) { *out_loss = (float)(s1[0] / 8388608.0); *out_used = s2[0]; }
}

// ---------------- fallback final ----------------
__global__ void k_final_fb(const float* __restrict__ partials, const float* __restrict__ used,
                           float* __restrict__ out_loss, float* __restrict__ out_used)
{
    __shared__ float s1[256], s2[256];
    int t = threadIdx.x;
    float a = partials[t] + partials[t + 256];
    float u = 0.f;
    for (int i = t; i < NE; i += 256) u += used[i];
    s1[t] = a; s2[t] = u;
    __syncthreads();
    for (int st = 128; st; st >>= 1) {
        if (t < st) { s1[t] += s1[t + st]; s2[t] += s2[t + st]; }
        __syncthreads();
    }
    if (t == 0) { *out_loss = s1[0] / 8388608.f; *out_used = s2[0]; }
}

extern "C" void kernel_launch(void* const* d_in, const int* in_sizes, int n_in,
                              void* d_out, int out_size, void* d_ws, size_t ws_size,
                              hipStream_t stream) {
    const float* z   = (const float*)d_in[0];
    const float* emb = (const float*)d_in[1];
    float* out      = (float*)d_out;
    float* outq     = out;
    float* out_loss = out + QOFF;
    float* out_idxf = out + QOFF + 1;
    float* out_used = out + QOFF + 1 + L_TOT;

    float* ws       = (float*)d_ws;
    float* enorm    = ws;                         // [0, 2048)
    float* used     = ws + 2048;                  // [2048, 4096)
    float* zn_part  = ws + 4096;                  // [4096, 5120)
    float* d1_part  = ws + 5120;                  // [5120, 5632)  512
    int*   flag_cnt = (int*)(ws + 5632);          // 1 (+pad)
    int*   ws_idx   = (int*)(ws + 5888);          // 32768
    int*   flag_list= (int*)(ws + 5888 + L_TOT);  // 32768 -> ends 71424

    // 2-stripe partials
    float* pd1w = ws + 71680;                     // 65536
    float* pd2w = ws + 137216;                    // 65536
    int*   pi1w = (int*)(ws + 202752);            // 65536 -> ends 268288 floats

    size_t i8_bytes = 2ull * (NE + L_TOT) * Dm;   // 17825792
    size_t pbd_off_f = 268288 + i8_bytes / 4;     // 8B-aligned byte offset
    size_t pbi_off_f = pbd_off_f + 2 * 262144;
    size_t need_i8 = (pbi_off_f + 262144) * 4;    // ~22.1 MB

    if (ws_size >= need_i8) {
        signed char* e_hi8 = (signed char*)(ws + 268288);
        signed char* e_lo8 = e_hi8 + (size_t)NE * Dm;
        signed char* z_hi8 = e_lo8 + (size_t)NE * Dm;
        signed char* z_lo8 = z_hi8 + (size_t)L_TOT * Dm;
        double* pbd = (double*)(ws + pbd_off_f);
        int*    pbi = (int*)(ws + pbi_off_f);
        k_split_i8<<<1024, 256, 0, stream>>>(z, emb, z_hi8, z_lo8, e_hi8, e_lo8,
                                             enorm, zn_part, used, flag_cnt);
        k_score_i8<<<512, 256, 0, stream>>>(z_hi8, z_lo8, e_hi8, e_lo8, enorm,
                                            pd1w, pd2w, pi1w);
        k_mg<<<L_TOT / 64, 256, 0, stream>>>(pd1w, pd2w, pi1w, emb, ws_idx, out_idxf,
                                             used, flag_cnt, flag_list, d1_part, outq);
        k_refine_scan<<<2048, 256, 0, stream>>>(z, emb, flag_cnt, flag_list, pbd, pbi);
        k_refine_merge<<<256, 256, 0, stream>>>(emb, flag_cnt, flag_list, pbd, pbi,
                                                ws_idx, out_idxf, used, outq);
        k_final<<<1, 256, 0, stream>>>(zn_part, d1_part, 512, used, out_loss, out_used);
    } else {
        hipMemsetAsync(used, 0, (size_t)3584 * 4, stream);
        k_enorm<<<NE / 4, 256, 0, stream>>>(emb, enorm);
        k_argmin_f32<<<L_TOT / BM, 256, 0, stream>>>(z, emb, enorm, ws_idx, out_idxf, used,
                                                     flag_cnt, flag_list);
        k_refine<<<256, 256, 0, stream>>>(z, emb, flag_cnt, flag_list, ws_idx, out_idxf,
                                          used, outq);
        k_gather_loss<<<L_TOT / 64, 256, 0, stream>>>(z, emb, ws_idx, outq, zn_part);
        k_final_fb<<<1, 256, 0, stream>>>(zn_part, used, out_loss, out_used);
    }
}

// Round 19
// 216.566 us; speedup vs baseline: 1.8422x; 1.0008x over previous
//
#include <hip/hip_runtime.h>
#include <cfloat>

#define Dm 256
#define HW 1024
#define NE 2048
#define L_TOT 32768
#define QOFF 8388608   // B*C*H*W
#define TAU 0.1f

#define QSCALE 4064.0f               // 32512/8
#define CHC 7.93613e-3f              // 2*65536/QSCALE^2
#define CXC 3.10005e-5f              // 2*256/QSCALE^2

typedef __attribute__((ext_vector_type(4))) int i32x4;
typedef const __attribute__((address_space(1))) unsigned int* as1_u32p;
typedef __attribute__((address_space(3))) unsigned int* as3_u32p;

#define GLL(gp, lp) __builtin_amdgcn_global_load_lds((as1_u32p)(gp), (as3_u32p)(lp), 16, 0, 0)

__device__ __forceinline__ void q8(float x, signed char& hi, signed char& lo) {
    int xi = __float2int_rn(x * QSCALE);
    xi = max(-32512, min(32512, xi));
    int h = (xi + 128) >> 8;
    hi = (signed char)h;
    lo = (signed char)(xi - (h << 8));
}

// ---------------- K1 (fallback only): code norms ----------------
__global__ void k_enorm(const float* __restrict__ emb, float* __restrict__ enorm) {
    int w = threadIdx.x >> 6, lane = threadIdx.x & 63;
    int n = blockIdx.x * 4 + w;
    const float4 v = *reinterpret_cast<const float4*>(emb + (size_t)n * Dm + lane * 4);
    double s = (double)v.x * v.x + (double)v.y * v.y + (double)v.z * v.z + (double)v.w * v.w;
    #pragma unroll
    for (int off = 32; off; off >>= 1) s += __shfl_xor(s, off);
    if (lane == 0) enorm[n] = (float)s;
}

// ---------------- fused: i8 split Z (transpose) + split E + norms + ws zeroing ----------------
__global__ __launch_bounds__(256) void k_split_i8(
    const float* __restrict__ z, const float* __restrict__ emb,
    signed char* __restrict__ z_hi, signed char* __restrict__ z_lo,
    signed char* __restrict__ e_hi, signed char* __restrict__ e_lo,
    float* __restrict__ enorm, float* __restrict__ zn_part,
    float* __restrict__ used, int* __restrict__ flag_cnt)
{
    __shared__ signed char zh[32][264];
    __shared__ signed char zl[32][264];
    __shared__ double zsum[4];
    const int t = threadIdx.x;
    const int w = t >> 6, lane = t & 63;

    if (blockIdx.x >= 16 && blockIdx.x < 24) used[(blockIdx.x - 16) * 256 + t] = 0.f;
    if (blockIdx.x == 24 && t == 0) *flag_cnt = 0;

    if (w < 2) {
        int n = blockIdx.x * 2 + w;
        const float4 v = *reinterpret_cast<const float4*>(emb + (size_t)n * Dm + lane * 4);
        float vv[4] = { v.x, v.y, v.z, v.w };
        double s = (double)v.x * v.x + (double)v.y * v.y + (double)v.z * v.z + (double)v.w * v.w;
        #pragma unroll
        for (int off = 32; off; off >>= 1) s += __shfl_xor(s, off);
        if (lane == 0) enorm[n] = (float)s;
        signed char h4[4], l4[4];
        #pragma unroll
        for (int j = 0; j < 4; ++j) q8(vv[j], h4[j], l4[j]);
        *reinterpret_cast<int*>(e_hi + (size_t)n * Dm + lane * 4) = *reinterpret_cast<int*>(h4);
        *reinterpret_cast<int*>(e_lo + (size_t)n * Dm + lane * 4) = *reinterpret_cast<int*>(l4);
    }

    const int b  = blockIdx.x >> 5;
    const int p0 = (blockIdx.x & 31) * 32;
    const int pp = t & 31, cb = t >> 5;
    const float* zb = z + (size_t)b * (Dm * HW) + p0 + pp;
    float zs = 0.f;
    for (int ci = 0; ci < 32; ++ci) {
        int c = ci * 8 + cb;
        float x = zb[(size_t)c * HW];
        zs = fmaf(x, x, zs);
        q8(x, zh[pp][c], zl[pp][c]);
    }
    double d = zs;
    #pragma unroll
    for (int off = 32; off; off >>= 1) d += __shfl_xor(d, off);
    if ((t & 63) == 0) zsum[w] = d;
    __syncthreads();
    if (t == 0) zn_part[blockIdx.x] = (float)(zsum[0] + zsum[1] + zsum[2] + zsum[3]);
    const int l0 = b * 1024 + p0;
    #pragma unroll
    for (int r = 0; r < 8; ++r) {
        int id = r * 256 + t;
        int row = id >> 6, ch = id & 63;
        *reinterpret_cast<int*>(z_hi + (size_t)(l0 + row) * Dm + ch * 4) =
            *reinterpret_cast<int*>(&zh[row][ch * 4]);
        *reinterpret_cast<int*>(z_lo + (size_t)(l0 + row) * Dm + ch * 4) =
            *reinterpret_cast<int*>(&zl[row][ch * 4]);
    }
}

// ---------------- K2: i8 score GEMM, A-resident LDS + counted-vmcnt steps ----------------
// r18 structure (A tile resident, 2 GLL/thread per B chunk) with the per-step
// __syncthreads replaced by: issue stage(c+1) -> s_waitcnt vmcnt(2) ->
// s_barrier -> ds_read+MFMA -> s_barrier. The 2 newest GLLs stay in flight
// across the barrier (T4); vmcnt(2) waits only for the PREVIOUS step's GLLs
// (issued a full step earlier -> latency hidden). barrier A: all stage(c)
// writes landed (each wave waited own vmcnt; counter decrements in issue
// order). barrier B: WAR, reads of buf[cur] precede step c+1's writes to it.
__global__ __launch_bounds__(256, 2) void k_score_i8(
    const signed char* __restrict__ zh, const signed char* __restrict__ zl,
    const signed char* __restrict__ eh, const signed char* __restrict__ el,
    const float* __restrict__ enorm,
    float* __restrict__ pd1, float* __restrict__ pd2, int* __restrict__ pi1)
{
    __shared__ signed char ldsA[65536];    // 8 regions (arr2 x kc4) of 8 KB
    __shared__ signed char ldsB[2][8192];  // double-buffered B chunk (K=64)

    const int t    = threadIdx.x;
    const int lane = t & 63, w = t >> 6;
    const int wm = w >> 1, wc = w & 1;
    const int c15 = lane & 15, g4 = lane >> 4;

    const int bx = blockIdx.x;
    const int wg = (bx & 7) * 64 + (bx >> 3);
    const int mi = wg >> 1, ni = wg & 1;
    const int l0 = mi * 128;
    const int nbase = ni * 1024;

    const int srow = t & 127;
    const int sc16 = t >> 7;
    const unsigned abase = (unsigned)((l0 + srow) * Dm);
    const unsigned bbase = (unsigned)((nbase + srow) * Dm);
    const int ldd = t * 16;

    // ---- A prologue (once): 16 GLL + first B chunk (2 GLL), full drain ----
    #pragma unroll
    for (int arr = 0; arr < 2; ++arr) {
        const signed char* As = arr ? zl : zh;
        #pragma unroll
        for (int kc = 0; kc < 4; ++kc) {
            #pragma unroll
            for (int r = 0; r < 2; ++r) {
                GLL(As + abase + kc * 64 + (r * 2 + sc16) * 16,
                    &ldsA[((arr * 4 + kc) * 2 + r) * 4096 + ldd]);
            }
        }
    }
    #pragma unroll
    for (int r = 0; r < 2; ++r)
        GLL(eh + bbase + (r * 2 + sc16) * 16, &ldsB[0][r * 4096 + ldd]);
    __syncthreads();

    int rowA[4], offB[4];
    #pragma unroll
    for (int m = 0; m < 4; ++m) rowA[m] = g4 * 2048 + (wm * 64 + m * 16 + c15) * 16;
    #pragma unroll
    for (int n = 0; n < 4; ++n) offB[n] = g4 * 2048 + (wc * 64 + n * 16 + c15) * 16;

    float d1[4][4], d2[4][4]; int i1[4][4];
    #pragma unroll
    for (int m = 0; m < 4; ++m)
        #pragma unroll
        for (int r = 0; r < 4; ++r) { d1[m][r] = 3.4e38f; d2[m][r] = 3.4e38f; i1[m][r] = 0; }

    int cur = 0;
    for (int nt = 0; nt < 8; ++nt) {
        i32x4 accH[4][4], accX[4][4];
        #pragma unroll
        for (int m = 0; m < 4; ++m)
            #pragma unroll
            for (int n = 0; n < 4; ++n) {
                accH[m][n] = (i32x4){0, 0, 0, 0};
                accX[m][n] = (i32x4){0, 0, 0, 0};
            }

        #pragma unroll
        for (int c = 0; c < 8; ++c) {
            const bool last = (c == 7 && nt == 7);
            // issue next B chunk (targets buf[cur^1]; its readers finished at
            // the previous step's barrier B)
            if (!last) {
                int nc = c + 1, nnt = nt;
                if (nc == 8) { nc = 0; ++nnt; }
                const signed char* Bs = (nc < 4) ? eh : el;
                const unsigned boff = bbase + ((unsigned)nnt << 15) + (unsigned)((nc & 3) * 64);
                #pragma unroll
                for (int r = 0; r < 2; ++r)
                    GLL(Bs + boff + (r * 2 + sc16) * 16, &ldsB[cur ^ 1][r * 4096 + ldd]);
                asm volatile("s_waitcnt vmcnt(2)" ::: "memory");
            } else {
                asm volatile("s_waitcnt vmcnt(0)" ::: "memory");
            }
            __builtin_amdgcn_sched_barrier(0);
            __builtin_amdgcn_s_barrier();            // A: stage(c) landed everywhere
            __builtin_amdgcn_sched_barrier(0);

            const int kc = c & 3;
            i32x4 bfv[4];
            #pragma unroll
            for (int n = 0; n < 4; ++n)
                bfv[n] = *reinterpret_cast<const i32x4*>(&ldsB[cur][offB[n]]);
            if (c < 4) {
                i32x4 afh[4], afl[4];
                #pragma unroll
                for (int m = 0; m < 4; ++m) {
                    afh[m] = *reinterpret_cast<const i32x4*>(&ldsA[kc * 8192 + rowA[m]]);
                    afl[m] = *reinterpret_cast<const i32x4*>(&ldsA[(4 + kc) * 8192 + rowA[m]]);
                }
                __builtin_amdgcn_s_setprio(1);
                #pragma unroll
                for (int m = 0; m < 4; ++m)
                    #pragma unroll
                    for (int n = 0; n < 4; ++n) {
                        accH[m][n] = __builtin_amdgcn_mfma_i32_16x16x64_i8(
                            afh[m], bfv[n], accH[m][n], 0, 0, 0);
                        accX[m][n] = __builtin_amdgcn_mfma_i32_16x16x64_i8(
                            afl[m], bfv[n], accX[m][n], 0, 0, 0);
                    }
                __builtin_amdgcn_s_setprio(0);
            } else {
                i32x4 afh[4];
                #pragma unroll
                for (int m = 0; m < 4; ++m)
                    afh[m] = *reinterpret_cast<const i32x4*>(&ldsA[kc * 8192 + rowA[m]]);
                __builtin_amdgcn_s_setprio(1);
                #pragma unroll
                for (int m = 0; m < 4; ++m)
                    #pragma unroll
                    for (int n = 0; n < 4; ++n)
                        accX[m][n] = __builtin_amdgcn_mfma_i32_16x16x64_i8(
                            afh[m], bfv[n], accX[m][n], 0, 0, 0);
                __builtin_amdgcn_s_setprio(0);
            }
            asm volatile("s_waitcnt lgkmcnt(0)" ::: "memory");
            __builtin_amdgcn_sched_barrier(0);
            __builtin_amdgcn_s_barrier();            // B: WAR for buf[cur]
            __builtin_amdgcn_sched_barrier(0);
            cur ^= 1;
        }

        // distances + running top-2 (codes ascend per lane -> lowest idx on tie)
        int n0 = nbase + nt * 128;
        #pragma unroll
        for (int n = 0; n < 4; ++n) {
            int ng = n0 + wc * 64 + n * 16 + c15;
            float en = enorm[ng];
            #pragma unroll
            for (int m = 0; m < 4; ++m)
                #pragma unroll
                for (int r = 0; r < 4; ++r) {
                    float sx = fmaf(-CXC, (float)accX[m][n][r], en);
                    float s  = fmaf(-CHC, (float)accH[m][n][r], sx);
                    if (s < d1[m][r]) { d2[m][r] = d1[m][r]; d1[m][r] = s; i1[m][r] = ng; }
                    else if (s < d2[m][r]) d2[m][r] = s;
                }
        }
    }

    #pragma unroll
    for (int off = 1; off <= 8; off <<= 1) {
        #pragma unroll
        for (int m = 0; m < 4; ++m)
            #pragma unroll
            for (int r = 0; r < 4; ++r) {
                float od1 = __shfl_xor(d1[m][r], off);
                int   oi1 = __shfl_xor(i1[m][r], off);
                float od2 = __shfl_xor(d2[m][r], off);
                float nd2 = fminf(fminf(d2[m][r], od2), fmaxf(d1[m][r], od1));
                if (od1 < d1[m][r] || (od1 == d1[m][r] && oi1 < i1[m][r])) {
                    d1[m][r] = od1; i1[m][r] = oi1;
                }
                d2[m][r] = nd2;
            }
    }

    float* rs1 = (float*)&ldsA[0];
    float* rs2 = rs1 + 128;
    int*   ri  = (int*)(rs2 + 128);
    if (wc == 1 && c15 == 0) {
        #pragma unroll
        for (int m = 0; m < 4; ++m)
            #pragma unroll
            for (int r = 0; r < 4; ++r) {
                int q = wm * 64 + m * 16 + g4 * 4 + r;
                rs1[q] = d1[m][r];
                rs2[q] = d2[m][r];
                ri [q] = i1[m][r];
            }
    }
    __syncthreads();
    if (wc == 0 && c15 == 0) {
        #pragma unroll
        for (int m = 0; m < 4; ++m)
            #pragma unroll
            for (int r = 0; r < 4; ++r) {
                int q = wm * 64 + m * 16 + g4 * 4 + r;
                float bd1 = d1[m][r], bd2 = d2[m][r]; int bi1 = i1[m][r];
                float od1 = rs1[q], od2 = rs2[q];
                int   oi1 = ri [q];
                float nd2 = fminf(fminf(bd2, od2), fmaxf(bd1, od1));
                if (od1 < bd1 || (od1 == bd1 && oi1 < bi1)) { bd1 = od1; bi1 = oi1; }
                bd2 = nd2;
                int gq = l0 + q;
                pd1[ni * L_TOT + gq] = bd1;
                pd2[ni * L_TOT + gq] = bd2;
                pi1[ni * L_TOT + gq] = bi1;
            }
    }
}

// ---------------- fused merge (2 stripes) + gather ----------------
__global__ __launch_bounds__(256) void k_mg(
    const float* __restrict__ pd1, const float* __restrict__ pd2,
    const int* __restrict__ pi1, const float* __restrict__ emb,
    int* __restrict__ ws_idx, float* __restrict__ out_idxf,
    float* __restrict__ used, int* __restrict__ flag_cnt,
    int* __restrict__ flag_list, float* __restrict__ d1_part,
    float* __restrict__ outq)
{
    __shared__ int sidx[64];
    __shared__ float eldT[Dm][65];
    const int t = threadIdx.x;
    const int l0 = blockIdx.x * 64;
    const int b = l0 >> 10, p0 = l0 & 1023;

    if (t < 64) {
        int gq = l0 + t;
        float d1 = pd1[gq], d2 = pd2[gq]; int i1 = pi1[gq];
        float od1 = pd1[L_TOT + gq], od2 = pd2[L_TOT + gq];
        int   oi1 = pi1[L_TOT + gq];
        float nd2 = fminf(fminf(d2, od2), fmaxf(d1, od1));
        if (od1 < d1 || (od1 == d1 && oi1 < i1)) { d1 = od1; i1 = oi1; }
        d2 = nd2;
        ws_idx[gq] = i1;
        out_idxf[gq] = (float)i1;
        if (d2 - d1 < TAU) {
            int pos = atomicAdd(flag_cnt, 1);
            flag_list[pos] = gq;
        } else {
            used[i1] = 1.0f;
        }
        sidx[t] = i1;
        float s = d1;
        #pragma unroll
        for (int off = 32; off; off >>= 1) s += __shfl_xor(s, off);
        if (t == 0) d1_part[blockIdx.x] = s;
    }
    __syncthreads();

    int w = t >> 6, lane = t & 63;
    for (int r = 0; r < 16; ++r) {
        int q = r * 4 + w;
        const float4 v = *reinterpret_cast<const float4*>(emb + (size_t)sidx[q] * Dm + lane * 4);
        eldT[lane * 4 + 0][q] = v.x; eldT[lane * 4 + 1][q] = v.y;
        eldT[lane * 4 + 2][q] = v.z; eldT[lane * 4 + 3][q] = v.w;
    }
    __syncthreads();
    const size_t obase = (size_t)b * (Dm * HW) + p0 + lane;
    #pragma unroll 4
    for (int it = 0; it < 64; ++it) {
        int c = w * 64 + it;
        outq[obase + (size_t)c * HW] = eldT[c][lane];
    }
}

// ---------------- fallback fp32 argmin (round-1 proven) ----------------
#define BM 64
#define BN 128
#define BK 64
__global__ __launch_bounds__(256, 2) void k_argmin_f32(
    const float* __restrict__ z, const float* __restrict__ emb,
    const float* __restrict__ enorm, int* __restrict__ ws_idx,
    float* __restrict__ out_idxf, float* __restrict__ used,
    int* __restrict__ flag_cnt, int* __restrict__ flag_list)
{
    __shared__ float zlds[BK][BM];
    __shared__ float el[BK][BN + 4];
    __shared__ float rd1[4][64];
    __shared__ int   ri1[4][64];
    __shared__ float rd2[4][64];

    const int t  = threadIdx.x;
    const int tq = t & 15;
    const int tn = t >> 4;
    const int l0 = blockIdx.x * BM;
    const int b  = l0 >> 10, p0 = l0 & 1023;
    const float* zb = z + (size_t)b * (Dm * HW) + p0;

    float d1[4], d2[4]; int i1[4];
    #pragma unroll
    for (int i = 0; i < 4; ++i) { d1[i] = FLT_MAX; d2[i] = FLT_MAX; i1[i] = 0; }

    for (int nt = 0; nt < NE / BN; ++nt) {
        const int n0 = nt * BN;
        float acc[4][8];
        #pragma unroll
        for (int i = 0; i < 4; ++i)
            #pragma unroll
            for (int j = 0; j < 8; ++j) acc[i][j] = 0.f;

        for (int kc = 0; kc < Dm / BK; ++kc) {
            __syncthreads();
            #pragma unroll
            for (int r = 0; r < 4; ++r) {
                int f = r * 256 + t;
                int kk = f >> 4, q4 = (f & 15) << 2;
                float4 v = *reinterpret_cast<const float4*>(zb + (size_t)(kc * BK + kk) * HW + q4);
                *reinterpret_cast<float4*>(&zlds[kk][q4]) = v;
            }
            #pragma unroll
            for (int r = 0; r < 8; ++r) {
                int f = r * 256 + t;
                int n = f >> 4, k4 = (f & 15) << 2;
                float4 v = *reinterpret_cast<const float4*>(emb + (size_t)(n0 + n) * Dm + kc * BK + k4);
                el[k4 + 0][n] = v.x; el[k4 + 1][n] = v.y;
                el[k4 + 2][n] = v.z; el[k4 + 3][n] = v.w;
            }
            __syncthreads();
            #pragma unroll 4
            for (int kk = 0; kk < BK; ++kk) {
                float4 zf = *reinterpret_cast<const float4*>(&zlds[kk][tq << 2]);
                float4 e0 = *reinterpret_cast<const float4*>(&el[kk][tn << 3]);
                float4 e1 = *reinterpret_cast<const float4*>(&el[kk][(tn << 3) + 4]);
                float zr[4] = { zf.x, zf.y, zf.z, zf.w };
                float er[8] = { e0.x, e0.y, e0.z, e0.w, e1.x, e1.y, e1.z, e1.w };
                #pragma unroll
                for (int i = 0; i < 4; ++i)
                    #pragma unroll
                    for (int j = 0; j < 8; ++j)
                        acc[i][j] = fmaf(zr[i], er[j], acc[i][j]);
            }
        }
        #pragma unroll
        for (int j = 0; j < 8; ++j) {
            int ng = n0 + (tn << 3) + j;
            float en = enorm[ng];
            #pragma unroll
            for (int i = 0; i < 4; ++i) {
                float s = fmaf(-2.f, acc[i][j], en);
                if (s < d1[i]) { d2[i] = d1[i]; d1[i] = s; i1[i] = ng; }
                else if (s < d2[i]) d2[i] = s;
            }
        }
    }
    #pragma unroll
    for (int off = 16; off <= 32; off <<= 1) {
        #pragma unroll
        for (int i = 0; i < 4; ++i) {
            float od1 = __shfl_xor(d1[i], off);
            int   oi1 = __shfl_xor(i1[i], off);
            float od2 = __shfl_xor(d2[i], off);
            float nd2 = fminf(fminf(d2[i], od2), fmaxf(d1[i], od1));
            bool take = (od1 < d1[i]) || (od1 == d1[i] && oi1 < i1[i]);
            if (take) { d1[i] = od1; i1[i] = oi1; }
            d2[i] = nd2;
        }
    }
    int w = t >> 6;
    if ((t & 63) < 16) {
        #pragma unroll
        for (int i = 0; i < 4; ++i) {
            rd1[w][(tq << 2) + i] = d1[i];
            ri1[w][(tq << 2) + i] = i1[i];
            rd2[w][(tq << 2) + i] = d2[i];
        }
    }
    __syncthreads();
    if (t < 64) {
        float bd1 = rd1[0][t]; int bi1 = ri1[0][t]; float bd2 = rd2[0][t];
        #pragma unroll
        for (int ww = 1; ww < 4; ++ww) {
            float od1 = rd1[ww][t]; int oi1 = ri1[ww][t]; float od2 = rd2[ww][t];
            float nd2 = fminf(fminf(bd2, od2), fmaxf(bd1, od1));
            if (od1 < bd1 || (od1 == bd1 && oi1 < bi1)) { bd1 = od1; bi1 = oi1; }
            bd2 = nd2;
        }
        int l = l0 + t;
        ws_idx[l] = bi1;
        out_idxf[l] = (float)bi1;
        if (bd2 - bd1 < TAU) {
            int pos = atomicAdd(flag_cnt, 1);
            flag_list[pos] = l;
        } else {
            used[bi1] = 1.0f;
        }
    }
}

// ---------------- K_refine scan: parallel (query x 256-code chunk) fp64 partial argmin ----------------
__global__ __launch_bounds__(256) void k_refine_scan(
    const float* __restrict__ z, const float* __restrict__ emb,
    const int* __restrict__ flag_cnt, const int* __restrict__ flag_list,
    double* __restrict__ pbd, int* __restrict__ pbi)
{
    __shared__ float zrow[Dm];
    __shared__ double sd[256];
    __shared__ int    si[256];
    const int t = threadIdx.x;
    const int ntask = *flag_cnt * 8;
    for (int task = blockIdx.x; task < ntask; task += gridDim.x) {
        const int fi = task >> 3, chunk = task & 7;
        const int l = flag_list[fi];
        const int b = l >> 10, p = l & 1023;
        const float* zq = z + (size_t)b * (Dm * HW) + p;
        __syncthreads();
        zrow[t] = zq[(size_t)t * HW];
        __syncthreads();
        const int n = chunk * 256 + t;
        const float* er = emb + (size_t)n * Dm;
        double dt0 = 0.0, dt1 = 0.0, dt2 = 0.0, dt3 = 0.0;
        double nm0 = 0.0, nm1 = 0.0, nm2 = 0.0, nm3 = 0.0;
        for (int c = 0; c < Dm; c += 4) {
            double e0 = er[c], e1 = er[c + 1], e2 = er[c + 2], e3 = er[c + 3];
            dt0 += e0 * (double)zrow[c];     nm0 += e0 * e0;
            dt1 += e1 * (double)zrow[c + 1]; nm1 += e1 * e1;
            dt2 += e2 * (double)zrow[c + 2]; nm2 += e2 * e2;
            dt3 += e3 * (double)zrow[c + 3]; nm3 += e3 * e3;
        }
        sd[t] = (nm0 + nm1) + (nm2 + nm3) - 2.0 * ((dt0 + dt1) + (dt2 + dt3));
        si[t] = n;
        __syncthreads();
        for (int st = 128; st; st >>= 1) {
            if (t < st) {
                double od = sd[t + st]; int oi = si[t + st];
                if (od < sd[t] || (od == sd[t] && oi < si[t])) { sd[t] = od; si[t] = oi; }
            }
            __syncthreads();
        }
        if (t == 0) { pbd[task] = sd[0]; pbi[task] = si[0]; }
    }
}

// ---------------- K_refine merge: 8-way lexicographic combine + outputs + outq patch ----------------
__global__ __launch_bounds__(256) void k_refine_merge(
    const float* __restrict__ emb, const int* __restrict__ flag_cnt,
    const int* __restrict__ flag_list, const double* __restrict__ pbd,
    const int* __restrict__ pbi, int* __restrict__ ws_idx,
    float* __restrict__ out_idxf, float* __restrict__ used,
    float* __restrict__ outq)
{
    __shared__ int bestn;
    const int t = threadIdx.x;
    const int nf = *flag_cnt;
    for (int fi = blockIdx.x; fi < nf; fi += gridDim.x) {
        const int l = flag_list[fi];
        __syncthreads();
        if (t == 0) {
            double bd = pbd[fi * 8]; int bi = pbi[fi * 8];
            #pragma unroll
            for (int c = 1; c < 8; ++c) {
                double od = pbd[fi * 8 + c]; int oi = pbi[fi * 8 + c];
                if (od < bd || (od == bd && oi < bi)) { bd = od; bi = oi; }
            }
            ws_idx[l] = bi;
            out_idxf[l] = (float)bi;
            used[bi] = 1.0f;
            bestn = bi;
        }
        __syncthreads();
        const int b = l >> 10, p = l & 1023;
        outq[(size_t)b * (Dm * HW) + (size_t)t * HW + p] = emb[(size_t)bestn * Dm + t];
    }
}

// ---------------- fallback serial refine (r8-proven) ----------------
__global__ void k_refine(const float* __restrict__ z, const float* __restrict__ emb,
                         const int* __restrict__ flag_cnt, const int* __restrict__ flag_list,
                         int* __restrict__ ws_idx, float* __restrict__ out_idxf,
                         float* __restrict__ used, float* __restrict__ outq)
{
    __shared__ float zrow[Dm];
    __shared__ double sd[256];
    __shared__ int    si[256];
    int nf = *flag_cnt;
    for (int fi = blockIdx.x; fi < nf; fi += gridDim.x) {
        int l = flag_list[fi];
        int b = l >> 10, p = l & 1023;
        const float* zq = z + (size_t)b * (Dm * HW) + p;
        __syncthreads();
        for (int c = threadIdx.x; c < Dm; c += blockDim.x) zrow[c] = zq[(size_t)c * HW];
        __syncthreads();
        double bd = DBL_MAX; int bi = 0;
        for (int nb = 0; nb < NE / 256; ++nb) {
            int n = nb * 256 + threadIdx.x;
            const float* er = emb + (size_t)n * Dm;
            double dt0 = 0.0, dt1 = 0.0, dt2 = 0.0, dt3 = 0.0;
            double nm0 = 0.0, nm1 = 0.0, nm2 = 0.0, nm3 = 0.0;
            for (int c = 0; c < Dm; c += 4) {
                double e0 = er[c], e1 = er[c + 1], e2 = er[c + 2], e3 = er[c + 3];
                dt0 += e0 * (double)zrow[c];     nm0 += e0 * e0;
                dt1 += e1 * (double)zrow[c + 1]; nm1 += e1 * e1;
                dt2 += e2 * (double)zrow[c + 2]; nm2 += e2 * e2;
                dt3 += e3 * (double)zrow[c + 3]; nm3 += e3 * e3;
            }
            double s = (nm0 + nm1) + (nm2 + nm3) - 2.0 * ((dt0 + dt1) + (dt2 + dt3));
            if (s < bd) { bd = s; bi = n; }
        }
        sd[threadIdx.x] = bd; si[threadIdx.x] = bi;
        __syncthreads();
        for (int st = 128; st; st >>= 1) {
            if (threadIdx.x < (unsigned)st) {
                double od = sd[threadIdx.x + st]; int oi = si[threadIdx.x + st];
                if (od < sd[threadIdx.x] || (od == sd[threadIdx.x] && oi < si[threadIdx.x])) {
                    sd[threadIdx.x] = od; si[threadIdx.x] = oi;
                }
            }
            __syncthreads();
        }
        if (threadIdx.x == 0) {
            ws_idx[l] = si[0];
            out_idxf[l] = (float)si[0];
            used[si[0]] = 1.0f;
        }
        __syncthreads();
        int bi0 = si[0];
        int c = threadIdx.x;
        outq[(size_t)b * (Dm * HW) + (size_t)c * HW + p] = emb[(size_t)bi0 * Dm + c];
        __syncthreads();
    }
}

// ---------------- fallback gather+loss ----------------
__global__ __launch_bounds__(256) void k_gather_loss(
    const float* __restrict__ z, const float* __restrict__ emb,
    const int* __restrict__ ws_idx, float* __restrict__ outq,
    float* __restrict__ partials)
{
    __shared__ int sidx[64];
    __shared__ float eldT[Dm][65];
    __shared__ float wsum[4];
    const int t = threadIdx.x;
    const int l0 = blockIdx.x * 64;
    const int b = l0 >> 10, p0 = l0 & 1023;
    if (t < 64) sidx[t] = ws_idx[l0 + t];
    __syncthreads();
    int w = t >> 6, lane = t & 63;
    for (int r = 0; r < 16; ++r) {
        int q = r * 4 + w;
        const float4 v = *reinterpret_cast<const float4*>(emb + (size_t)sidx[q] * Dm + lane * 4);
        eldT[lane * 4 + 0][q] = v.x; eldT[lane * 4 + 1][q] = v.y;
        eldT[lane * 4 + 2][q] = v.z; eldT[lane * 4 + 3][q] = v.w;
    }
    __syncthreads();
    float ls = 0.f;
    const size_t obase = (size_t)b * (Dm * HW) + p0 + lane;
    for (int it = 0; it < 64; ++it) {
        int c = w * 64 + it;
        size_t o = obase + (size_t)c * HW;
        float qv = eldT[c][lane];
        float zv = z[o];
        outq[o] = qv;
        float df = qv - zv;
        ls = fmaf(df, df, ls);
    }
    #pragma unroll
    for (int off = 32; off; off >>= 1) ls += __shfl_xor(ls, off);
    if (lane == 0) wsum[w] = ls;
    __syncthreads();
    if (t == 0) partials[blockIdx.x] = wsum[0] + wsum[1] + wsum[2] + wsum[3];
}

// ---------------- final: loss = (Sum||z||^2 + Sum d1)/count, used count ----------------
__global__ void k_final(const float* __restrict__ zn_part, const float* __restrict__ d1_part,
                        int nd1, const float* __restrict__ used,
                        float* __restrict__ out_loss, float* __restrict__ out_used)
{
    __shared__ double s1[256];
    __shared__ float  s2[256];
    int t = threadIdx.x;
    double a = 0.0;
    for (int i = t; i < 1024; i += 256) a += (double)zn_part[i];
    for (int i = t; i < nd1; i += 256) a += (double)d1_part[i];
    float u = 0.f;
    for (int i = t; i < NE; i += 256) u += used[i];
    s1[t] = a; s2[t] = u;
    __syncthreads();
    for (int st = 128; st; st >>= 1) {
        if (t < st) { s1[t] += s1[t + st]; s2[t] += s2[t + st]; }
        __syncthreads();
    }
    if (t == 0) { *out_loss = (float)(s1[0] / 8388608.0); *out_used = s2[0]; }
}

// ---------------- fallback final ----------------
__global__ void k_final_fb(const float* __restrict__ partials, const float* __restrict__ used,
                           float* __restrict__ out_loss, float* __restrict__ out_used)
{
    __shared__ float s1[256], s2[256];
    int t = threadIdx.x;
    float a = partials[t] + partials[t + 256];
    float u = 0.f;
    for (int i = t; i < NE; i += 256) u += used[i];
    s1[t] = a; s2[t] = u;
    __syncthreads();
    for (int st = 128; st; st >>= 1) {
        if (t < st) { s1[t] += s1[t + st]; s2[t] += s2[t + st]; }
        __syncthreads();
    }
    if (t == 0) { *out_loss = s1[0] / 8388608.f; *out_used = s2[0]; }
}

extern "C" void kernel_launch(void* const* d_in, const int* in_sizes, int n_in,
                              void* d_out, int out_size, void* d_ws, size_t ws_size,
                              hipStream_t stream) {
    const float* z   = (const float*)d_in[0];
    const float* emb = (const float*)d_in[1];
    float* out      = (float*)d_out;
    float* outq     = out;
    float* out_loss = out + QOFF;
    float* out_idxf = out + QOFF + 1;
    float* out_used = out + QOFF + 1 + L_TOT;

    float* ws       = (float*)d_ws;
    float* enorm    = ws;                         // [0, 2048)
    float* used     = ws + 2048;                  // [2048, 4096)
    float* zn_part  = ws + 4096;                  // [4096, 5120)
    float* d1_part  = ws + 5120;                  // [5120, 5632)  512
    int*   flag_cnt = (int*)(ws + 5632);          // 1 (+pad)
    int*   ws_idx   = (int*)(ws + 5888);          // 32768
    int*   flag_list= (int*)(ws + 5888 + L_TOT);  // 32768 -> ends 71424

    // 2-stripe partials
    float* pd1w = ws + 71680;                     // 65536
    float* pd2w = ws + 137216;                    // 65536
    int*   pi1w = (int*)(ws + 202752);            // 65536 -> ends 268288 floats

    size_t i8_bytes = 2ull * (NE + L_TOT) * Dm;   // 17825792
    size_t pbd_off_f = 268288 + i8_bytes / 4;     // 8B-aligned byte offset
    size_t pbi_off_f = pbd_off_f + 2 * 262144;
    size_t need_i8 = (pbi_off_f + 262144) * 4;    // ~22.1 MB

    if (ws_size >= need_i8) {
        signed char* e_hi8 = (signed char*)(ws + 268288);
        signed char* e_lo8 = e_hi8 + (size_t)NE * Dm;
        signed char* z_hi8 = e_lo8 + (size_t)NE * Dm;
        signed char* z_lo8 = z_hi8 + (size_t)L_TOT * Dm;
        double* pbd = (double*)(ws + pbd_off_f);
        int*    pbi = (int*)(ws + pbi_off_f);
        k_split_i8<<<1024, 256, 0, stream>>>(z, emb, z_hi8, z_lo8, e_hi8, e_lo8,
                                             enorm, zn_part, used, flag_cnt);
        k_score_i8<<<512, 256, 0, stream>>>(z_hi8, z_lo8, e_hi8, e_lo8, enorm,
                                            pd1w, pd2w, pi1w);
        k_mg<<<L_TOT / 64, 256, 0, stream>>>(pd1w, pd2w, pi1w, emb, ws_idx, out_idxf,
                                             used, flag_cnt, flag_list, d1_part, outq);
        k_refine_scan<<<2048, 256, 0, stream>>>(z, emb, flag_cnt, flag_list, pbd, pbi);
        k_refine_merge<<<256, 256, 0, stream>>>(emb, flag_cnt, flag_list, pbd, pbi,
                                                ws_idx, out_idxf, used, outq);
        k_final<<<1, 256, 0, stream>>>(zn_part, d1_part, 512, used, out_loss, out_used);
    } else {
        hipMemsetAsync(used, 0, (size_t)3584 * 4, stream);
        k_enorm<<<NE / 4, 256, 0, stream>>>(emb, enorm);
        k_argmin_f32<<<L_TOT / BM, 256, 0, stream>>>(z, emb, enorm, ws_idx, out_idxf, used,
                                                     flag_cnt, flag_list);
        k_refine<<<256, 256, 0, stream>>>(z, emb, flag_cnt, flag_list, ws_idx, out_idxf,
                                          used, outq);
        k_gather_loss<<<L_TOT / 64, 256, 0, stream>>>(z, emb, ws_idx, outq, zn_part);
        k_final_fb<<<1, 256, 0, stream>>>(zn_part, used, out_loss, out_used);
    }
}

// Round 20
// 215.792 us; speedup vs baseline: 1.8488x; 1.0036x over previous
//
#include <hip/hip_runtime.h>
#include <cfloat>

#define Dm 256
#define HW 1024
#define NE 2048
#define L_TOT 32768
#define QOFF 8388608   // B*C*H*W
#define TAU 0.1f

#define QSCALE 4064.0f               // 32512/8
#define CHC 7.93613e-3f              // 2*65536/QSCALE^2
#define CXC 3.10005e-5f              // 2*256/QSCALE^2

typedef __attribute__((ext_vector_type(4))) int i32x4;
typedef const __attribute__((address_space(1))) unsigned int* as1_u32p;
typedef __attribute__((address_space(3))) unsigned int* as3_u32p;

#define GLL(gp, lp) __builtin_amdgcn_global_load_lds((as1_u32p)(gp), (as3_u32p)(lp), 16, 0, 0)

__device__ __forceinline__ void q8(float x, signed char& hi, signed char& lo) {
    int xi = __float2int_rn(x * QSCALE);
    xi = max(-32512, min(32512, xi));
    int h = (xi + 128) >> 8;
    hi = (signed char)h;
    lo = (signed char)(xi - (h << 8));
}

// ---------------- K1 (fallback only): code norms ----------------
__global__ void k_enorm(const float* __restrict__ emb, float* __restrict__ enorm) {
    int w = threadIdx.x >> 6, lane = threadIdx.x & 63;
    int n = blockIdx.x * 4 + w;
    const float4 v = *reinterpret_cast<const float4*>(emb + (size_t)n * Dm + lane * 4);
    double s = (double)v.x * v.x + (double)v.y * v.y + (double)v.z * v.z + (double)v.w * v.w;
    #pragma unroll
    for (int off = 32; off; off >>= 1) s += __shfl_xor(s, off);
    if (lane == 0) enorm[n] = (float)s;
}

// ---------------- fused: i8 split Z (transpose, float4 reads) + split E + norms ----------------
__global__ __launch_bounds__(256) void k_split_i8(
    const float* __restrict__ z, const float* __restrict__ emb,
    signed char* __restrict__ z_hi, signed char* __restrict__ z_lo,
    signed char* __restrict__ e_hi, signed char* __restrict__ e_lo,
    float* __restrict__ enorm, float* __restrict__ zn_part,
    float* __restrict__ used, int* __restrict__ flag_cnt)
{
    __shared__ signed char zh[32][264];
    __shared__ signed char zl[32][264];
    __shared__ double zsum[4];
    const int t = threadIdx.x;
    const int w = t >> 6, lane = t & 63;

    if (blockIdx.x >= 16 && blockIdx.x < 24) used[(blockIdx.x - 16) * 256 + t] = 0.f;
    if (blockIdx.x == 24 && t == 0) *flag_cnt = 0;

    // fused E-split: waves 0,1 each handle one emb row
    if (w < 2) {
        int n = blockIdx.x * 2 + w;
        const float4 v = *reinterpret_cast<const float4*>(emb + (size_t)n * Dm + lane * 4);
        float vv[4] = { v.x, v.y, v.z, v.w };
        double s = (double)v.x * v.x + (double)v.y * v.y + (double)v.z * v.z + (double)v.w * v.w;
        #pragma unroll
        for (int off = 32; off; off >>= 1) s += __shfl_xor(s, off);
        if (lane == 0) enorm[n] = (float)s;
        signed char h4[4], l4[4];
        #pragma unroll
        for (int j = 0; j < 4; ++j) q8(vv[j], h4[j], l4[j]);
        *reinterpret_cast<int*>(e_hi + (size_t)n * Dm + lane * 4) = *reinterpret_cast<int*>(h4);
        *reinterpret_cast<int*>(e_lo + (size_t)n * Dm + lane * 4) = *reinterpret_cast<int*>(l4);
    }

    // Z split+transpose + ||z||^2 partial: float4 along HW (4x fewer load issues)
    const int b  = blockIdx.x >> 5;
    const int p0 = (blockIdx.x & 31) * 32;
    const int cq = t >> 3;                        // channel within round
    const int q  = t & 7;                         // HW quad -> positions q*4..q*4+3
    const float* zb = z + (size_t)b * (Dm * HW) + p0 + q * 4;
    float zs = 0.f;
    #pragma unroll
    for (int ci = 0; ci < 8; ++ci) {
        int c = ci * 32 + cq;
        float4 v = *reinterpret_cast<const float4*>(zb + (size_t)c * HW);
        float vv[4] = { v.x, v.y, v.z, v.w };
        #pragma unroll
        for (int j = 0; j < 4; ++j) {
            zs = fmaf(vv[j], vv[j], zs);
            q8(vv[j], zh[q * 4 + j][c], zl[q * 4 + j][c]);
        }
    }
    double d = zs;
    #pragma unroll
    for (int off = 32; off; off >>= 1) d += __shfl_xor(d, off);
    if ((t & 63) == 0) zsum[w] = d;
    __syncthreads();
    if (t == 0) zn_part[blockIdx.x] = (float)(zsum[0] + zsum[1] + zsum[2] + zsum[3]);
    const int l0 = b * 1024 + p0;
    #pragma unroll
    for (int r = 0; r < 8; ++r) {
        int id = r * 256 + t;
        int row = id >> 6, ch = id & 63;
        *reinterpret_cast<int*>(z_hi + (size_t)(l0 + row) * Dm + ch * 4) =
            *reinterpret_cast<int*>(&zh[row][ch * 4]);
        *reinterpret_cast<int*>(z_lo + (size_t)(l0 + row) * Dm + ch * 4) =
            *reinterpret_cast<int*>(&zl[row][ch * 4]);
    }
}

// ---------------- K2: i8 score GEMM, A-resident LDS + counted-vmcnt (r19-proven, verbatim) ----------------
__global__ __launch_bounds__(256, 2) void k_score_i8(
    const signed char* __restrict__ zh, const signed char* __restrict__ zl,
    const signed char* __restrict__ eh, const signed char* __restrict__ el,
    const float* __restrict__ enorm,
    float* __restrict__ pd1, float* __restrict__ pd2, int* __restrict__ pi1)
{
    __shared__ signed char ldsA[65536];    // 8 regions (arr2 x kc4) of 8 KB
    __shared__ signed char ldsB[2][8192];  // double-buffered B chunk (K=64)

    const int t    = threadIdx.x;
    const int lane = t & 63, w = t >> 6;
    const int wm = w >> 1, wc = w & 1;
    const int c15 = lane & 15, g4 = lane >> 4;

    const int bx = blockIdx.x;
    const int wg = (bx & 7) * 64 + (bx >> 3);
    const int mi = wg >> 1, ni = wg & 1;
    const int l0 = mi * 128;
    const int nbase = ni * 1024;

    const int srow = t & 127;
    const int sc16 = t >> 7;
    const unsigned abase = (unsigned)((l0 + srow) * Dm);
    const unsigned bbase = (unsigned)((nbase + srow) * Dm);
    const int ldd = t * 16;

    #pragma unroll
    for (int arr = 0; arr < 2; ++arr) {
        const signed char* As = arr ? zl : zh;
        #pragma unroll
        for (int kc = 0; kc < 4; ++kc) {
            #pragma unroll
            for (int r = 0; r < 2; ++r) {
                GLL(As + abase + kc * 64 + (r * 2 + sc16) * 16,
                    &ldsA[((arr * 4 + kc) * 2 + r) * 4096 + ldd]);
            }
        }
    }
    #pragma unroll
    for (int r = 0; r < 2; ++r)
        GLL(eh + bbase + (r * 2 + sc16) * 16, &ldsB[0][r * 4096 + ldd]);
    __syncthreads();

    int rowA[4], offB[4];
    #pragma unroll
    for (int m = 0; m < 4; ++m) rowA[m] = g4 * 2048 + (wm * 64 + m * 16 + c15) * 16;
    #pragma unroll
    for (int n = 0; n < 4; ++n) offB[n] = g4 * 2048 + (wc * 64 + n * 16 + c15) * 16;

    float d1[4][4], d2[4][4]; int i1[4][4];
    #pragma unroll
    for (int m = 0; m < 4; ++m)
        #pragma unroll
        for (int r = 0; r < 4; ++r) { d1[m][r] = 3.4e38f; d2[m][r] = 3.4e38f; i1[m][r] = 0; }

    int cur = 0;
    for (int nt = 0; nt < 8; ++nt) {
        i32x4 accH[4][4], accX[4][4];
        #pragma unroll
        for (int m = 0; m < 4; ++m)
            #pragma unroll
            for (int n = 0; n < 4; ++n) {
                accH[m][n] = (i32x4){0, 0, 0, 0};
                accX[m][n] = (i32x4){0, 0, 0, 0};
            }

        #pragma unroll
        for (int c = 0; c < 8; ++c) {
            const bool last = (c == 7 && nt == 7);
            if (!last) {
                int nc = c + 1, nnt = nt;
                if (nc == 8) { nc = 0; ++nnt; }
                const signed char* Bs = (nc < 4) ? eh : el;
                const unsigned boff = bbase + ((unsigned)nnt << 15) + (unsigned)((nc & 3) * 64);
                #pragma unroll
                for (int r = 0; r < 2; ++r)
                    GLL(Bs + boff + (r * 2 + sc16) * 16, &ldsB[cur ^ 1][r * 4096 + ldd]);
                asm volatile("s_waitcnt vmcnt(2)" ::: "memory");
            } else {
                asm volatile("s_waitcnt vmcnt(0)" ::: "memory");
            }
            __builtin_amdgcn_sched_barrier(0);
            __builtin_amdgcn_s_barrier();            // A: stage(c) landed everywhere
            __builtin_amdgcn_sched_barrier(0);

            const int kc = c & 3;
            i32x4 bfv[4];
            #pragma unroll
            for (int n = 0; n < 4; ++n)
                bfv[n] = *reinterpret_cast<const i32x4*>(&ldsB[cur][offB[n]]);
            if (c < 4) {
                i32x4 afh[4], afl[4];
                #pragma unroll
                for (int m = 0; m < 4; ++m) {
                    afh[m] = *reinterpret_cast<const i32x4*>(&ldsA[kc * 8192 + rowA[m]]);
                    afl[m] = *reinterpret_cast<const i32x4*>(&ldsA[(4 + kc) * 8192 + rowA[m]]);
                }
                __builtin_amdgcn_s_setprio(1);
                #pragma unroll
                for (int m = 0; m < 4; ++m)
                    #pragma unroll
                    for (int n = 0; n < 4; ++n) {
                        accH[m][n] = __builtin_amdgcn_mfma_i32_16x16x64_i8(
                            afh[m], bfv[n], accH[m][n], 0, 0, 0);
                        accX[m][n] = __builtin_amdgcn_mfma_i32_16x16x64_i8(
                            afl[m], bfv[n], accX[m][n], 0, 0, 0);
                    }
                __builtin_amdgcn_s_setprio(0);
            } else {
                i32x4 afh[4];
                #pragma unroll
                for (int m = 0; m < 4; ++m)
                    afh[m] = *reinterpret_cast<const i32x4*>(&ldsA[kc * 8192 + rowA[m]]);
                __builtin_amdgcn_s_setprio(1);
                #pragma unroll
                for (int m = 0; m < 4; ++m)
                    #pragma unroll
                    for (int n = 0; n < 4; ++n)
                        accX[m][n] = __builtin_amdgcn_mfma_i32_16x16x64_i8(
                            afh[m], bfv[n], accX[m][n], 0, 0, 0);
                __builtin_amdgcn_s_setprio(0);
            }
            asm volatile("s_waitcnt lgkmcnt(0)" ::: "memory");
            __builtin_amdgcn_sched_barrier(0);
            __builtin_amdgcn_s_barrier();            // B: WAR for buf[cur]
            __builtin_amdgcn_sched_barrier(0);
            cur ^= 1;
        }

        int n0 = nbase + nt * 128;
        #pragma unroll
        for (int n = 0; n < 4; ++n) {
            int ng = n0 + wc * 64 + n * 16 + c15;
            float en = enorm[ng];
            #pragma unroll
            for (int m = 0; m < 4; ++m)
                #pragma unroll
                for (int r = 0; r < 4; ++r) {
                    float sx = fmaf(-CXC, (float)accX[m][n][r], en);
                    float s  = fmaf(-CHC, (float)accH[m][n][r], sx);
                    if (s < d1[m][r]) { d2[m][r] = d1[m][r]; d1[m][r] = s; i1[m][r] = ng; }
                    else if (s < d2[m][r]) d2[m][r] = s;
                }
        }
    }

    #pragma unroll
    for (int off = 1; off <= 8; off <<= 1) {
        #pragma unroll
        for (int m = 0; m < 4; ++m)
            #pragma unroll
            for (int r = 0; r < 4; ++r) {
                float od1 = __shfl_xor(d1[m][r], off);
                int   oi1 = __shfl_xor(i1[m][r], off);
                float od2 = __shfl_xor(d2[m][r], off);
                float nd2 = fminf(fminf(d2[m][r], od2), fmaxf(d1[m][r], od1));
                if (od1 < d1[m][r] || (od1 == d1[m][r] && oi1 < i1[m][r])) {
                    d1[m][r] = od1; i1[m][r] = oi1;
                }
                d2[m][r] = nd2;
            }
    }

    float* rs1 = (float*)&ldsA[0];
    float* rs2 = rs1 + 128;
    int*   ri  = (int*)(rs2 + 128);
    if (wc == 1 && c15 == 0) {
        #pragma unroll
        for (int m = 0; m < 4; ++m)
            #pragma unroll
            for (int r = 0; r < 4; ++r) {
                int q = wm * 64 + m * 16 + g4 * 4 + r;
                rs1[q] = d1[m][r];
                rs2[q] = d2[m][r];
                ri [q] = i1[m][r];
            }
    }
    __syncthreads();
    if (wc == 0 && c15 == 0) {
        #pragma unroll
        for (int m = 0; m < 4; ++m)
            #pragma unroll
            for (int r = 0; r < 4; ++r) {
                int q = wm * 64 + m * 16 + g4 * 4 + r;
                float bd1 = d1[m][r], bd2 = d2[m][r]; int bi1 = i1[m][r];
                float od1 = rs1[q], od2 = rs2[q];
                int   oi1 = ri [q];
                float nd2 = fminf(fminf(bd2, od2), fmaxf(bd1, od1));
                if (od1 < bd1 || (od1 == bd1 && oi1 < bi1)) { bd1 = od1; bi1 = oi1; }
                bd2 = nd2;
                int gq = l0 + q;
                pd1[ni * L_TOT + gq] = bd1;
                pd2[ni * L_TOT + gq] = bd2;
                pi1[ni * L_TOT + gq] = bi1;
            }
    }
}

// ---------------- fused merge (2 stripes) + gather ----------------
__global__ __launch_bounds__(256) void k_mg(
    const float* __restrict__ pd1, const float* __restrict__ pd2,
    const int* __restrict__ pi1, const float* __restrict__ emb,
    int* __restrict__ ws_idx, float* __restrict__ out_idxf,
    float* __restrict__ used, int* __restrict__ flag_cnt,
    int* __restrict__ flag_list, float* __restrict__ d1_part,
    float* __restrict__ outq)
{
    __shared__ int sidx[64];
    __shared__ float eldT[Dm][65];
    const int t = threadIdx.x;
    const int l0 = blockIdx.x * 64;
    const int b = l0 >> 10, p0 = l0 & 1023;

    if (t < 64) {
        int gq = l0 + t;
        float d1 = pd1[gq], d2 = pd2[gq]; int i1 = pi1[gq];
        float od1 = pd1[L_TOT + gq], od2 = pd2[L_TOT + gq];
        int   oi1 = pi1[L_TOT + gq];
        float nd2 = fminf(fminf(d2, od2), fmaxf(d1, od1));
        if (od1 < d1 || (od1 == d1 && oi1 < i1)) { d1 = od1; i1 = oi1; }
        d2 = nd2;
        ws_idx[gq] = i1;
        out_idxf[gq] = (float)i1;
        if (d2 - d1 < TAU) {
            int pos = atomicAdd(flag_cnt, 1);
            flag_list[pos] = gq;
        } else {
            used[i1] = 1.0f;
        }
        sidx[t] = i1;
        float s = d1;
        #pragma unroll
        for (int off = 32; off; off >>= 1) s += __shfl_xor(s, off);
        if (t == 0) d1_part[blockIdx.x] = s;
    }
    __syncthreads();

    int w = t >> 6, lane = t & 63;
    for (int r = 0; r < 16; ++r) {
        int q = r * 4 + w;
        const float4 v = *reinterpret_cast<const float4*>(emb + (size_t)sidx[q] * Dm + lane * 4);
        eldT[lane * 4 + 0][q] = v.x; eldT[lane * 4 + 1][q] = v.y;
        eldT[lane * 4 + 2][q] = v.z; eldT[lane * 4 + 3][q] = v.w;
    }
    __syncthreads();
    const size_t obase = (size_t)b * (Dm * HW) + p0 + lane;
    #pragma unroll 4
    for (int it = 0; it < 64; ++it) {
        int c = w * 64 + it;
        outq[obase + (size_t)c * HW] = eldT[c][lane];
    }
}

// ---------------- fallback fp32 argmin (round-1 proven) ----------------
#define BM 64
#define BN 128
#define BK 64
__global__ __launch_bounds__(256, 2) void k_argmin_f32(
    const float* __restrict__ z, const float* __restrict__ emb,
    const float* __restrict__ enorm, int* __restrict__ ws_idx,
    float* __restrict__ out_idxf, float* __restrict__ used,
    int* __restrict__ flag_cnt, int* __restrict__ flag_list)
{
    __shared__ float zlds[BK][BM];
    __shared__ float el[BK][BN + 4];
    __shared__ float rd1[4][64];
    __shared__ int   ri1[4][64];
    __shared__ float rd2[4][64];

    const int t  = threadIdx.x;
    const int tq = t & 15;
    const int tn = t >> 4;
    const int l0 = blockIdx.x * BM;
    const int b  = l0 >> 10, p0 = l0 & 1023;
    const float* zb = z + (size_t)b * (Dm * HW) + p0;

    float d1[4], d2[4]; int i1[4];
    #pragma unroll
    for (int i = 0; i < 4; ++i) { d1[i] = FLT_MAX; d2[i] = FLT_MAX; i1[i] = 0; }

    for (int nt = 0; nt < NE / BN; ++nt) {
        const int n0 = nt * BN;
        float acc[4][8];
        #pragma unroll
        for (int i = 0; i < 4; ++i)
            #pragma unroll
            for (int j = 0; j < 8; ++j) acc[i][j] = 0.f;

        for (int kc = 0; kc < Dm / BK; ++kc) {
            __syncthreads();
            #pragma unroll
            for (int r = 0; r < 4; ++r) {
                int f = r * 256 + t;
                int kk = f >> 4, q4 = (f & 15) << 2;
                float4 v = *reinterpret_cast<const float4*>(zb + (size_t)(kc * BK + kk) * HW + q4);
                *reinterpret_cast<float4*>(&zlds[kk][q4]) = v;
            }
            #pragma unroll
            for (int r = 0; r < 8; ++r) {
                int f = r * 256 + t;
                int n = f >> 4, k4 = (f & 15) << 2;
                float4 v = *reinterpret_cast<const float4*>(emb + (size_t)(n0 + n) * Dm + kc * BK + k4);
                el[k4 + 0][n] = v.x; el[k4 + 1][n] = v.y;
                el[k4 + 2][n] = v.z; el[k4 + 3][n] = v.w;
            }
            __syncthreads();
            #pragma unroll 4
            for (int kk = 0; kk < BK; ++kk) {
                float4 zf = *reinterpret_cast<const float4*>(&zlds[kk][tq << 2]);
                float4 e0 = *reinterpret_cast<const float4*>(&el[kk][tn << 3]);
                float4 e1 = *reinterpret_cast<const float4*>(&el[kk][(tn << 3) + 4]);
                float zr[4] = { zf.x, zf.y, zf.z, zf.w };
                float er[8] = { e0.x, e0.y, e0.z, e0.w, e1.x, e1.y, e1.z, e1.w };
                #pragma unroll
                for (int i = 0; i < 4; ++i)
                    #pragma unroll
                    for (int j = 0; j < 8; ++j)
                        acc[i][j] = fmaf(zr[i], er[j], acc[i][j]);
            }
        }
        #pragma unroll
        for (int j = 0; j < 8; ++j) {
            int ng = n0 + (tn << 3) + j;
            float en = enorm[ng];
            #pragma unroll
            for (int i = 0; i < 4; ++i) {
                float s = fmaf(-2.f, acc[i][j], en);
                if (s < d1[i]) { d2[i] = d1[i]; d1[i] = s; i1[i] = ng; }
                else if (s < d2[i]) d2[i] = s;
            }
        }
    }
    #pragma unroll
    for (int off = 16; off <= 32; off <<= 1) {
        #pragma unroll
        for (int i = 0; i < 4; ++i) {
            float od1 = __shfl_xor(d1[i], off);
            int   oi1 = __shfl_xor(i1[i], off);
            float od2 = __shfl_xor(d2[i], off);
            float nd2 = fminf(fminf(d2[i], od2), fmaxf(d1[i], od1));
            bool take = (od1 < d1[i]) || (od1 == d1[i] && oi1 < i1[i]);
            if (take) { d1[i] = od1; i1[i] = oi1; }
            d2[i] = nd2;
        }
    }
    int w = t >> 6;
    if ((t & 63) < 16) {
        #pragma unroll
        for (int i = 0; i < 4; ++i) {
            rd1[w][(tq << 2) + i] = d1[i];
            ri1[w][(tq << 2) + i] = i1[i];
            rd2[w][(tq << 2) + i] = d2[i];
        }
    }
    __syncthreads();
    if (t < 64) {
        float bd1 = rd1[0][t]; int bi1 = ri1[0][t]; float bd2 = rd2[0][t];
        #pragma unroll
        for (int ww = 1; ww < 4; ++ww) {
            float od1 = rd1[ww][t]; int oi1 = ri1[ww][t]; float od2 = rd2[ww][t];
            float nd2 = fminf(fminf(bd2, od2), fmaxf(bd1, od1));
            if (od1 < bd1 || (od1 == bd1 && oi1 < bi1)) { bd1 = od1; bi1 = oi1; }
            bd2 = nd2;
        }
        int l = l0 + t;
        ws_idx[l] = bi1;
        out_idxf[l] = (float)bi1;
        if (bd2 - bd1 < TAU) {
            int pos = atomicAdd(flag_cnt, 1);
            flag_list[pos] = l;
        } else {
            used[bi1] = 1.0f;
        }
    }
}

// ---------------- K_refine scan: parallel (query x 256-code chunk) fp64 partial argmin ----------------
__global__ __launch_bounds__(256) void k_refine_scan(
    const float* __restrict__ z, const float* __restrict__ emb,
    const int* __restrict__ flag_cnt, const int* __restrict__ flag_list,
    double* __restrict__ pbd, int* __restrict__ pbi)
{
    __shared__ float zrow[Dm];
    __shared__ double sd[256];
    __shared__ int    si[256];
    const int t = threadIdx.x;
    const int ntask = *flag_cnt * 8;
    for (int task = blockIdx.x; task < ntask; task += gridDim.x) {
        const int fi = task >> 3, chunk = task & 7;
        const int l = flag_list[fi];
        const int b = l >> 10, p = l & 1023;
        const float* zq = z + (size_t)b * (Dm * HW) + p;
        __syncthreads();
        zrow[t] = zq[(size_t)t * HW];
        __syncthreads();
        const int n = chunk * 256 + t;
        const float* er = emb + (size_t)n * Dm;
        double dt0 = 0.0, dt1 = 0.0, dt2 = 0.0, dt3 = 0.0;
        double nm0 = 0.0, nm1 = 0.0, nm2 = 0.0, nm3 = 0.0;
        for (int c = 0; c < Dm; c += 4) {
            double e0 = er[c], e1 = er[c + 1], e2 = er[c + 2], e3 = er[c + 3];
            dt0 += e0 * (double)zrow[c];     nm0 += e0 * e0;
            dt1 += e1 * (double)zrow[c + 1]; nm1 += e1 * e1;
            dt2 += e2 * (double)zrow[c + 2]; nm2 += e2 * e2;
            dt3 += e3 * (double)zrow[c + 3]; nm3 += e3 * e3;
        }
        sd[t] = (nm0 + nm1) + (nm2 + nm3) - 2.0 * ((dt0 + dt1) + (dt2 + dt3));
        si[t] = n;
        __syncthreads();
        for (int st = 128; st; st >>= 1) {
            if (t < st) {
                double od = sd[t + st]; int oi = si[t + st];
                if (od < sd[t] || (od == sd[t] && oi < si[t])) { sd[t] = od; si[t] = oi; }
            }
            __syncthreads();
        }
        if (t == 0) { pbd[task] = sd[0]; pbi[task] = si[0]; }
    }
}

// ---------------- K_refine merge: 8-way lexicographic combine + outputs + outq patch ----------------
__global__ __launch_bounds__(256) void k_refine_merge(
    const float* __restrict__ emb, const int* __restrict__ flag_cnt,
    const int* __restrict__ flag_list, const double* __restrict__ pbd,
    const int* __restrict__ pbi, int* __restrict__ ws_idx,
    float* __restrict__ out_idxf, float* __restrict__ used,
    float* __restrict__ outq)
{
    __shared__ int bestn;
    const int t = threadIdx.x;
    const int nf = *flag_cnt;
    for (int fi = blockIdx.x; fi < nf; fi += gridDim.x) {
        const int l = flag_list[fi];
        __syncthreads();
        if (t == 0) {
            double bd = pbd[fi * 8]; int bi = pbi[fi * 8];
            #pragma unroll
            for (int c = 1; c < 8; ++c) {
                double od = pbd[fi * 8 + c]; int oi = pbi[fi * 8 + c];
                if (od < bd || (od == bd && oi < bi)) { bd = od; bi = oi; }
            }
            ws_idx[l] = bi;
            out_idxf[l] = (float)bi;
            used[bi] = 1.0f;
            bestn = bi;
        }
        __syncthreads();
        const int b = l >> 10, p = l & 1023;
        outq[(size_t)b * (Dm * HW) + (size_t)t * HW + p] = emb[(size_t)bestn * Dm + t];
    }
}

// ---------------- fallback serial refine (r8-proven) ----------------
__global__ void k_refine(const float* __restrict__ z, const float* __restrict__ emb,
                         const int* __restrict__ flag_cnt, const int* __restrict__ flag_list,
                         int* __restrict__ ws_idx, float* __restrict__ out_idxf,
                         float* __restrict__ used, float* __restrict__ outq)
{
    __shared__ float zrow[Dm];
    __shared__ double sd[256];
    __shared__ int    si[256];
    int nf = *flag_cnt;
    for (int fi = blockIdx.x; fi < nf; fi += gridDim.x) {
        int l = flag_list[fi];
        int b = l >> 10, p = l & 1023;
        const float* zq = z + (size_t)b * (Dm * HW) + p;
        __syncthreads();
        for (int c = threadIdx.x; c < Dm; c += blockDim.x) zrow[c] = zq[(size_t)c * HW];
        __syncthreads();
        double bd = DBL_MAX; int bi = 0;
        for (int nb = 0; nb < NE / 256; ++nb) {
            int n = nb * 256 + threadIdx.x;
            const float* er = emb + (size_t)n * Dm;
            double dt0 = 0.0, dt1 = 0.0, dt2 = 0.0, dt3 = 0.0;
            double nm0 = 0.0, nm1 = 0.0, nm2 = 0.0, nm3 = 0.0;
            for (int c = 0; c < Dm; c += 4) {
                double e0 = er[c], e1 = er[c + 1], e2 = er[c + 2], e3 = er[c + 3];
                dt0 += e0 * (double)zrow[c];     nm0 += e0 * e0;
                dt1 += e1 * (double)zrow[c + 1]; nm1 += e1 * e1;
                dt2 += e2 * (double)zrow[c + 2]; nm2 += e2 * e2;
                dt3 += e3 * (double)zrow[c + 3]; nm3 += e3 * e3;
            }
            double s = (nm0 + nm1) + (nm2 + nm3) - 2.0 * ((dt0 + dt1) + (dt2 + dt3));
            if (s < bd) { bd = s; bi = n; }
        }
        sd[threadIdx.x] = bd; si[threadIdx.x] = bi;
        __syncthreads();
        for (int st = 128; st; st >>= 1) {
            if (threadIdx.x < (unsigned)st) {
                double od = sd[threadIdx.x + st]; int oi = si[threadIdx.x + st];
                if (od < sd[threadIdx.x] || (od == sd[threadIdx.x] && oi < si[threadIdx.x])) {
                    sd[threadIdx.x] = od; si[threadIdx.x] = oi;
                }
            }
            __syncthreads();
        }
        if (threadIdx.x == 0) {
            ws_idx[l] = si[0];
            out_idxf[l] = (float)si[0];
            used[si[0]] = 1.0f;
        }
        __syncthreads();
        int bi0 = si[0];
        int c = threadIdx.x;
        outq[(size_t)b * (Dm * HW) + (size_t)c * HW + p] = emb[(size_t)bi0 * Dm + c];
        __syncthreads();
    }
}

// ---------------- fallback gather+loss ----------------
__global__ __launch_bounds__(256) void k_gather_loss(
    const float* __restrict__ z, const float* __restrict__ emb,
    const int* __restrict__ ws_idx, float* __restrict__ outq,
    float* __restrict__ partials)
{
    __shared__ int sidx[64];
    __shared__ float eldT[Dm][65];
    __shared__ float wsum[4];
    const int t = threadIdx.x;
    const int l0 = blockIdx.x * 64;
    const int b = l0 >> 10, p0 = l0 & 1023;
    if (t < 64) sidx[t] = ws_idx[l0 + t];
    __syncthreads();
    int w = t >> 6, lane = t & 63;
    for (int r = 0; r < 16; ++r) {
        int q = r * 4 + w;
        const float4 v = *reinterpret_cast<const float4*>(emb + (size_t)sidx[q] * Dm + lane * 4);
        eldT[lane * 4 + 0][q] = v.x; eldT[lane * 4 + 1][q] = v.y;
        eldT[lane * 4 + 2][q] = v.z; eldT[lane * 4 + 3][q] = v.w;
    }
    __syncthreads();
    float ls = 0.f;
    const size_t obase = (size_t)b * (Dm * HW) + p0 + lane;
    for (int it = 0; it < 64; ++it) {
        int c = w * 64 + it;
        size_t o = obase + (size_t)c * HW;
        float qv = eldT[c][lane];
        float zv = z[o];
        outq[o] = qv;
        float df = qv - zv;
        ls = fmaf(df, df, ls);
    }
    #pragma unroll
    for (int off = 32; off; off >>= 1) ls += __shfl_xor(ls, off);
    if (lane == 0) wsum[w] = ls;
    __syncthreads();
    if (t == 0) partials[blockIdx.x] = wsum[0] + wsum[1] + wsum[2] + wsum[3];
}

// ---------------- final: loss = (Sum||z||^2 + Sum d1)/count, used count ----------------
__global__ void k_final(const float* __restrict__ zn_part, const float* __restrict__ d1_part,
                        int nd1, const float* __restrict__ used,
                        float* __restrict__ out_loss, float* __restrict__ out_used)
{
    __shared__ double s1[256];
    __shared__ float  s2[256];
    int t = threadIdx.x;
    double a = 0.0;
    for (int i = t; i < 1024; i += 256) a += (double)zn_part[i];
    for (int i = t; i < nd1; i += 256) a += (double)d1_part[i];
    float u = 0.f;
    for (int i = t; i < NE; i += 256) u += used[i];
    s1[t] = a; s2[t] = u;
    __syncthreads();
    for (int st = 128; st; st >>= 1) {
        if (t < st) { s1[t] += s1[t + st]; s2[t] += s2[t + st]; }
        __syncthreads();
    }
    if (t == 0) { *out_loss = (float)(s1[0] / 8388608.0); *out_used = s2[0]; }
}

// ---------------- fallback final ----------------
__global__ void k_final_fb(const float* __restrict__ partials, const float* __restrict__ used,
                           float* __restrict__ out_loss, float* __restrict__ out_used)
{
    __shared__ float s1[256], s2[256];
    int t = threadIdx.x;
    float a = partials[t] + partials[t + 256];
    float u = 0.f;
    for (int i = t; i < NE; i += 256) u += used[i];
    s1[t] = a; s2[t] = u;
    __syncthreads();
    for (int st = 128; st; st >>= 1) {
        if (t < st) { s1[t] += s1[t + st]; s2[t] += s2[t + st]; }
        __syncthreads();
    }
    if (t == 0) { *out_loss = s1[0] / 8388608.f; *out_used = s2[0]; }
}

extern "C" void kernel_launch(void* const* d_in, const int* in_sizes, int n_in,
                              void* d_out, int out_size, void* d_ws, size_t ws_size,
                              hipStream_t stream) {
    const float* z   = (const float*)d_in[0];
    const float* emb = (const float*)d_in[1];
    float* out      = (float*)d_out;
    float* outq     = out;
    float* out_loss = out + QOFF;
    float* out_idxf = out + QOFF + 1;
    float* out_used = out + QOFF + 1 + L_TOT;

    float* ws       = (float*)d_ws;
    float* enorm    = ws;                         // [0, 2048)
    float* used     = ws + 2048;                  // [2048, 4096)
    float* zn_part  = ws + 4096;                  // [4096, 5120)
    float* d1_part  = ws + 5120;                  // [5120, 5632)  512
    int*   flag_cnt = (int*)(ws + 5632);          // 1 (+pad)
    int*   ws_idx   = (int*)(ws + 5888);          // 32768
    int*   flag_list= (int*)(ws + 5888 + L_TOT);  // 32768 -> ends 71424

    // 2-stripe partials
    float* pd1w = ws + 71680;                     // 65536
    float* pd2w = ws + 137216;                    // 65536
    int*   pi1w = (int*)(ws + 202752);            // 65536 -> ends 268288 floats

    size_t i8_bytes = 2ull * (NE + L_TOT) * Dm;   // 17825792
    size_t pbd_off_f = 268288 + i8_bytes / 4;     // 8B-aligned byte offset
    size_t pbi_off_f = pbd_off_f + 2 * 262144;
    size_t need_i8 = (pbi_off_f + 262144) * 4;    // ~22.1 MB

    if (ws_size >= need_i8) {
        signed char* e_hi8 = (signed char*)(ws + 268288);
        signed char* e_lo8 = e_hi8 + (size_t)NE * Dm;
        signed char* z_hi8 = e_lo8 + (size_t)NE * Dm;
        signed char* z_lo8 = z_hi8 + (size_t)L_TOT * Dm;
        double* pbd = (double*)(ws + pbd_off_f);
        int*    pbi = (int*)(ws + pbi_off_f);
        k_split_i8<<<1024, 256, 0, stream>>>(z, emb, z_hi8, z_lo8, e_hi8, e_lo8,
                                             enorm, zn_part, used, flag_cnt);
        k_score_i8<<<512, 256, 0, stream>>>(z_hi8, z_lo8, e_hi8, e_lo8, enorm,
                                            pd1w, pd2w, pi1w);
        k_mg<<<L_TOT / 64, 256, 0, stream>>>(pd1w, pd2w, pi1w, emb, ws_idx, out_idxf,
                                             used, flag_cnt, flag_list, d1_part, outq);
        k_refine_scan<<<2048, 256, 0, stream>>>(z, emb, flag_cnt, flag_list, pbd, pbi);
        k_refine_merge<<<256, 256, 0, stream>>>(emb, flag_cnt, flag_list, pbd, pbi,
                                                ws_idx, out_idxf, used, outq);
        k_final<<<1, 256, 0, stream>>>(zn_part, d1_part, 512, used, out_loss, out_used);
    } else {
        hipMemsetAsync(used, 0, (size_t)3584 * 4, stream);
        k_enorm<<<NE / 4, 256, 0, stream>>>(emb, enorm);
        k_argmin_f32<<<L_TOT / BM, 256, 0, stream>>>(z, emb, enorm, ws_idx, out_idxf, used,
                                                     flag_cnt, flag_list);
        k_refine<<<256, 256, 0, stream>>>(z, emb, flag_cnt, flag_list, ws_idx, out_idxf,
                                          used, outq);
        k_gather_loss<<<L_TOT / 64, 256, 0, stream>>>(z, emb, ws_idx, outq, zn_part);
        k_final_fb<<<1, 256, 0, stream>>>(zn_part, used, out_loss, out_used);
    }
}